// Round 8
// baseline (593.784 us; speedup 1.0000x reference)
//
#include <hip/hip_runtime.h>

#define FEAT 18432

typedef __attribute__((ext_vector_type(8))) short short8;
typedef __attribute__((ext_vector_type(4))) float f32x4;

__device__ __forceinline__ float b2f(unsigned short s) {
  union { unsigned int u; float f; } v; v.u = ((unsigned int)s) << 16; return v.f;
}
__device__ __forceinline__ unsigned short f2bf(float x) {
  union { float f; unsigned int u; } v; v.f = x;
  unsigned int u = v.u;
  unsigned int r = (u + 0x7FFFu + ((u >> 16) & 1u)) >> 16;
  return (unsigned short)r;
}

// async global->LDS, 16B per lane; LDS dest = base + lane*16 (wave-uniform base)
__device__ __forceinline__ void gl_lds16(const void* g, void* l) {
  __builtin_amdgcn_global_load_lds(
      (const __attribute__((address_space(1))) unsigned int*)g,
      (__attribute__((address_space(3))) unsigned int*)l, 16, 0, 0);
}

// K0: s1[b][c][96][96] (f32) -> xTn[b][f][ic] bf16, ic contiguous (128B rows),
// with 16B chunks swizzled within each row: pos = chunk ^ (f&7)  (f&7 == c&7).
__global__ __launch_bounds__(256) void k_transpose(const float* __restrict__ s1,
                                                   unsigned short* __restrict__ xT) {
  int c = blockIdx.x, b = blockIdx.y;
  __shared__ float lds[96 * 99];            // plane [h][w], pad 99
  int t = threadIdx.x;
  const float* src = s1 + ((size_t)b * 128 + c) * 9216;
  for (int idx = t; idx < 2304; idx += 256) {
    float4 v = ((const float4*)src)[idx];
    int h = idx / 24, w0 = (idx - h * 24) * 4;
    float* p = lds + h * 99 + w0;
    p[0] = v.x; p[1] = v.y; p[2] = v.z; p[3] = v.w;
  }
  __syncthreads();
  unsigned short* dstb = xT + (size_t)b * FEAT * 64;
  int sw = c & 7;
  for (int idx = t; idx < 1152; idx += 256) {
    int p1p2 = idx >> 3, gh = idx & 7;
    int p1 = p1p2 / 12, p2 = p1p2 - p1 * 12;
    const float* row = lds + (gh * 12 + p1) * 99 + p2;
    uint4 u;
    u.x = f2bf(row[0])  | ((unsigned int)f2bf(row[12]) << 16);
    u.y = f2bf(row[24]) | ((unsigned int)f2bf(row[36]) << 16);
    u.z = f2bf(row[48]) | ((unsigned int)f2bf(row[60]) << 16);
    u.w = f2bf(row[72]) | ((unsigned int)f2bf(row[84]) << 16);
    int f = p1p2 * 128 + c;
    int pos = gh ^ sw;
    *(uint4*)(dstb + (size_t)f * 64 + pos * 8) = u;
  }
}

// K_prep: pack pe_w -> wpk[oc][320] bf16 with chunk swizzle
__global__ __launch_bounds__(256) void k_prep(const float* __restrict__ pe_w,
                                              unsigned short* __restrict__ wpk) {
  int oc0 = blockIdx.x * 8;
  for (int e = threadIdx.x; e < 2560; e += 256) {
    int oc = oc0 + e / 320;
    int kL = e - (e / 320) * 320;
    int ic = kL & 63, kk = kL >> 6;
    float v = pe_w[(oc * 64 + ic) * 5 + kk];
    int LC = kL >> 3;
    int pos = (LC & 56) | ((LC & 7) ^ (oc & 7));
    wpk[oc * 320 + (pos << 3) + (kL & 7)] = f2bf(v);
  }
}

// K1 (MFMA): conv1d over f as GEMM M=64(oc) x N=18432(f) x K=320
// + BN(eval) + ReLU + selective square. Staging via global_load_lds (16B),
// swizzled LDS reads (conflict-free b128).
__global__ __launch_bounds__(256) void k_conv_pe(
    const unsigned short* __restrict__ xT, const unsigned short* __restrict__ wpk,
    const float* __restrict__ bn_g, const float* __restrict__ bn_b,
    const float* __restrict__ bn_m, const float* __restrict__ bn_v,
    const int* __restrict__ indexp, unsigned short* __restrict__ ym) {
  extern __shared__ char smem[];
  unsigned short* Wl = (unsigned short*)smem;            // 64*320*2 = 40960 B
  unsigned short* xl = (unsigned short*)(smem + 40960);  // 260*64*2 = 33280 B
  float* scf = (float*)(smem + 74240);
  float* shf = (float*)(smem + 74496);
  int*   sli = (int*)(smem + 74752);
  int t = threadIdx.x;
  int b = blockIdx.y;
  int blk_f0 = blockIdx.x << 9;
  int lane = t & 63, w = t >> 6;
  int n16 = lane & 15, q = lane >> 4;

  for (int j = 0; j < 10; ++j) {
    int seg = w * 10 + j;
    gl_lds16((const char*)wpk + (seg << 10) + lane * 16, (char*)Wl + (seg << 10));
  }
  if (t < 64) {
    float sc = bn_g[t] * rsqrtf(bn_v[t] + 1e-5f);
    scf[t] = sc;
    shf[t] = bn_b[t] - bn_m[t] * sc;
    int i0 = indexp[0] / 12 * 8 + indexp[1] / 12;
    int i1 = indexp[2] / 12 * 8 + indexp[3] / 12;
    int i2 = indexp[4] / 12 * 8 + indexp[5] / 12;
    int i3 = indexp[6] / 12 * 8 + indexp[7] / 12;
    sli[t] = (t == i0 || t == i1 || t == i2 || t == i3) ? 1 : 0;
  }

  const unsigned short* xb = xT + (size_t)b * FEAT * 64;
  const unsigned int* xbu = (const unsigned int*)xb;

  for (int wnd = 0; wnd < 2; ++wnd) {
    int F0 = blk_f0 + (wnd << 8);
    __syncthreads();
    int flA = (F0 == 0) ? 2 : 0;
    for (int j = 0; j < 8; ++j) {
      int seg = (w << 3) + j;
      int gRow = F0 - 2 + flA + (seg << 3);
      gl_lds16((const char*)xb + (size_t)gRow * 128 + lane * 16,
               (char*)xl + flA * 128 + (seg << 10));
    }
    if (t < 128) {
      int r0 = (flA == 2) ? 0 : 256;
      int fl = (t < 64) ? (r0 + (t >> 5)) : (258 + ((t >> 5) & 1));
      int j = t & 31;
      int f = F0 - 2 + fl;
      unsigned int v = 0;
      if (f >= 0 && f < FEAT) v = xbu[(size_t)f * 32 + j];
      ((unsigned int*)xl)[fl * 32 + j] = v;
    }
    __syncthreads();

    f32x4 acc[4][4];
#pragma unroll
    for (int mt = 0; mt < 4; ++mt)
#pragma unroll
      for (int nt = 0; nt < 4; ++nt) acc[mt][nt] = (f32x4){0.f, 0.f, 0.f, 0.f};

    int rowB = w * 64 + n16;
#pragma unroll
    for (int kk = 0; kk < 5; ++kk) {
      int swb = (n16 + kk + 6) & 7;
#pragma unroll
      for (int ih = 0; ih < 2; ++ih) {
        int ca = (ih << 2) | q;
        const unsigned short* Ap = Wl + kk * 64 + ((ca ^ (n16 & 7)) << 3) + n16 * 320;
        short8 a0 = *(const short8*)(Ap);
        short8 a1 = *(const short8*)(Ap + 16 * 320);
        short8 a2 = *(const short8*)(Ap + 32 * 320);
        short8 a3 = *(const short8*)(Ap + 48 * 320);
        const unsigned short* Bp = xl + ((ca ^ swb) << 3) + (rowB + kk) * 64;
        short8 b0 = *(const short8*)(Bp);
        short8 b1 = *(const short8*)(Bp + 16 * 64);
        short8 b2 = *(const short8*)(Bp + 32 * 64);
        short8 b3 = *(const short8*)(Bp + 48 * 64);
        acc[0][0] = __builtin_amdgcn_mfma_f32_16x16x32_bf16(a0, b0, acc[0][0], 0, 0, 0);
        acc[0][1] = __builtin_amdgcn_mfma_f32_16x16x32_bf16(a0, b1, acc[0][1], 0, 0, 0);
        acc[0][2] = __builtin_amdgcn_mfma_f32_16x16x32_bf16(a0, b2, acc[0][2], 0, 0, 0);
        acc[0][3] = __builtin_amdgcn_mfma_f32_16x16x32_bf16(a0, b3, acc[0][3], 0, 0, 0);
        acc[1][0] = __builtin_amdgcn_mfma_f32_16x16x32_bf16(a1, b0, acc[1][0], 0, 0, 0);
        acc[1][1] = __builtin_amdgcn_mfma_f32_16x16x32_bf16(a1, b1, acc[1][1], 0, 0, 0);
        acc[1][2] = __builtin_amdgcn_mfma_f32_16x16x32_bf16(a1, b2, acc[1][2], 0, 0, 0);
        acc[1][3] = __builtin_amdgcn_mfma_f32_16x16x32_bf16(a1, b3, acc[1][3], 0, 0, 0);
        acc[2][0] = __builtin_amdgcn_mfma_f32_16x16x32_bf16(a2, b0, acc[2][0], 0, 0, 0);
        acc[2][1] = __builtin_amdgcn_mfma_f32_16x16x32_bf16(a2, b1, acc[2][1], 0, 0, 0);
        acc[2][2] = __builtin_amdgcn_mfma_f32_16x16x32_bf16(a2, b2, acc[2][2], 0, 0, 0);
        acc[2][3] = __builtin_amdgcn_mfma_f32_16x16x32_bf16(a2, b3, acc[2][3], 0, 0, 0);
        acc[3][0] = __builtin_amdgcn_mfma_f32_16x16x32_bf16(a3, b0, acc[3][0], 0, 0, 0);
        acc[3][1] = __builtin_amdgcn_mfma_f32_16x16x32_bf16(a3, b1, acc[3][1], 0, 0, 0);
        acc[3][2] = __builtin_amdgcn_mfma_f32_16x16x32_bf16(a3, b2, acc[3][2], 0, 0, 0);
        acc[3][3] = __builtin_amdgcn_mfma_f32_16x16x32_bf16(a3, b3, acc[3][3], 0, 0, 0);
      }
    }

#pragma unroll
    for (int mt = 0; mt < 4; ++mt) {
#pragma unroll
      for (int i = 0; i < 4; ++i) {
        int oc = mt * 16 + q * 4 + i;
        float sc = scf[oc], sh = shf[oc];
        bool sel = sli[oc] != 0;
        unsigned short* yo = ym + ((size_t)b * 64 + oc) * FEAT + F0 + w * 64 + n16;
#pragma unroll
        for (int nt = 0; nt < 4; ++nt) {
          float y = fmaf(acc[mt][nt][i], sc, sh);
          y = fmaxf(y, 0.f);
          if (!sel) y *= y;
          yo[nt * 16] = f2bf(y);
        }
      }
    }
  }
}

// K2: 3x3 avg pool 96->32 in patch layout -> ori[b][n][c] (f32)
__global__ __launch_bounds__(256) void k_pool9(const unsigned short* __restrict__ ym,
                                               float* __restrict__ ori) {
  int oc = blockIdx.x, b = blockIdx.y;
  const unsigned short* src = ym + ((size_t)b * 64 + oc) * FEAT;
  int oh0 = (oc >> 3) << 2, ow0 = (oc & 7) << 2;
  for (int idx = threadIdx.x; idx < 2048; idx += 256) {
    int c = idx & 127, nl = idx >> 7;
    int pg1 = nl >> 2, pg2 = nl & 3;
    int pbase = (pg1 * 36 + pg2 * 3) * 128 + c;
    float s = 0.f;
#pragma unroll
    for (int dy = 0; dy < 3; ++dy)
#pragma unroll
      for (int dx = 0; dx < 3; ++dx)
        s += b2f(src[pbase + (dy * 12 + dx) * 128]);
    int n = (oh0 + pg1) * 32 + ow0 + pg2;
    ori[((size_t)b * 1024 + n) * 128 + c] = s * (1.f / 9.f);
  }
}

// K3: 2x2 avg pool of o (f32, 64->32) + LayerNorm over C -> ofl[b][n][c]
__global__ __launch_bounds__(256) void k_poolo_ln(
    const float* __restrict__ o, const float* __restrict__ lng,
    const float* __restrict__ lnb, float* __restrict__ ofl) {
  int y = blockIdx.x, b = blockIdx.y;
  __shared__ float pl[128 * 33];
  int t = threadIdx.x;
  for (int idx = t; idx < 4096; idx += 256) {
    int xo = idx & 31, c = idx >> 5;
    const float* p = o + (((size_t)b * 128 + c) * 64 + 2 * y) * 64 + 2 * xo;
    float2 a = *(const float2*)p;
    float2 d = *(const float2*)(p + 64);
    pl[c * 33 + xo] = 0.25f * (a.x + a.y + d.x + d.y);
  }
  __syncthreads();
  int xo = t >> 3, l8 = t & 7;
  float v[16]; float s = 0.f, q = 0.f;
#pragma unroll
  for (int i = 0; i < 16; ++i) {
    float x = pl[(l8 * 16 + i) * 33 + xo];
    v[i] = x; s += x; q += x * x;
  }
#pragma unroll
  for (int off = 1; off < 8; off <<= 1) {
    s += __shfl_xor(s, off, 8);
    q += __shfl_xor(q, off, 8);
  }
  float mean = s * (1.f / 128.f);
  float var = q * (1.f / 128.f) - mean * mean;
  float inv = rsqrtf(var + 1e-5f);
  float* dst = ofl + ((size_t)b * 1024 + y * 32 + xo) * 128 + l8 * 16;
#pragma unroll
  for (int i = 0; i < 16; ++i)
    dst[i] = (v[i] - mean) * inv * lng[l8 * 16 + i] + lnb[l8 * 16 + i];
}

// K4: LayerNorm over C of ori -> sn
__global__ __launch_bounds__(128) void k_ln(
    const float* __restrict__ src, const float* __restrict__ lng,
    const float* __restrict__ lnb, float* __restrict__ dst) {
  int n = blockIdx.x, b = blockIdx.y;
  size_t base = ((size_t)b * 1024 + n) * 128;
  int c = threadIdx.x;
  float v = src[base + c];
  float s = v, q = v * v;
#pragma unroll
  for (int off = 32; off > 0; off >>= 1) {
    s += __shfl_xor(s, off, 64);
    q += __shfl_xor(q, off, 64);
  }
  __shared__ float red[4];
  if ((c & 63) == 0) { red[(c >> 6) * 2] = s; red[(c >> 6) * 2 + 1] = q; }
  __syncthreads();
  s = red[0] + red[2]; q = red[1] + red[3];
  float mean = s * (1.f / 128.f);
  float var = q * (1.f / 128.f) - mean * mean;
  float inv = rsqrtf(var + 1e-5f);
  dst[base + c] = (v - mean) * inv * lng[c] + lnb[c];
}

// K5: out[M][Ncols] = A[M][128] @ W[Ncols][128]^T + bias
__global__ __launch_bounds__(256) void k_gemm(
    const float* __restrict__ A, const float* __restrict__ W,
    const float* __restrict__ bias, float* __restrict__ out, int Ncols) {
  int mt = blockIdx.x, ct = blockIdx.y;
  int m0 = mt << 6, c0 = ct << 6;
  __shared__ float Al[64 * 67], Wl[64 * 67];
  int t = threadIdx.x, tm = t & 15, tc = t >> 4;
  float acc[4][4];
#pragma unroll
  for (int i = 0; i < 4; ++i)
#pragma unroll
    for (int j = 0; j < 4; ++j) acc[i][j] = 0.f;
  for (int kc = 0; kc < 2; ++kc) {
    __syncthreads();
    for (int idx = t; idx < 4096; idx += 256) {
      int r = idx >> 6, kk = idx & 63;
      Al[r * 67 + kk] = A[(size_t)(m0 + r) * 128 + kc * 64 + kk];
      Wl[r * 67 + kk] = W[(size_t)(c0 + r) * 128 + kc * 64 + kk];
    }
    __syncthreads();
    for (int kk = 0; kk < 64; ++kk) {
      float a[4], w[4];
#pragma unroll
      for (int i = 0; i < 4; ++i) a[i] = Al[(tm * 4 + i) * 67 + kk];
#pragma unroll
      for (int j = 0; j < 4; ++j) w[j] = Wl[(tc * 4 + j) * 67 + kk];
#pragma unroll
      for (int i = 0; i < 4; ++i)
#pragma unroll
        for (int j = 0; j < 4; ++j) acc[i][j] = fmaf(a[i], w[j], acc[i][j]);
    }
  }
#pragma unroll
  for (int i = 0; i < 4; ++i) {
    float4 vv;
    vv.x = acc[i][0] + bias[c0 + tc * 4 + 0];
    vv.y = acc[i][1] + bias[c0 + tc * 4 + 1];
    vv.z = acc[i][2] + bias[c0 + tc * 4 + 2];
    vv.w = acc[i][3] + bias[c0 + tc * 4 + 3];
    *(float4*)(out + (size_t)(m0 + tm * 4 + i) * Ncols + c0 + tc * 4) = vv;
  }
}

// K_cvt: qkvb f32 [b][1024][384] -> qkb bf16 [b][h][{q,k}][1024][32];
//        yvbuf f32 [b][1024][128] -> vtb bf16 [b][h][32][1024] (V transposed).
__global__ __launch_bounds__(256) void k_cvt(const float* __restrict__ qkv,
                                             const float* __restrict__ yv,
                                             unsigned short* __restrict__ qkb,
                                             unsigned short* __restrict__ vtb) {
  int nt = blockIdx.x, b = blockIdx.y;   // 64 n per block
  int n0 = nt << 6;
  int t = threadIdx.x;
  __shared__ unsigned short tl[64 * 132];
  const float* qb = qkv + ((size_t)b * 1024 + n0) * 384;
  for (int it = 0; it < 16; ++it) {
    int idx = it * 256 + t;
    int n = idx >> 6, c4 = idx & 63;     // c = c4*4 in [0,256)
    float4 v = *(const float4*)(qb + (size_t)n * 384 + c4 * 4);
    int c = c4 << 2;
    int kind = c >> 7, h = (c >> 5) & 3, d = c & 31;
    uint2 u;
    u.x = (unsigned int)f2bf(v.x) | ((unsigned int)f2bf(v.y) << 16);
    u.y = (unsigned int)f2bf(v.z) | ((unsigned int)f2bf(v.w) << 16);
    *(uint2*)(qkb + ((((size_t)b * 4 + h) * 2 + kind) * 1024 + n0 + n) * 32 + d) = u;
  }
  const float* vb = yv + ((size_t)b * 1024 + n0) * 128;
  for (int it = 0; it < 8; ++it) {
    int idx = it * 256 + t;
    int n = idx >> 5, c4 = idx & 31;
    float4 v = *(const float4*)(vb + (size_t)n * 128 + c4 * 4);
    unsigned short* o = tl + n * 132 + c4 * 4;
    o[0] = f2bf(v.x); o[1] = f2bf(v.y); o[2] = f2bf(v.z); o[3] = f2bf(v.w);
  }
  __syncthreads();
  int c = t >> 1, half = t & 1;          // c = h*32+d in [0,128)
  unsigned short* orow = vtb + (((size_t)b * 4 + (c >> 5)) * 32 + (c & 31)) * 1024 + n0 + half * 32;
#pragma unroll
  for (int k = 0; k < 4; ++k) {
    short8 pack;
#pragma unroll
    for (int j = 0; j < 8; ++j)
      pack[j] = (short)tl[(half * 32 + k * 8 + j) * 132 + c];
    *(short8*)(orow + k * 8) = pack;
  }
}

// K6 (MFMA): flash attention. v4: swapped QK^T (S = mfma(K,Q)) puts a full
// q-row's scores lane-local -> softmax reduce = VALU tree + 2 shfl; P write =
// 4x b64. P layout & PV path unchanged.
__global__ __launch_bounds__(256) void k_attn(const float* __restrict__ qkv,
                                              const unsigned short* __restrict__ qkb,
                                              const unsigned short* __restrict__ vtb,
                                              float* __restrict__ att) {
  int qt = blockIdx.x, h = blockIdx.y, b = blockIdx.z;
  __shared__ unsigned short Qs[64 * 40];
  __shared__ unsigned short Ks[64 * 40];
  __shared__ unsigned short Vt[32 * 72];
  __shared__ unsigned short Pw[4 * 16 * 68];  // per-wave [q16][key64], stride 68
  int t = threadIdx.x;
  int lane = t & 63, w = t >> 6;
  int quad = lane >> 4, l16 = lane & 15;
  const float* qbase = qkv + (size_t)b * 1024 * 384;   // epilogue v residual (f32)
  const unsigned short* qrow = qkb + (((size_t)b * 4 + h) * 2 + 0) * 1024 * 32;
  const unsigned short* krow = qkb + (((size_t)b * 4 + h) * 2 + 1) * 1024 * 32;
  const unsigned short* vrow = vtb + ((size_t)b * 4 + h) * 32 * 1024;
  int q0 = qt << 6;
  int hd = h * 32;

  {
    int r = t >> 2, cq = t & 3;
    short8 v = *(const short8*)(qrow + (size_t)(q0 + r) * 32 + cq * 8);
    *(short8*)(Qs + r * 40 + cq * 8) = v;
  }
  __syncthreads();
  short8 aq = *(const short8*)(Qs + (w * 16 + l16) * 40 + quad * 8);

  f32x4 O[2];
  O[0] = (f32x4){0.f, 0.f, 0.f, 0.f};
  O[1] = (f32x4){0.f, 0.f, 0.f, 0.f};
  float mi0 = -1e30f, li0 = 0.f;       // per-lane, q = l16 (uniform across quads)
  unsigned short* Pme = Pw + w * (16 * 68);
  const float scl = 0.17677669529663688f;

  for (int ci = 0; ci < 16; ++ci) {
    __syncthreads();
    int kn0 = ci << 6;
    {
      int r = t >> 2, cq = t & 3;
      short8 kv = *(const short8*)(krow + (size_t)(kn0 + r) * 32 + cq * 8);
      *(short8*)(Ks + r * 40 + cq * 8) = kv;
      int d = t >> 3, cc = t & 7;
      short8 vv = *(const short8*)(vrow + (size_t)d * 1024 + kn0 + cc * 8);
      *(short8*)(Vt + d * 72 + cc * 8) = vv;
    }
    __syncthreads();

    // swapped: S[nt] row = key(quad*4+reg), col = q(l16)
    f32x4 S[4];
#pragma unroll
    for (int nt = 0; nt < 4; ++nt) S[nt] = (f32x4){0.f, 0.f, 0.f, 0.f};
#pragma unroll
    for (int nt = 0; nt < 4; ++nt) {
      short8 bk = *(const short8*)(Ks + (nt * 16 + l16) * 40 + quad * 8);
      S[nt] = __builtin_amdgcn_mfma_f32_16x16x32_bf16(bk, aq, S[nt], 0, 0, 0);
    }

    // lane-local 16 scores of q-row l16: key = nt*16 + quad*4 + reg
    float sv[16];
#pragma unroll
    for (int nt = 0; nt < 4; ++nt)
#pragma unroll
      for (int r = 0; r < 4; ++r) sv[nt * 4 + r] = S[nt][r] * scl;
    float m0 = fmaxf(fmaxf(sv[0], sv[1]), fmaxf(sv[2], sv[3]));
    float m1 = fmaxf(fmaxf(sv[4], sv[5]), fmaxf(sv[6], sv[7]));
    float m2 = fmaxf(fmaxf(sv[8], sv[9]), fmaxf(sv[10], sv[11]));
    float m3 = fmaxf(fmaxf(sv[12], sv[13]), fmaxf(sv[14], sv[15]));
    float rm = fmaxf(fmaxf(m0, m1), fmaxf(m2, m3));
    rm = fmaxf(rm, __shfl_xor(rm, 16));
    rm = fmaxf(rm, __shfl_xor(rm, 32));
    float nm = fmaxf(mi0, rm);
    float alpha = __expf(mi0 - nm);
    mi0 = nm;

    float psnt[4];
    unsigned short* pwr = Pme + l16 * 68 + quad * 4;
#pragma unroll
    for (int nt = 0; nt < 4; ++nt) {
      float p0 = __expf(sv[nt * 4 + 0] - nm);
      float p1 = __expf(sv[nt * 4 + 1] - nm);
      float p2 = __expf(sv[nt * 4 + 2] - nm);
      float p3 = __expf(sv[nt * 4 + 3] - nm);
      psnt[nt] = (p0 + p1) + (p2 + p3);
      uint2 u;
      u.x = (unsigned int)f2bf(p0) | ((unsigned int)f2bf(p1) << 16);
      u.y = (unsigned int)f2bf(p2) | ((unsigned int)f2bf(p3) << 16);
      *(uint2*)(pwr + nt * 16) = u;
    }
    float ps = (psnt[0] + psnt[1]) + (psnt[2] + psnt[3]);
    ps += __shfl_xor(ps, 16);
    ps += __shfl_xor(ps, 32);
    li0 = li0 * alpha + ps;

    // transpose alpha from q=l16 domain to q=quad*4+reg (O row domain)
    float al0 = __shfl(alpha, quad * 4 + 0);
    float al1 = __shfl(alpha, quad * 4 + 1);
    float al2 = __shfl(alpha, quad * 4 + 2);
    float al3 = __shfl(alpha, quad * 4 + 3);
    O[0][0] *= al0; O[1][0] *= al0;
    O[0][1] *= al1; O[1][1] *= al1;
    O[0][2] *= al2; O[1][2] *= al2;
    O[0][3] *= al3; O[1][3] *= al3;

#pragma unroll
    for (int kc = 0; kc < 2; ++kc) {
      short8 bv0 = *(const short8*)(Vt + l16 * 72 + kc * 32 + quad * 8);
      short8 bv1 = *(const short8*)(Vt + (16 + l16) * 72 + kc * 32 + quad * 8);
      short8 ap = *(const short8*)(Pme + l16 * 68 + kc * 32 + quad * 8);
      O[0] = __builtin_amdgcn_mfma_f32_16x16x32_bf16(ap, bv0, O[0], 0, 0, 0);
      O[1] = __builtin_amdgcn_mfma_f32_16x16x32_bf16(ap, bv1, O[1], 0, 0, 0);
    }
  }

#pragma unroll
  for (int reg = 0; reg < 4; ++reg) {
    float lit = __shfl(li0, quad * 4 + reg);
    int n = q0 + w * 16 + quad * 4 + reg;
    float inv = 1.f / lit;
#pragma unroll
    for (int nt = 0; nt < 2; ++nt) {
      int dd = hd + nt * 16 + l16;
      float val = O[nt][reg] * inv + qbase[(size_t)n * 384 + 256 + dd];
      att[((size_t)b * 1024 + n) * 128 + dd] = val;
    }
  }
}

// K7: proj GEMM + bias + ori residual, write transposed xv2[b][c][n]
__global__ __launch_bounds__(256) void k_proj(
    const float* __restrict__ att, const float* __restrict__ proj_w,
    const float* __restrict__ proj_b, const float* __restrict__ ori,
    float* __restrict__ xv2) {
  int nt = blockIdx.x, b = blockIdx.y;
  int n0 = nt << 6;
  __shared__ float Al[64 * 67], Wl[128 * 67];
  int t = threadIdx.x, tn = t & 15, tc = t >> 4;
  float acc[4][8];
#pragma unroll
  for (int i = 0; i < 4; ++i)
#pragma unroll
    for (int j = 0; j < 8; ++j) acc[i][j] = 0.f;
  const float* Ab = att + ((size_t)b * 1024 + n0) * 128;
  for (int kc = 0; kc < 2; ++kc) {
    __syncthreads();
    for (int idx = t; idx < 4096; idx += 256) {
      int r = idx >> 6, kk = idx & 63;
      Al[r * 67 + kk] = Ab[(size_t)r * 128 + kc * 64 + kk];
    }
    for (int idx = t; idx < 8192; idx += 256) {
      int r = idx >> 6, kk = idx & 63;
      Wl[r * 67 + kk] = proj_w[(size_t)r * 128 + kc * 64 + kk];
    }
    __syncthreads();
    for (int kk = 0; kk < 64; ++kk) {
      float a[4], w[8];
#pragma unroll
      for (int i = 0; i < 4; ++i) a[i] = Al[(tn * 4 + i) * 67 + kk];
#pragma unroll
      for (int j = 0; j < 8; ++j) w[j] = Wl[(tc * 8 + j) * 67 + kk];
#pragma unroll
      for (int i = 0; i < 4; ++i)
#pragma unroll
        for (int j = 0; j < 8; ++j) acc[i][j] = fmaf(a[i], w[j], acc[i][j]);
    }
  }
#pragma unroll
  for (int j = 0; j < 8; ++j) {
    int c = tc * 8 + j;
    float pb = proj_b[c];
    float4 vv;
    vv.x = acc[0][j] + pb + ori[((size_t)b * 1024 + n0 + tn * 4 + 0) * 128 + c];
    vv.y = acc[1][j] + pb + ori[((size_t)b * 1024 + n0 + tn * 4 + 1) * 128 + c];
    vv.z = acc[2][j] + pb + ori[((size_t)b * 1024 + n0 + tn * 4 + 2) * 128 + c];
    vv.w = acc[3][j] + pb + ori[((size_t)b * 1024 + n0 + tn * 4 + 3) * 128 + c];
    *(float4*)(xv2 + ((size_t)b * 128 + c) * 1024 + n0 + tn * 4) = vv;
  }
}

// K8: conv1d over n (128->128 channels, K=5, pad=2) + residual.
// v5: ch-split (g halves ic) + depth-1 HALF-CHUNK weight prefetch: ping-pong
// 20-float buffers (4 ic x 5 taps), fully static indexing. ~90 VGPR — keeps
// weights in registers (round-3's 40+40 dbuf hit the 128-VGPR cliff; the
// no-prefetch version let the compiler sink loads -> per-chain L2 stalls).
__global__ __launch_bounds__(256, 4) void k_conv1d(
    const float* __restrict__ xv2, const float* __restrict__ cw,
    float* __restrict__ xv3) {
  int nt = blockIdx.x, b = blockIdx.y;
  int n0 = nt << 4;                        // 16 n per block
  __shared__ float xl[128 * 20];           // [ic][j], j = n - (n0-2), window of 20
  __shared__ float part[128 * 16];         // g=1 partial sums
  int t = threadIdx.x;
  const float* xb = xv2 + (size_t)b * 128 * 1024;
  for (int idx = t; idx < 2560; idx += 256) {
    int ic = idx / 20, j = idx - ic * 20;
    int n = n0 + j - 2;
    xl[idx] = (n >= 0 && n < 1024) ? xb[(size_t)ic * 1024 + n] : 0.f;
  }
  __syncthreads();

  int oc = t & 127, g = t >> 7;            // g in {0,1}: ic-half
  float acc[16];
#pragma unroll
  for (int i = 0; i < 16; ++i) acc[i] = 0.f;

  const float4* wbase = (const float4*)(cw + (size_t)oc * 640 + g * 320);
  float wA[20], wB[20];

#define LOADH(W, H) do { \
  _Pragma("unroll") \
  for (int q2 = 0; q2 < 5; ++q2) { \
    float4 v = wbase[(H) * 5 + q2]; \
    W[q2 * 4] = v.x; W[q2 * 4 + 1] = v.y; W[q2 * 4 + 2] = v.z; W[q2 * 4 + 3] = v.w; \
  } } while (0)

#define COMPUTEH(W, H) do { \
  _Pragma("unroll") \
  for (int il = 0; il < 4; ++il) { \
    int ic = g * 64 + (H) * 4 + il; \
    const float* xr = xl + ic * 20;      /* wave-uniform broadcast */ \
    float xw[20]; \
    _Pragma("unroll") \
    for (int q2 = 0; q2 < 5; ++q2) { \
      float4 v = *(const float4*)(xr + q2 * 4); \
      xw[q2 * 4] = v.x; xw[q2 * 4 + 1] = v.y; xw[q2 * 4 + 2] = v.z; xw[q2 * 4 + 3] = v.w; \
    } \
    float w0 = W[il * 5], w1 = W[il * 5 + 1], w2 = W[il * 5 + 2]; \
    float w3 = W[il * 5 + 3], w4 = W[il * 5 + 4]; \
    _Pragma("unroll") \
    for (int i = 0; i < 16; ++i) \
      acc[i] = fmaf(xw[i], w0, fmaf(xw[i + 1], w1, fmaf(xw[i + 2], w2, \
               fmaf(xw[i + 3], w3, fmaf(xw[i + 4], w4, acc[i]))))); \
  } } while (0)

  LOADH(wA, 0);
#pragma unroll 1
  for (int h = 0; h < 16; h += 2) {
    LOADH(wB, h + 1);                      // h+1 <= 15 always
    COMPUTEH(wA, h);
    if (h + 2 < 16) LOADH(wA, h + 2);
    COMPUTEH(wB, h + 1);
  }
#undef LOADH
#undef COMPUTEH

  if (g == 1) {
#pragma unroll
    for (int i = 0; i < 16; ++i) part[oc * 16 + i] = acc[i];
  }
  __syncthreads();
  if (g == 0) {
    const float* res = xb + (size_t)oc * 1024 + n0;
    float* outp = xv3 + ((size_t)b * 128 + oc) * 1024 + n0;
    const float* pp = part + oc * 16;
#pragma unroll
    for (int q2 = 0; q2 < 4; ++q2) {
      float4 r = *(const float4*)(res + q2 * 4);
      float4 p = *(const float4*)(pp + q2 * 4);
      float4 o_;
      o_.x = r.x + p.x + acc[q2 * 4 + 0];
      o_.y = r.y + p.y + acc[q2 * 4 + 1];
      o_.z = r.z + p.z + acc[q2 * 4 + 2];
      o_.w = r.w + p.w + acc[q2 * 4 + 3];
      *(float4*)(outp + q2 * 4) = o_;
    }
  }
}

// K9: bilinear 32->96 align_corners=True, f32 out
__global__ __launch_bounds__(256) void k_bilinear(const float* __restrict__ xv3,
                                                  float* __restrict__ out) {
  int idx = blockIdx.x * 256 + threadIdx.x;
  int X = idx % 96;
  int t2 = idx / 96;
  int Y = t2 % 96;
  int bc = t2 / 96;
  const float* src = xv3 + (size_t)bc * 1024;
  const float r = 31.f / 95.f;
  float py = Y * r, px = X * r;
  int y0 = (int)py, x0 = (int)px;
  float wy = py - y0, wx = px - x0;
  int y1 = y0 < 31 ? y0 + 1 : 31, x1 = x0 < 31 ? x0 + 1 : 31;
  float a = src[y0 * 32 + x0], b_ = src[y0 * 32 + x1];
  float c_ = src[y1 * 32 + x0], d_ = src[y1 * 32 + x1];
  float t0 = a * (1.f - wy) + c_ * wy;
  float t1 = b_ * (1.f - wy) + d_ * wy;
  out[idx] = t0 * (1.f - wx) + t1 * wx;
}

extern "C" void kernel_launch(void* const* d_in, const int* in_sizes, int n_in,
                              void* d_out, int out_size, void* d_ws, size_t ws_size,
                              hipStream_t stream) {
  (void)in_sizes; (void)n_in; (void)out_size; (void)ws_size;
  const float* s1    = (const float*)d_in[0];
  const float* o     = (const float*)d_in[1];
  const int*   indx  = (const int*)d_in[2];
  const float* pe_w  = (const float*)d_in[3];
  const float* bn_g  = (const float*)d_in[4];
  const float* bn_b  = (const float*)d_in[5];
  const float* bn_m  = (const float*)d_in[6];
  const float* bn_v  = (const float*)d_in[7];
  const float* lnx_g = (const float*)d_in[8];
  const float* lnx_b = (const float*)d_in[9];
  const float* lny_g = (const float*)d_in[10];
  const float* lny_b = (const float*)d_in[11];
  const float* qkv_w = (const float*)d_in[12];
  const float* qkv_b = (const float*)d_in[13];
  const float* yv_w  = (const float*)d_in[14];
  const float* yv_b  = (const float*)d_in[15];
  const float* proj_w = (const float*)d_in[16];
  const float* proj_b = (const float*)d_in[17];
  const float* c1d_w  = (const float*)d_in[18];

  char* ws = (char*)d_ws;
  // Phase 1: xTn bf16 [ws+0, 37.7MB) [f][ic] swizzled, ymh bf16 [ws+37.7MB, 75.5MB).
  unsigned short* xTh = (unsigned short*)ws;
  unsigned short* ymh = (unsigned short*)(ws + 37748736);
  // wpk (41KB packed weights) lives in d_out scratch (overwritten by k_bilinear at the end).
  unsigned short* wpk = (unsigned short*)d_out;
  // Phase 2 (xTh dead after k_conv_pe): region A = [ws+0, 37.7MB)
  float* ori  = (float*)ws;                 // [0, 8.4MB)
  float* sn   = (float*)(ws + 8388608);     // dead after yv gemm
  float* ofl  = (float*)(ws + 16777216);    // dead after qkv gemm
  float* attb = (float*)(ws + 25165824);    // [25.2MB, 33.6MB)
  // Phase 3 (ymh dead after k_pool9): region B = [ws+37.7MB, 75.5MB)
  float* qkvb  = (float*)(ws + 37748736);   // 25.2MB
  float* yvbuf = (float*)(ws + 62914560);   // 8.4MB, dead after k_cvt
  // bf16 attn operands:
  unsigned short* qkb = (unsigned short*)(ws + 16777216);  // alias ofl, 8.4MB
  unsigned short* vtb = (unsigned short*)(ws + 71303168);  // tail, 4.2MB
  float* xv2   = (float*)(ws + 37748736);   // alias qkvb (dead after k_attn)
  float* xv3   = (float*)(ws + 46137344);

  hipLaunchKernelGGL(k_prep, dim3(8), dim3(256), 0, stream, pe_w, wpk);
  hipLaunchKernelGGL(k_transpose, dim3(128, 16), dim3(256), 0, stream, s1, xTh);
  hipLaunchKernelGGL(k_conv_pe, dim3(36, 16), dim3(256), 75008, stream,
                     xTh, wpk, bn_g, bn_b, bn_m, bn_v, indx, ymh);
  hipLaunchKernelGGL(k_pool9, dim3(64, 16), dim3(256), 0, stream, ymh, ori);
  hipLaunchKernelGGL(k_poolo_ln, dim3(32, 16), dim3(256), 0, stream, o, lnx_g, lnx_b, ofl);
  hipLaunchKernelGGL(k_ln, dim3(1024, 16), dim3(128), 0, stream, ori, lny_g, lny_b, sn);
  hipLaunchKernelGGL(k_gemm, dim3(256, 6), dim3(256), 0, stream, ofl, qkv_w, qkv_b, qkvb, 384);
  hipLaunchKernelGGL(k_gemm, dim3(256, 2), dim3(256), 0, stream, sn, yv_w, yv_b, yvbuf, 128);
  hipLaunchKernelGGL(k_cvt, dim3(16, 16), dim3(256), 0, stream, qkvb, yvbuf, qkb, vtb);
  hipLaunchKernelGGL(k_attn, dim3(16, 4, 16), dim3(256), 0, stream, qkvb, qkb, vtb, attb);
  hipLaunchKernelGGL(k_proj, dim3(16, 16), dim3(256), 0, stream, attb, proj_w, proj_b, ori, xv2);
  hipLaunchKernelGGL(k_conv1d, dim3(64, 16), dim3(256), 0, stream, xv2, c1d_w, xv3);
  hipLaunchKernelGGL(k_bilinear, dim3(73728), dim3(256), 0, stream, xv3, (float*)d_out);
}

// Round 9
// 474.507 us; speedup vs baseline: 1.2514x; 1.2514x over previous
//
#include <hip/hip_runtime.h>

#define FEAT 18432

typedef __attribute__((ext_vector_type(8))) short short8;
typedef __attribute__((ext_vector_type(4))) float f32x4;

__device__ __forceinline__ float b2f(unsigned short s) {
  union { unsigned int u; float f; } v; v.u = ((unsigned int)s) << 16; return v.f;
}
__device__ __forceinline__ unsigned short f2bf(float x) {
  union { float f; unsigned int u; } v; v.f = x;
  unsigned int u = v.u;
  unsigned int r = (u + 0x7FFFu + ((u >> 16) & 1u)) >> 16;
  return (unsigned short)r;
}

// async global->LDS, 16B per lane; LDS dest = base + lane*16 (wave-uniform base)
__device__ __forceinline__ void gl_lds16(const void* g, void* l) {
  __builtin_amdgcn_global_load_lds(
      (const __attribute__((address_space(1))) unsigned int*)g,
      (__attribute__((address_space(3))) unsigned int*)l, 16, 0, 0);
}

// K0: s1[b][c][96][96] (f32) -> xTn[b][f][ic] bf16, ic contiguous (128B rows),
// with 16B chunks swizzled within each row: pos = chunk ^ (f&7)  (f&7 == c&7).
__global__ __launch_bounds__(256) void k_transpose(const float* __restrict__ s1,
                                                   unsigned short* __restrict__ xT) {
  int c = blockIdx.x, b = blockIdx.y;
  __shared__ float lds[96 * 99];            // plane [h][w], pad 99
  int t = threadIdx.x;
  const float* src = s1 + ((size_t)b * 128 + c) * 9216;
  for (int idx = t; idx < 2304; idx += 256) {
    float4 v = ((const float4*)src)[idx];
    int h = idx / 24, w0 = (idx - h * 24) * 4;
    float* p = lds + h * 99 + w0;
    p[0] = v.x; p[1] = v.y; p[2] = v.z; p[3] = v.w;
  }
  __syncthreads();
  unsigned short* dstb = xT + (size_t)b * FEAT * 64;
  int sw = c & 7;
  for (int idx = t; idx < 1152; idx += 256) {
    int p1p2 = idx >> 3, gh = idx & 7;
    int p1 = p1p2 / 12, p2 = p1p2 - p1 * 12;
    const float* row = lds + (gh * 12 + p1) * 99 + p2;
    uint4 u;
    u.x = f2bf(row[0])  | ((unsigned int)f2bf(row[12]) << 16);
    u.y = f2bf(row[24]) | ((unsigned int)f2bf(row[36]) << 16);
    u.z = f2bf(row[48]) | ((unsigned int)f2bf(row[60]) << 16);
    u.w = f2bf(row[72]) | ((unsigned int)f2bf(row[84]) << 16);
    int f = p1p2 * 128 + c;
    int pos = gh ^ sw;
    *(uint4*)(dstb + (size_t)f * 64 + pos * 8) = u;
  }
}

// K_prep: pack pe_w -> wpk[oc][320] bf16 with chunk swizzle
__global__ __launch_bounds__(256) void k_prep(const float* __restrict__ pe_w,
                                              unsigned short* __restrict__ wpk) {
  int oc0 = blockIdx.x * 8;
  for (int e = threadIdx.x; e < 2560; e += 256) {
    int oc = oc0 + e / 320;
    int kL = e - (e / 320) * 320;
    int ic = kL & 63, kk = kL >> 6;
    float v = pe_w[(oc * 64 + ic) * 5 + kk];
    int LC = kL >> 3;
    int pos = (LC & 56) | ((LC & 7) ^ (oc & 7));
    wpk[oc * 320 + (pos << 3) + (kL & 7)] = f2bf(v);
  }
}

// K_prepc: transpose conv1d weights cw[oc][640] -> cwt[r640][oc] (oc contiguous)
__global__ __launch_bounds__(256) void k_prepc(const float* __restrict__ cw,
                                               float* __restrict__ cwt) {
  int e0 = (blockIdx.x * 256 + threadIdx.x) * 4;   // 80 blocks x 256 x 4 = 81920
#pragma unroll
  for (int j = 0; j < 4; ++j) {
    int e = e0 + j;
    int r = e >> 7, oc = e & 127;
    cwt[e] = cw[(size_t)oc * 640 + r];
  }
}

// K1 (MFMA): conv1d over f as GEMM M=64(oc) x N=18432(f) x K=320
// + BN(eval) + ReLU + selective square. Staging via global_load_lds (16B),
// swizzled LDS reads (conflict-free b128).
__global__ __launch_bounds__(256) void k_conv_pe(
    const unsigned short* __restrict__ xT, const unsigned short* __restrict__ wpk,
    const float* __restrict__ bn_g, const float* __restrict__ bn_b,
    const float* __restrict__ bn_m, const float* __restrict__ bn_v,
    const int* __restrict__ indexp, unsigned short* __restrict__ ym) {
  extern __shared__ char smem[];
  unsigned short* Wl = (unsigned short*)smem;            // 64*320*2 = 40960 B
  unsigned short* xl = (unsigned short*)(smem + 40960);  // 260*64*2 = 33280 B
  float* scf = (float*)(smem + 74240);
  float* shf = (float*)(smem + 74496);
  int*   sli = (int*)(smem + 74752);
  int t = threadIdx.x;
  int b = blockIdx.y;
  int blk_f0 = blockIdx.x << 9;
  int lane = t & 63, w = t >> 6;
  int n16 = lane & 15, q = lane >> 4;

  for (int j = 0; j < 10; ++j) {
    int seg = w * 10 + j;
    gl_lds16((const char*)wpk + (seg << 10) + lane * 16, (char*)Wl + (seg << 10));
  }
  if (t < 64) {
    float sc = bn_g[t] * rsqrtf(bn_v[t] + 1e-5f);
    scf[t] = sc;
    shf[t] = bn_b[t] - bn_m[t] * sc;
    int i0 = indexp[0] / 12 * 8 + indexp[1] / 12;
    int i1 = indexp[2] / 12 * 8 + indexp[3] / 12;
    int i2 = indexp[4] / 12 * 8 + indexp[5] / 12;
    int i3 = indexp[6] / 12 * 8 + indexp[7] / 12;
    sli[t] = (t == i0 || t == i1 || t == i2 || t == i3) ? 1 : 0;
  }

  const unsigned short* xb = xT + (size_t)b * FEAT * 64;
  const unsigned int* xbu = (const unsigned int*)xb;

  for (int wnd = 0; wnd < 2; ++wnd) {
    int F0 = blk_f0 + (wnd << 8);
    __syncthreads();
    int flA = (F0 == 0) ? 2 : 0;
    for (int j = 0; j < 8; ++j) {
      int seg = (w << 3) + j;
      int gRow = F0 - 2 + flA + (seg << 3);
      gl_lds16((const char*)xb + (size_t)gRow * 128 + lane * 16,
               (char*)xl + flA * 128 + (seg << 10));
    }
    if (t < 128) {
      int r0 = (flA == 2) ? 0 : 256;
      int fl = (t < 64) ? (r0 + (t >> 5)) : (258 + ((t >> 5) & 1));
      int j = t & 31;
      int f = F0 - 2 + fl;
      unsigned int v = 0;
      if (f >= 0 && f < FEAT) v = xbu[(size_t)f * 32 + j];
      ((unsigned int*)xl)[fl * 32 + j] = v;
    }
    __syncthreads();

    f32x4 acc[4][4];
#pragma unroll
    for (int mt = 0; mt < 4; ++mt)
#pragma unroll
      for (int nt = 0; nt < 4; ++nt) acc[mt][nt] = (f32x4){0.f, 0.f, 0.f, 0.f};

    int rowB = w * 64 + n16;
#pragma unroll
    for (int kk = 0; kk < 5; ++kk) {
      int swb = (n16 + kk + 6) & 7;
#pragma unroll
      for (int ih = 0; ih < 2; ++ih) {
        int ca = (ih << 2) | q;
        const unsigned short* Ap = Wl + kk * 64 + ((ca ^ (n16 & 7)) << 3) + n16 * 320;
        short8 a0 = *(const short8*)(Ap);
        short8 a1 = *(const short8*)(Ap + 16 * 320);
        short8 a2 = *(const short8*)(Ap + 32 * 320);
        short8 a3 = *(const short8*)(Ap + 48 * 320);
        const unsigned short* Bp = xl + ((ca ^ swb) << 3) + (rowB + kk) * 64;
        short8 b0 = *(const short8*)(Bp);
        short8 b1 = *(const short8*)(Bp + 16 * 64);
        short8 b2 = *(const short8*)(Bp + 32 * 64);
        short8 b3 = *(const short8*)(Bp + 48 * 64);
        acc[0][0] = __builtin_amdgcn_mfma_f32_16x16x32_bf16(a0, b0, acc[0][0], 0, 0, 0);
        acc[0][1] = __builtin_amdgcn_mfma_f32_16x16x32_bf16(a0, b1, acc[0][1], 0, 0, 0);
        acc[0][2] = __builtin_amdgcn_mfma_f32_16x16x32_bf16(a0, b2, acc[0][2], 0, 0, 0);
        acc[0][3] = __builtin_amdgcn_mfma_f32_16x16x32_bf16(a0, b3, acc[0][3], 0, 0, 0);
        acc[1][0] = __builtin_amdgcn_mfma_f32_16x16x32_bf16(a1, b0, acc[1][0], 0, 0, 0);
        acc[1][1] = __builtin_amdgcn_mfma_f32_16x16x32_bf16(a1, b1, acc[1][1], 0, 0, 0);
        acc[1][2] = __builtin_amdgcn_mfma_f32_16x16x32_bf16(a1, b2, acc[1][2], 0, 0, 0);
        acc[1][3] = __builtin_amdgcn_mfma_f32_16x16x32_bf16(a1, b3, acc[1][3], 0, 0, 0);
        acc[2][0] = __builtin_amdgcn_mfma_f32_16x16x32_bf16(a2, b0, acc[2][0], 0, 0, 0);
        acc[2][1] = __builtin_amdgcn_mfma_f32_16x16x32_bf16(a2, b1, acc[2][1], 0, 0, 0);
        acc[2][2] = __builtin_amdgcn_mfma_f32_16x16x32_bf16(a2, b2, acc[2][2], 0, 0, 0);
        acc[2][3] = __builtin_amdgcn_mfma_f32_16x16x32_bf16(a2, b3, acc[2][3], 0, 0, 0);
        acc[3][0] = __builtin_amdgcn_mfma_f32_16x16x32_bf16(a3, b0, acc[3][0], 0, 0, 0);
        acc[3][1] = __builtin_amdgcn_mfma_f32_16x16x32_bf16(a3, b1, acc[3][1], 0, 0, 0);
        acc[3][2] = __builtin_amdgcn_mfma_f32_16x16x32_bf16(a3, b2, acc[3][2], 0, 0, 0);
        acc[3][3] = __builtin_amdgcn_mfma_f32_16x16x32_bf16(a3, b3, acc[3][3], 0, 0, 0);
      }
    }

#pragma unroll
    for (int mt = 0; mt < 4; ++mt) {
#pragma unroll
      for (int i = 0; i < 4; ++i) {
        int oc = mt * 16 + q * 4 + i;
        float sc = scf[oc], sh = shf[oc];
        bool sel = sli[oc] != 0;
        unsigned short* yo = ym + ((size_t)b * 64 + oc) * FEAT + F0 + w * 64 + n16;
#pragma unroll
        for (int nt = 0; nt < 4; ++nt) {
          float y = fmaf(acc[mt][nt][i], sc, sh);
          y = fmaxf(y, 0.f);
          if (!sel) y *= y;
          yo[nt * 16] = f2bf(y);
        }
      }
    }
  }
}

// K2: 3x3 avg pool 96->32 in patch layout -> ori[b][n][c] (f32)
__global__ __launch_bounds__(256) void k_pool9(const unsigned short* __restrict__ ym,
                                               float* __restrict__ ori) {
  int oc = blockIdx.x, b = blockIdx.y;
  const unsigned short* src = ym + ((size_t)b * 64 + oc) * FEAT;
  int oh0 = (oc >> 3) << 2, ow0 = (oc & 7) << 2;
  for (int idx = threadIdx.x; idx < 2048; idx += 256) {
    int c = idx & 127, nl = idx >> 7;
    int pg1 = nl >> 2, pg2 = nl & 3;
    int pbase = (pg1 * 36 + pg2 * 3) * 128 + c;
    float s = 0.f;
#pragma unroll
    for (int dy = 0; dy < 3; ++dy)
#pragma unroll
      for (int dx = 0; dx < 3; ++dx)
        s += b2f(src[pbase + (dy * 12 + dx) * 128]);
    int n = (oh0 + pg1) * 32 + ow0 + pg2;
    ori[((size_t)b * 1024 + n) * 128 + c] = s * (1.f / 9.f);
  }
}

// K3: 2x2 avg pool of o (f32, 64->32) + LayerNorm over C -> ofl[b][n][c]
__global__ __launch_bounds__(256) void k_poolo_ln(
    const float* __restrict__ o, const float* __restrict__ lng,
    const float* __restrict__ lnb, float* __restrict__ ofl) {
  int y = blockIdx.x, b = blockIdx.y;
  __shared__ float pl[128 * 33];
  int t = threadIdx.x;
  for (int idx = t; idx < 4096; idx += 256) {
    int xo = idx & 31, c = idx >> 5;
    const float* p = o + (((size_t)b * 128 + c) * 64 + 2 * y) * 64 + 2 * xo;
    float2 a = *(const float2*)p;
    float2 d = *(const float2*)(p + 64);
    pl[c * 33 + xo] = 0.25f * (a.x + a.y + d.x + d.y);
  }
  __syncthreads();
  int xo = t >> 3, l8 = t & 7;
  float v[16]; float s = 0.f, q = 0.f;
#pragma unroll
  for (int i = 0; i < 16; ++i) {
    float x = pl[(l8 * 16 + i) * 33 + xo];
    v[i] = x; s += x; q += x * x;
  }
#pragma unroll
  for (int off = 1; off < 8; off <<= 1) {
    s += __shfl_xor(s, off, 8);
    q += __shfl_xor(q, off, 8);
  }
  float mean = s * (1.f / 128.f);
  float var = q * (1.f / 128.f) - mean * mean;
  float inv = rsqrtf(var + 1e-5f);
  float* dst = ofl + ((size_t)b * 1024 + y * 32 + xo) * 128 + l8 * 16;
#pragma unroll
  for (int i = 0; i < 16; ++i)
    dst[i] = (v[i] - mean) * inv * lng[l8 * 16 + i] + lnb[l8 * 16 + i];
}

// K4: LayerNorm over C of ori -> sn
__global__ __launch_bounds__(128) void k_ln(
    const float* __restrict__ src, const float* __restrict__ lng,
    const float* __restrict__ lnb, float* __restrict__ dst) {
  int n = blockIdx.x, b = blockIdx.y;
  size_t base = ((size_t)b * 1024 + n) * 128;
  int c = threadIdx.x;
  float v = src[base + c];
  float s = v, q = v * v;
#pragma unroll
  for (int off = 32; off > 0; off >>= 1) {
    s += __shfl_xor(s, off, 64);
    q += __shfl_xor(q, off, 64);
  }
  __shared__ float red[4];
  if ((c & 63) == 0) { red[(c >> 6) * 2] = s; red[(c >> 6) * 2 + 1] = q; }
  __syncthreads();
  s = red[0] + red[2]; q = red[1] + red[3];
  float mean = s * (1.f / 128.f);
  float var = q * (1.f / 128.f) - mean * mean;
  float inv = rsqrtf(var + 1e-5f);
  dst[base + c] = (v - mean) * inv * lng[c] + lnb[c];
}

// K5: out[M][Ncols] = A[M][128] @ W[Ncols][128]^T + bias
__global__ __launch_bounds__(256) void k_gemm(
    const float* __restrict__ A, const float* __restrict__ W,
    const float* __restrict__ bias, float* __restrict__ out, int Ncols) {
  int mt = blockIdx.x, ct = blockIdx.y;
  int m0 = mt << 6, c0 = ct << 6;
  __shared__ float Al[64 * 67], Wl[64 * 67];
  int t = threadIdx.x, tm = t & 15, tc = t >> 4;
  float acc[4][4];
#pragma unroll
  for (int i = 0; i < 4; ++i)
#pragma unroll
    for (int j = 0; j < 4; ++j) acc[i][j] = 0.f;
  for (int kc = 0; kc < 2; ++kc) {
    __syncthreads();
    for (int idx = t; idx < 4096; idx += 256) {
      int r = idx >> 6, kk = idx & 63;
      Al[r * 67 + kk] = A[(size_t)(m0 + r) * 128 + kc * 64 + kk];
      Wl[r * 67 + kk] = W[(size_t)(c0 + r) * 128 + kc * 64 + kk];
    }
    __syncthreads();
    for (int kk = 0; kk < 64; ++kk) {
      float a[4], w[4];
#pragma unroll
      for (int i = 0; i < 4; ++i) a[i] = Al[(tm * 4 + i) * 67 + kk];
#pragma unroll
      for (int j = 0; j < 4; ++j) w[j] = Wl[(tc * 4 + j) * 67 + kk];
#pragma unroll
      for (int i = 0; i < 4; ++i)
#pragma unroll
        for (int j = 0; j < 4; ++j) acc[i][j] = fmaf(a[i], w[j], acc[i][j]);
    }
  }
#pragma unroll
  for (int i = 0; i < 4; ++i) {
    float4 vv;
    vv.x = acc[i][0] + bias[c0 + tc * 4 + 0];
    vv.y = acc[i][1] + bias[c0 + tc * 4 + 1];
    vv.z = acc[i][2] + bias[c0 + tc * 4 + 2];
    vv.w = acc[i][3] + bias[c0 + tc * 4 + 3];
    *(float4*)(out + (size_t)(m0 + tm * 4 + i) * Ncols + c0 + tc * 4) = vv;
  }
}

// K_cvt: qkvb f32 [b][1024][384] -> qkb bf16 [b][h][{q,k}][1024][32];
//        yvbuf f32 [b][1024][128] -> vtb bf16 [b][h][32][1024] (V transposed).
__global__ __launch_bounds__(256) void k_cvt(const float* __restrict__ qkv,
                                             const float* __restrict__ yv,
                                             unsigned short* __restrict__ qkb,
                                             unsigned short* __restrict__ vtb) {
  int nt = blockIdx.x, b = blockIdx.y;   // 64 n per block
  int n0 = nt << 6;
  int t = threadIdx.x;
  __shared__ unsigned short tl[64 * 132];
  const float* qb = qkv + ((size_t)b * 1024 + n0) * 384;
  for (int it = 0; it < 16; ++it) {
    int idx = it * 256 + t;
    int n = idx >> 6, c4 = idx & 63;     // c = c4*4 in [0,256)
    float4 v = *(const float4*)(qb + (size_t)n * 384 + c4 * 4);
    int c = c4 << 2;
    int kind = c >> 7, h = (c >> 5) & 3, d = c & 31;
    uint2 u;
    u.x = (unsigned int)f2bf(v.x) | ((unsigned int)f2bf(v.y) << 16);
    u.y = (unsigned int)f2bf(v.z) | ((unsigned int)f2bf(v.w) << 16);
    *(uint2*)(qkb + ((((size_t)b * 4 + h) * 2 + kind) * 1024 + n0 + n) * 32 + d) = u;
  }
  const float* vb = yv + ((size_t)b * 1024 + n0) * 128;
  for (int it = 0; it < 8; ++it) {
    int idx = it * 256 + t;
    int n = idx >> 5, c4 = idx & 31;
    float4 v = *(const float4*)(vb + (size_t)n * 128 + c4 * 4);
    unsigned short* o = tl + n * 132 + c4 * 4;
    o[0] = f2bf(v.x); o[1] = f2bf(v.y); o[2] = f2bf(v.z); o[3] = f2bf(v.w);
  }
  __syncthreads();
  int c = t >> 1, half = t & 1;          // c = h*32+d in [0,128)
  unsigned short* orow = vtb + (((size_t)b * 4 + (c >> 5)) * 32 + (c & 31)) * 1024 + n0 + half * 32;
#pragma unroll
  for (int k = 0; k < 4; ++k) {
    short8 pack;
#pragma unroll
    for (int j = 0; j < 8; ++j)
      pack[j] = (short)tl[(half * 32 + k * 8 + j) * 132 + c];
    *(short8*)(orow + k * 8) = pack;
  }
}

// K6 (MFMA): flash attention. v4: swapped QK^T (S = mfma(K,Q)) puts a full
// q-row's scores lane-local -> softmax reduce = VALU tree + 2 shfl; P write =
// 4x b64. P layout & PV path unchanged.
__global__ __launch_bounds__(256) void k_attn(const float* __restrict__ qkv,
                                              const unsigned short* __restrict__ qkb,
                                              const unsigned short* __restrict__ vtb,
                                              float* __restrict__ att) {
  int qt = blockIdx.x, h = blockIdx.y, b = blockIdx.z;
  __shared__ unsigned short Qs[64 * 40];
  __shared__ unsigned short Ks[64 * 40];
  __shared__ unsigned short Vt[32 * 72];
  __shared__ unsigned short Pw[4 * 16 * 68];  // per-wave [q16][key64], stride 68
  int t = threadIdx.x;
  int lane = t & 63, w = t >> 6;
  int quad = lane >> 4, l16 = lane & 15;
  const float* qbase = qkv + (size_t)b * 1024 * 384;   // epilogue v residual (f32)
  const unsigned short* qrow = qkb + (((size_t)b * 4 + h) * 2 + 0) * 1024 * 32;
  const unsigned short* krow = qkb + (((size_t)b * 4 + h) * 2 + 1) * 1024 * 32;
  const unsigned short* vrow = vtb + ((size_t)b * 4 + h) * 32 * 1024;
  int q0 = qt << 6;
  int hd = h * 32;

  {
    int r = t >> 2, cq = t & 3;
    short8 v = *(const short8*)(qrow + (size_t)(q0 + r) * 32 + cq * 8);
    *(short8*)(Qs + r * 40 + cq * 8) = v;
  }
  __syncthreads();
  short8 aq = *(const short8*)(Qs + (w * 16 + l16) * 40 + quad * 8);

  f32x4 O[2];
  O[0] = (f32x4){0.f, 0.f, 0.f, 0.f};
  O[1] = (f32x4){0.f, 0.f, 0.f, 0.f};
  float mi0 = -1e30f, li0 = 0.f;       // per-lane, q = l16 (uniform across quads)
  unsigned short* Pme = Pw + w * (16 * 68);
  const float scl = 0.17677669529663688f;

  for (int ci = 0; ci < 16; ++ci) {
    __syncthreads();
    int kn0 = ci << 6;
    {
      int r = t >> 2, cq = t & 3;
      short8 kv = *(const short8*)(krow + (size_t)(kn0 + r) * 32 + cq * 8);
      *(short8*)(Ks + r * 40 + cq * 8) = kv;
      int d = t >> 3, cc = t & 7;
      short8 vv = *(const short8*)(vrow + (size_t)d * 1024 + kn0 + cc * 8);
      *(short8*)(Vt + d * 72 + cc * 8) = vv;
    }
    __syncthreads();

    // swapped: S[nt] row = key(quad*4+reg), col = q(l16)
    f32x4 S[4];
#pragma unroll
    for (int nt = 0; nt < 4; ++nt) S[nt] = (f32x4){0.f, 0.f, 0.f, 0.f};
#pragma unroll
    for (int nt = 0; nt < 4; ++nt) {
      short8 bk = *(const short8*)(Ks + (nt * 16 + l16) * 40 + quad * 8);
      S[nt] = __builtin_amdgcn_mfma_f32_16x16x32_bf16(bk, aq, S[nt], 0, 0, 0);
    }

    // lane-local 16 scores of q-row l16: key = nt*16 + quad*4 + reg
    float sv[16];
#pragma unroll
    for (int nt = 0; nt < 4; ++nt)
#pragma unroll
      for (int r = 0; r < 4; ++r) sv[nt * 4 + r] = S[nt][r] * scl;
    float m0 = fmaxf(fmaxf(sv[0], sv[1]), fmaxf(sv[2], sv[3]));
    float m1 = fmaxf(fmaxf(sv[4], sv[5]), fmaxf(sv[6], sv[7]));
    float m2 = fmaxf(fmaxf(sv[8], sv[9]), fmaxf(sv[10], sv[11]));
    float m3 = fmaxf(fmaxf(sv[12], sv[13]), fmaxf(sv[14], sv[15]));
    float rm = fmaxf(fmaxf(m0, m1), fmaxf(m2, m3));
    rm = fmaxf(rm, __shfl_xor(rm, 16));
    rm = fmaxf(rm, __shfl_xor(rm, 32));
    float nm = fmaxf(mi0, rm);
    float alpha = __expf(mi0 - nm);
    mi0 = nm;

    float psnt[4];
    unsigned short* pwr = Pme + l16 * 68 + quad * 4;
#pragma unroll
    for (int nt = 0; nt < 4; ++nt) {
      float p0 = __expf(sv[nt * 4 + 0] - nm);
      float p1 = __expf(sv[nt * 4 + 1] - nm);
      float p2 = __expf(sv[nt * 4 + 2] - nm);
      float p3 = __expf(sv[nt * 4 + 3] - nm);
      psnt[nt] = (p0 + p1) + (p2 + p3);
      uint2 u;
      u.x = (unsigned int)f2bf(p0) | ((unsigned int)f2bf(p1) << 16);
      u.y = (unsigned int)f2bf(p2) | ((unsigned int)f2bf(p3) << 16);
      *(uint2*)(pwr + nt * 16) = u;
    }
    float ps = (psnt[0] + psnt[1]) + (psnt[2] + psnt[3]);
    ps += __shfl_xor(ps, 16);
    ps += __shfl_xor(ps, 32);
    li0 = li0 * alpha + ps;

    // transpose alpha from q=l16 domain to q=quad*4+reg (O row domain)
    float al0 = __shfl(alpha, quad * 4 + 0);
    float al1 = __shfl(alpha, quad * 4 + 1);
    float al2 = __shfl(alpha, quad * 4 + 2);
    float al3 = __shfl(alpha, quad * 4 + 3);
    O[0][0] *= al0; O[1][0] *= al0;
    O[0][1] *= al1; O[1][1] *= al1;
    O[0][2] *= al2; O[1][2] *= al2;
    O[0][3] *= al3; O[1][3] *= al3;

#pragma unroll
    for (int kc = 0; kc < 2; ++kc) {
      short8 bv0 = *(const short8*)(Vt + l16 * 72 + kc * 32 + quad * 8);
      short8 bv1 = *(const short8*)(Vt + (16 + l16) * 72 + kc * 32 + quad * 8);
      short8 ap = *(const short8*)(Pme + l16 * 68 + kc * 32 + quad * 8);
      O[0] = __builtin_amdgcn_mfma_f32_16x16x32_bf16(ap, bv0, O[0], 0, 0, 0);
      O[1] = __builtin_amdgcn_mfma_f32_16x16x32_bf16(ap, bv1, O[1], 0, 0, 0);
    }
  }

#pragma unroll
  for (int reg = 0; reg < 4; ++reg) {
    float lit = __shfl(li0, quad * 4 + reg);
    int n = q0 + w * 16 + quad * 4 + reg;
    float inv = 1.f / lit;
#pragma unroll
    for (int nt = 0; nt < 2; ++nt) {
      int dd = hd + nt * 16 + l16;
      float val = O[nt][reg] * inv + qbase[(size_t)n * 384 + 256 + dd];
      att[((size_t)b * 1024 + n) * 128 + dd] = val;
    }
  }
}

// K7: proj GEMM + bias + ori residual, write transposed xv2[b][c][n]
__global__ __launch_bounds__(256) void k_proj(
    const float* __restrict__ att, const float* __restrict__ proj_w,
    const float* __restrict__ proj_b, const float* __restrict__ ori,
    float* __restrict__ xv2) {
  int nt = blockIdx.x, b = blockIdx.y;
  int n0 = nt << 6;
  __shared__ float Al[64 * 67], Wl[128 * 67];
  int t = threadIdx.x, tn = t & 15, tc = t >> 4;
  float acc[4][8];
#pragma unroll
  for (int i = 0; i < 4; ++i)
#pragma unroll
    for (int j = 0; j < 8; ++j) acc[i][j] = 0.f;
  const float* Ab = att + ((size_t)b * 1024 + n0) * 128;
  for (int kc = 0; kc < 2; ++kc) {
    __syncthreads();
    for (int idx = t; idx < 4096; idx += 256) {
      int r = idx >> 6, kk = idx & 63;
      Al[r * 67 + kk] = Ab[(size_t)r * 128 + kc * 64 + kk];
    }
    for (int idx = t; idx < 8192; idx += 256) {
      int r = idx >> 6, kk = idx & 63;
      Wl[r * 67 + kk] = proj_w[(size_t)r * 128 + kc * 64 + kk];
    }
    __syncthreads();
    for (int kk = 0; kk < 64; ++kk) {
      float a[4], w[8];
#pragma unroll
      for (int i = 0; i < 4; ++i) a[i] = Al[(tn * 4 + i) * 67 + kk];
#pragma unroll
      for (int j = 0; j < 8; ++j) w[j] = Wl[(tc * 8 + j) * 67 + kk];
#pragma unroll
      for (int i = 0; i < 4; ++i)
#pragma unroll
        for (int j = 0; j < 8; ++j) acc[i][j] = fmaf(a[i], w[j], acc[i][j]);
    }
  }
#pragma unroll
  for (int j = 0; j < 8; ++j) {
    int c = tc * 8 + j;
    float pb = proj_b[c];
    float4 vv;
    vv.x = acc[0][j] + pb + ori[((size_t)b * 1024 + n0 + tn * 4 + 0) * 128 + c];
    vv.y = acc[1][j] + pb + ori[((size_t)b * 1024 + n0 + tn * 4 + 1) * 128 + c];
    vv.z = acc[2][j] + pb + ori[((size_t)b * 1024 + n0 + tn * 4 + 2) * 128 + c];
    vv.w = acc[3][j] + pb + ori[((size_t)b * 1024 + n0 + tn * 4 + 3) * 128 + c];
    *(float4*)(xv2 + ((size_t)b * 128 + c) * 1024 + n0 + tn * 4) = vv;
  }
}

// K8: conv1d over n (128->128 channels, K=5, pad=2) + residual.
// v6: weights staged per 8-ic chunk in LDS (wl[40][128], oc-contiguous ->
// conflict-free lane reads; staged via global_load_lds from pre-transposed cwt).
// g splits n (8 each): every thread accumulates full ic range (no part buffer).
// No register arrays -> no spills (r8's wA/wB went to scratch: 485MB writes).
__global__ __launch_bounds__(256) void k_conv1d(
    const float* __restrict__ xv2, const float* __restrict__ cwt,
    float* __restrict__ xv3) {
  extern __shared__ char cs[];
  float* xl = (float*)cs;                  // [128][20], 10240 B
  float* wl = (float*)(cs + 10240);        // [40][128], 20480 B
  int nt = blockIdx.x, b = blockIdx.y;
  int n0 = nt << 4;                        // 16 n per block
  int t = threadIdx.x;
  int lane = t & 63, w = t >> 6;
  const float* xb = xv2 + (size_t)b * 128 * 1024;
  for (int idx = t; idx < 2560; idx += 256) {
    int ic = idx / 20, j = idx - ic * 20;
    int n = n0 + j - 2;
    xl[idx] = (n >= 0 && n < 1024) ? xb[(size_t)ic * 1024 + n] : 0.f;
  }

  int oc = t & 127, g = t >> 7;            // g in {0,1}: n-half (wave-uniform)
  float acc[8];
#pragma unroll
  for (int i = 0; i < 8; ++i) acc[i] = 0.f;

#pragma unroll 1
  for (int ch = 0; ch < 16; ++ch) {
    __syncthreads();                       // wl free (prev chunk consumed) + xl ready (ch=0)
#pragma unroll
    for (int j = 0; j < 5; ++j) {
      int seg = w * 5 + j;                 // 20 segs x 1KiB = 20480 B
      gl_lds16((const char*)cwt + (size_t)ch * 20480 + (seg << 10) + lane * 16,
               (char*)wl + (seg << 10));
    }
    __syncthreads();                       // staging complete

#pragma unroll
    for (int icl = 0; icl < 8; ++icl) {
      int ic = ch * 8 + icl;
      const float* xr = xl + ic * 20 + (g << 3);   // wave-uniform broadcast, 16B aligned
      float xw[12];
#pragma unroll
      for (int q2 = 0; q2 < 3; ++q2) {
        float4 v = *(const float4*)(xr + q2 * 4);
        xw[q2 * 4] = v.x; xw[q2 * 4 + 1] = v.y; xw[q2 * 4 + 2] = v.z; xw[q2 * 4 + 3] = v.w;
      }
      const float* wr = wl + icl * 5 * 128 + oc;   // lanes consecutive oc: conflict-free
      float w0 = wr[0], w1 = wr[128], w2 = wr[256], w3 = wr[384], w4 = wr[512];
#pragma unroll
      for (int i = 0; i < 8; ++i)
        acc[i] = fmaf(xw[i], w0, fmaf(xw[i + 1], w1, fmaf(xw[i + 2], w2,
                 fmaf(xw[i + 3], w3, fmaf(xw[i + 4], w4, acc[i])))));
    }
  }

  const float* res = xb + (size_t)oc * 1024 + n0 + (g << 3);
  float* outp = xv3 + ((size_t)b * 128 + oc) * 1024 + n0 + (g << 3);
#pragma unroll
  for (int i = 0; i < 8; ++i) outp[i] = res[i] + acc[i];
}

// K9: bilinear 32->96 align_corners=True, f32 out
__global__ __launch_bounds__(256) void k_bilinear(const float* __restrict__ xv3,
                                                  float* __restrict__ out) {
  int idx = blockIdx.x * 256 + threadIdx.x;
  int X = idx % 96;
  int t2 = idx / 96;
  int Y = t2 % 96;
  int bc = t2 / 96;
  const float* src = xv3 + (size_t)bc * 1024;
  const float r = 31.f / 95.f;
  float py = Y * r, px = X * r;
  int y0 = (int)py, x0 = (int)px;
  float wy = py - y0, wx = px - x0;
  int y1 = y0 < 31 ? y0 + 1 : 31, x1 = x0 < 31 ? x0 + 1 : 31;
  float a = src[y0 * 32 + x0], b_ = src[y0 * 32 + x1];
  float c_ = src[y1 * 32 + x0], d_ = src[y1 * 32 + x1];
  float t0 = a * (1.f - wy) + c_ * wy;
  float t1 = b_ * (1.f - wy) + d_ * wy;
  out[idx] = t0 * (1.f - wx) + t1 * wx;
}

extern "C" void kernel_launch(void* const* d_in, const int* in_sizes, int n_in,
                              void* d_out, int out_size, void* d_ws, size_t ws_size,
                              hipStream_t stream) {
  (void)in_sizes; (void)n_in; (void)out_size; (void)ws_size;
  const float* s1    = (const float*)d_in[0];
  const float* o     = (const float*)d_in[1];
  const int*   indx  = (const int*)d_in[2];
  const float* pe_w  = (const float*)d_in[3];
  const float* bn_g  = (const float*)d_in[4];
  const float* bn_b  = (const float*)d_in[5];
  const float* bn_m  = (const float*)d_in[6];
  const float* bn_v  = (const float*)d_in[7];
  const float* lnx_g = (const float*)d_in[8];
  const float* lnx_b = (const float*)d_in[9];
  const float* lny_g = (const float*)d_in[10];
  const float* lny_b = (const float*)d_in[11];
  const float* qkv_w = (const float*)d_in[12];
  const float* qkv_b = (const float*)d_in[13];
  const float* yv_w  = (const float*)d_in[14];
  const float* yv_b  = (const float*)d_in[15];
  const float* proj_w = (const float*)d_in[16];
  const float* proj_b = (const float*)d_in[17];
  const float* c1d_w  = (const float*)d_in[18];

  char* ws = (char*)d_ws;
  // Phase 1: xTn bf16 [ws+0, 37.7MB) [f][ic] swizzled, ymh bf16 [ws+37.7MB, 75.5MB).
  unsigned short* xTh = (unsigned short*)ws;
  unsigned short* ymh = (unsigned short*)(ws + 37748736);
  // d_out scratch (overwritten only by k_bilinear at the very end):
  //   wpk  (41KB packed conv_pe weights) at +0
  //   cwt  (328KB transposed conv1d weights) at +64KB
  unsigned short* wpk = (unsigned short*)d_out;
  float* cwt = (float*)((char*)d_out + 65536);
  // Phase 2 (xTh dead after k_conv_pe): region A = [ws+0, 37.7MB)
  float* ori  = (float*)ws;                 // [0, 8.4MB)
  float* sn   = (float*)(ws + 8388608);     // dead after yv gemm
  float* ofl  = (float*)(ws + 16777216);    // dead after qkv gemm
  float* attb = (float*)(ws + 25165824);    // [25.2MB, 33.6MB)
  // Phase 3 (ymh dead after k_pool9): region B = [ws+37.7MB, 75.5MB)
  float* qkvb  = (float*)(ws + 37748736);   // 25.2MB
  float* yvbuf = (float*)(ws + 62914560);   // 8.4MB, dead after k_cvt
  // bf16 attn operands:
  unsigned short* qkb = (unsigned short*)(ws + 16777216);  // alias ofl, 8.4MB
  unsigned short* vtb = (unsigned short*)(ws + 71303168);  // tail, 4.2MB
  float* xv2   = (float*)(ws + 37748736);   // alias qkvb (dead after k_attn)
  float* xv3   = (float*)(ws + 46137344);

  hipLaunchKernelGGL(k_prep, dim3(8), dim3(256), 0, stream, pe_w, wpk);
  hipLaunchKernelGGL(k_prepc, dim3(80), dim3(256), 0, stream, c1d_w, cwt);
  hipLaunchKernelGGL(k_transpose, dim3(128, 16), dim3(256), 0, stream, s1, xTh);
  hipLaunchKernelGGL(k_conv_pe, dim3(36, 16), dim3(256), 75008, stream,
                     xTh, wpk, bn_g, bn_b, bn_m, bn_v, indx, ymh);
  hipLaunchKernelGGL(k_pool9, dim3(64, 16), dim3(256), 0, stream, ymh, ori);
  hipLaunchKernelGGL(k_poolo_ln, dim3(32, 16), dim3(256), 0, stream, o, lnx_g, lnx_b, ofl);
  hipLaunchKernelGGL(k_ln, dim3(1024, 16), dim3(128), 0, stream, ori, lny_g, lny_b, sn);
  hipLaunchKernelGGL(k_gemm, dim3(256, 6), dim3(256), 0, stream, ofl, qkv_w, qkv_b, qkvb, 384);
  hipLaunchKernelGGL(k_gemm, dim3(256, 2), dim3(256), 0, stream, sn, yv_w, yv_b, yvbuf, 128);
  hipLaunchKernelGGL(k_cvt, dim3(16, 16), dim3(256), 0, stream, qkvb, yvbuf, qkb, vtb);
  hipLaunchKernelGGL(k_attn, dim3(16, 4, 16), dim3(256), 0, stream, qkvb, qkb, vtb, attb);
  hipLaunchKernelGGL(k_proj, dim3(16, 16), dim3(256), 0, stream, attb, proj_w, proj_b, ori, xv2);
  hipLaunchKernelGGL(k_conv1d, dim3(64, 16), dim3(256), 30720, stream, xv2, cwt, xv3);
  hipLaunchKernelGGL(k_bilinear, dim3(73728), dim3(256), 0, stream, xv3, (float*)d_out);
}

// Round 10
// 470.880 us; speedup vs baseline: 1.2610x; 1.0077x over previous
//
#include <hip/hip_runtime.h>

#define FEAT 18432

typedef __attribute__((ext_vector_type(8))) short short8;
typedef __attribute__((ext_vector_type(4))) float f32x4;

__device__ __forceinline__ float b2f(unsigned short s) {
  union { unsigned int u; float f; } v; v.u = ((unsigned int)s) << 16; return v.f;
}
__device__ __forceinline__ unsigned short f2bf(float x) {
  union { float f; unsigned int u; } v; v.f = x;
  unsigned int u = v.u;
  unsigned int r = (u + 0x7FFFu + ((u >> 16) & 1u)) >> 16;
  return (unsigned short)r;
}

// async global->LDS, 16B per lane; LDS dest = base + lane*16 (wave-uniform base)
__device__ __forceinline__ void gl_lds16(const void* g, void* l) {
  __builtin_amdgcn_global_load_lds(
      (const __attribute__((address_space(1))) unsigned int*)g,
      (__attribute__((address_space(3))) unsigned int*)l, 16, 0, 0);
}

// K0: s1[b][c][96][96] (f32) -> xTn[b][f][ic] bf16, ic contiguous (128B rows),
// with 16B chunks swizzled within each row: pos = chunk ^ (f&7)  (f&7 == c&7).
__global__ __launch_bounds__(256) void k_transpose(const float* __restrict__ s1,
                                                   unsigned short* __restrict__ xT) {
  int c = blockIdx.x, b = blockIdx.y;
  __shared__ float lds[96 * 99];            // plane [h][w], pad 99
  int t = threadIdx.x;
  const float* src = s1 + ((size_t)b * 128 + c) * 9216;
  for (int idx = t; idx < 2304; idx += 256) {
    float4 v = ((const float4*)src)[idx];
    int h = idx / 24, w0 = (idx - h * 24) * 4;
    float* p = lds + h * 99 + w0;
    p[0] = v.x; p[1] = v.y; p[2] = v.z; p[3] = v.w;
  }
  __syncthreads();
  unsigned short* dstb = xT + (size_t)b * FEAT * 64;
  int sw = c & 7;
  for (int idx = t; idx < 1152; idx += 256) {
    int p1p2 = idx >> 3, gh = idx & 7;
    int p1 = p1p2 / 12, p2 = p1p2 - p1 * 12;
    const float* row = lds + (gh * 12 + p1) * 99 + p2;
    uint4 u;
    u.x = f2bf(row[0])  | ((unsigned int)f2bf(row[12]) << 16);
    u.y = f2bf(row[24]) | ((unsigned int)f2bf(row[36]) << 16);
    u.z = f2bf(row[48]) | ((unsigned int)f2bf(row[60]) << 16);
    u.w = f2bf(row[72]) | ((unsigned int)f2bf(row[84]) << 16);
    int f = p1p2 * 128 + c;
    int pos = gh ^ sw;
    *(uint4*)(dstb + (size_t)f * 64 + pos * 8) = u;
  }
}

// K_prep: pack pe_w -> wpk[oc][320] bf16 with chunk swizzle
__global__ __launch_bounds__(256) void k_prep(const float* __restrict__ pe_w,
                                              unsigned short* __restrict__ wpk) {
  int oc0 = blockIdx.x * 8;
  for (int e = threadIdx.x; e < 2560; e += 256) {
    int oc = oc0 + e / 320;
    int kL = e - (e / 320) * 320;
    int ic = kL & 63, kk = kL >> 6;
    float v = pe_w[(oc * 64 + ic) * 5 + kk];
    int LC = kL >> 3;
    int pos = (LC & 56) | ((LC & 7) ^ (oc & 7));
    wpk[oc * 320 + (pos << 3) + (kL & 7)] = f2bf(v);
  }
}

// K_prepc: transpose conv1d weights cw[oc][640] -> cwt[r640][oc] (oc contiguous)
__global__ __launch_bounds__(256) void k_prepc(const float* __restrict__ cw,
                                               float* __restrict__ cwt) {
  int e0 = (blockIdx.x * 256 + threadIdx.x) * 4;   // 80 blocks x 256 x 4 = 81920
#pragma unroll
  for (int j = 0; j < 4; ++j) {
    int e = e0 + j;
    int r = e >> 7, oc = e & 127;
    cwt[e] = cw[(size_t)oc * 640 + r];
  }
}

// K1 (MFMA): conv1d over f as GEMM M=64(oc) x N=18432(f) x K=320
// + BN(eval) + ReLU + selective square. Staging via global_load_lds (16B),
// swizzled LDS reads (conflict-free b128).
__global__ __launch_bounds__(256) void k_conv_pe(
    const unsigned short* __restrict__ xT, const unsigned short* __restrict__ wpk,
    const float* __restrict__ bn_g, const float* __restrict__ bn_b,
    const float* __restrict__ bn_m, const float* __restrict__ bn_v,
    const int* __restrict__ indexp, unsigned short* __restrict__ ym) {
  extern __shared__ char smem[];
  unsigned short* Wl = (unsigned short*)smem;            // 64*320*2 = 40960 B
  unsigned short* xl = (unsigned short*)(smem + 40960);  // 260*64*2 = 33280 B
  float* scf = (float*)(smem + 74240);
  float* shf = (float*)(smem + 74496);
  int*   sli = (int*)(smem + 74752);
  int t = threadIdx.x;
  int b = blockIdx.y;
  int blk_f0 = blockIdx.x << 9;
  int lane = t & 63, w = t >> 6;
  int n16 = lane & 15, q = lane >> 4;

  for (int j = 0; j < 10; ++j) {
    int seg = w * 10 + j;
    gl_lds16((const char*)wpk + (seg << 10) + lane * 16, (char*)Wl + (seg << 10));
  }
  if (t < 64) {
    float sc = bn_g[t] * rsqrtf(bn_v[t] + 1e-5f);
    scf[t] = sc;
    shf[t] = bn_b[t] - bn_m[t] * sc;
    int i0 = indexp[0] / 12 * 8 + indexp[1] / 12;
    int i1 = indexp[2] / 12 * 8 + indexp[3] / 12;
    int i2 = indexp[4] / 12 * 8 + indexp[5] / 12;
    int i3 = indexp[6] / 12 * 8 + indexp[7] / 12;
    sli[t] = (t == i0 || t == i1 || t == i2 || t == i3) ? 1 : 0;
  }

  const unsigned short* xb = xT + (size_t)b * FEAT * 64;
  const unsigned int* xbu = (const unsigned int*)xb;

  for (int wnd = 0; wnd < 2; ++wnd) {
    int F0 = blk_f0 + (wnd << 8);
    __syncthreads();
    int flA = (F0 == 0) ? 2 : 0;
    for (int j = 0; j < 8; ++j) {
      int seg = (w << 3) + j;
      int gRow = F0 - 2 + flA + (seg << 3);
      gl_lds16((const char*)xb + (size_t)gRow * 128 + lane * 16,
               (char*)xl + flA * 128 + (seg << 10));
    }
    if (t < 128) {
      int r0 = (flA == 2) ? 0 : 256;
      int fl = (t < 64) ? (r0 + (t >> 5)) : (258 + ((t >> 5) & 1));
      int j = t & 31;
      int f = F0 - 2 + fl;
      unsigned int v = 0;
      if (f >= 0 && f < FEAT) v = xbu[(size_t)f * 32 + j];
      ((unsigned int*)xl)[fl * 32 + j] = v;
    }
    __syncthreads();

    f32x4 acc[4][4];
#pragma unroll
    for (int mt = 0; mt < 4; ++mt)
#pragma unroll
      for (int nt = 0; nt < 4; ++nt) acc[mt][nt] = (f32x4){0.f, 0.f, 0.f, 0.f};

    int rowB = w * 64 + n16;
#pragma unroll
    for (int kk = 0; kk < 5; ++kk) {
      int swb = (n16 + kk + 6) & 7;
#pragma unroll
      for (int ih = 0; ih < 2; ++ih) {
        int ca = (ih << 2) | q;
        const unsigned short* Ap = Wl + kk * 64 + ((ca ^ (n16 & 7)) << 3) + n16 * 320;
        short8 a0 = *(const short8*)(Ap);
        short8 a1 = *(const short8*)(Ap + 16 * 320);
        short8 a2 = *(const short8*)(Ap + 32 * 320);
        short8 a3 = *(const short8*)(Ap + 48 * 320);
        const unsigned short* Bp = xl + ((ca ^ swb) << 3) + (rowB + kk) * 64;
        short8 b0 = *(const short8*)(Bp);
        short8 b1 = *(const short8*)(Bp + 16 * 64);
        short8 b2 = *(const short8*)(Bp + 32 * 64);
        short8 b3 = *(const short8*)(Bp + 48 * 64);
        acc[0][0] = __builtin_amdgcn_mfma_f32_16x16x32_bf16(a0, b0, acc[0][0], 0, 0, 0);
        acc[0][1] = __builtin_amdgcn_mfma_f32_16x16x32_bf16(a0, b1, acc[0][1], 0, 0, 0);
        acc[0][2] = __builtin_amdgcn_mfma_f32_16x16x32_bf16(a0, b2, acc[0][2], 0, 0, 0);
        acc[0][3] = __builtin_amdgcn_mfma_f32_16x16x32_bf16(a0, b3, acc[0][3], 0, 0, 0);
        acc[1][0] = __builtin_amdgcn_mfma_f32_16x16x32_bf16(a1, b0, acc[1][0], 0, 0, 0);
        acc[1][1] = __builtin_amdgcn_mfma_f32_16x16x32_bf16(a1, b1, acc[1][1], 0, 0, 0);
        acc[1][2] = __builtin_amdgcn_mfma_f32_16x16x32_bf16(a1, b2, acc[1][2], 0, 0, 0);
        acc[1][3] = __builtin_amdgcn_mfma_f32_16x16x32_bf16(a1, b3, acc[1][3], 0, 0, 0);
        acc[2][0] = __builtin_amdgcn_mfma_f32_16x16x32_bf16(a2, b0, acc[2][0], 0, 0, 0);
        acc[2][1] = __builtin_amdgcn_mfma_f32_16x16x32_bf16(a2, b1, acc[2][1], 0, 0, 0);
        acc[2][2] = __builtin_amdgcn_mfma_f32_16x16x32_bf16(a2, b2, acc[2][2], 0, 0, 0);
        acc[2][3] = __builtin_amdgcn_mfma_f32_16x16x32_bf16(a2, b3, acc[2][3], 0, 0, 0);
        acc[3][0] = __builtin_amdgcn_mfma_f32_16x16x32_bf16(a3, b0, acc[3][0], 0, 0, 0);
        acc[3][1] = __builtin_amdgcn_mfma_f32_16x16x32_bf16(a3, b1, acc[3][1], 0, 0, 0);
        acc[3][2] = __builtin_amdgcn_mfma_f32_16x16x32_bf16(a3, b2, acc[3][2], 0, 0, 0);
        acc[3][3] = __builtin_amdgcn_mfma_f32_16x16x32_bf16(a3, b3, acc[3][3], 0, 0, 0);
      }
    }

#pragma unroll
    for (int mt = 0; mt < 4; ++mt) {
#pragma unroll
      for (int i = 0; i < 4; ++i) {
        int oc = mt * 16 + q * 4 + i;
        float sc = scf[oc], sh = shf[oc];
        bool sel = sli[oc] != 0;
        unsigned short* yo = ym + ((size_t)b * 64 + oc) * FEAT + F0 + w * 64 + n16;
#pragma unroll
        for (int nt = 0; nt < 4; ++nt) {
          float y = fmaf(acc[mt][nt][i], sc, sh);
          y = fmaxf(y, 0.f);
          if (!sel) y *= y;
          yo[nt * 16] = f2bf(y);
        }
      }
    }
  }
}

// K2: 3x3 avg pool 96->32 + fused LayerNorm over C. Writes ori (raw pooled)
// and sn (LN'd). Each pass computes 2 full n-rows (128 c each across 2 waves);
// row mean/var via wave shuffle + cross-wave LDS combine (same math as old k_ln).
__global__ __launch_bounds__(256) void k_pool9ln(
    const unsigned short* __restrict__ ym, const float* __restrict__ lng,
    const float* __restrict__ lnb, float* __restrict__ ori, float* __restrict__ sn) {
  int oc = blockIdx.x, b = blockIdx.y;
  const unsigned short* src = ym + ((size_t)b * 64 + oc) * FEAT;
  int oh0 = (oc >> 3) << 2, ow0 = (oc & 7) << 2;
  __shared__ float red[8];
  int t = threadIdx.x;
  int c = t & 127, hr = t >> 7, wv = t >> 6, l64 = t & 63;
  float g = lng[c], bb = lnb[c];
  for (int p = 0; p < 8; ++p) {
    int nl = p * 2 + hr;
    int pg1 = nl >> 2, pg2 = nl & 3;
    int pbase = (pg1 * 36 + pg2 * 3) * 128 + c;
    float s = 0.f;
#pragma unroll
    for (int dy = 0; dy < 3; ++dy)
#pragma unroll
      for (int dx = 0; dx < 3; ++dx)
        s += b2f(src[pbase + (dy * 12 + dx) * 128]);
    float val = s * (1.f / 9.f);
    float su = val, q = val * val;
#pragma unroll
    for (int off = 32; off > 0; off >>= 1) {
      su += __shfl_xor(su, off, 64);
      q += __shfl_xor(q, off, 64);
    }
    if (l64 == 0) { red[wv * 2] = su; red[wv * 2 + 1] = q; }
    __syncthreads();
    float S = red[hr * 4 + 0] + red[hr * 4 + 2];
    float Q = red[hr * 4 + 1] + red[hr * 4 + 3];
    float mean = S * (1.f / 128.f);
    float var = Q * (1.f / 128.f) - mean * mean;
    float inv = rsqrtf(var + 1e-5f);
    int n = (oh0 + pg1) * 32 + ow0 + pg2;
    size_t base = ((size_t)b * 1024 + n) * 128 + c;
    ori[base] = val;
    sn[base] = (val - mean) * inv * g + bb;
    __syncthreads();   // red reuse next pass
  }
}

// K3: 2x2 avg pool of o (f32, 64->32) + LayerNorm over C -> ofl[b][n][c]
__global__ __launch_bounds__(256) void k_poolo_ln(
    const float* __restrict__ o, const float* __restrict__ lng,
    const float* __restrict__ lnb, float* __restrict__ ofl) {
  int y = blockIdx.x, b = blockIdx.y;
  __shared__ float pl[128 * 33];
  int t = threadIdx.x;
  for (int idx = t; idx < 4096; idx += 256) {
    int xo = idx & 31, c = idx >> 5;
    const float* p = o + (((size_t)b * 128 + c) * 64 + 2 * y) * 64 + 2 * xo;
    float2 a = *(const float2*)p;
    float2 d = *(const float2*)(p + 64);
    pl[c * 33 + xo] = 0.25f * (a.x + a.y + d.x + d.y);
  }
  __syncthreads();
  int xo = t >> 3, l8 = t & 7;
  float v[16]; float s = 0.f, q = 0.f;
#pragma unroll
  for (int i = 0; i < 16; ++i) {
    float x = pl[(l8 * 16 + i) * 33 + xo];
    v[i] = x; s += x; q += x * x;
  }
#pragma unroll
  for (int off = 1; off < 8; off <<= 1) {
    s += __shfl_xor(s, off, 8);
    q += __shfl_xor(q, off, 8);
  }
  float mean = s * (1.f / 128.f);
  float var = q * (1.f / 128.f) - mean * mean;
  float inv = rsqrtf(var + 1e-5f);
  float* dst = ofl + ((size_t)b * 1024 + y * 32 + xo) * 128 + l8 * 16;
#pragma unroll
  for (int i = 0; i < 16; ++i)
    dst[i] = (v[i] - mean) * inv * lng[l8 * 16 + i] + lnb[l8 * 16 + i];
}

// K5: out[M][Ncols] = A[M][128] @ W[Ncols][128]^T + bias
__global__ __launch_bounds__(256) void k_gemm(
    const float* __restrict__ A, const float* __restrict__ W,
    const float* __restrict__ bias, float* __restrict__ out, int Ncols) {
  int mt = blockIdx.x, ct = blockIdx.y;
  int m0 = mt << 6, c0 = ct << 6;
  __shared__ float Al[64 * 67], Wl[64 * 67];
  int t = threadIdx.x, tm = t & 15, tc = t >> 4;
  float acc[4][4];
#pragma unroll
  for (int i = 0; i < 4; ++i)
#pragma unroll
    for (int j = 0; j < 4; ++j) acc[i][j] = 0.f;
  for (int kc = 0; kc < 2; ++kc) {
    __syncthreads();
    for (int idx = t; idx < 4096; idx += 256) {
      int r = idx >> 6, kk = idx & 63;
      Al[r * 67 + kk] = A[(size_t)(m0 + r) * 128 + kc * 64 + kk];
      Wl[r * 67 + kk] = W[(size_t)(c0 + r) * 128 + kc * 64 + kk];
    }
    __syncthreads();
    for (int kk = 0; kk < 64; ++kk) {
      float a[4], w[4];
#pragma unroll
      for (int i = 0; i < 4; ++i) a[i] = Al[(tm * 4 + i) * 67 + kk];
#pragma unroll
      for (int j = 0; j < 4; ++j) w[j] = Wl[(tc * 4 + j) * 67 + kk];
#pragma unroll
      for (int i = 0; i < 4; ++i)
#pragma unroll
        for (int j = 0; j < 4; ++j) acc[i][j] = fmaf(a[i], w[j], acc[i][j]);
    }
  }
#pragma unroll
  for (int i = 0; i < 4; ++i) {
    float4 vv;
    vv.x = acc[i][0] + bias[c0 + tc * 4 + 0];
    vv.y = acc[i][1] + bias[c0 + tc * 4 + 1];
    vv.z = acc[i][2] + bias[c0 + tc * 4 + 2];
    vv.w = acc[i][3] + bias[c0 + tc * 4 + 3];
    *(float4*)(out + (size_t)(m0 + tm * 4 + i) * Ncols + c0 + tc * 4) = vv;
  }
}

// K_cvt: qkvb f32 [b][1024][384] -> qkb bf16 [b][h][{q,k}][1024][32];
//        yvbuf f32 [b][1024][128] -> vtb bf16 [b][h][32][1024] (V transposed).
__global__ __launch_bounds__(256) void k_cvt(const float* __restrict__ qkv,
                                             const float* __restrict__ yv,
                                             unsigned short* __restrict__ qkb,
                                             unsigned short* __restrict__ vtb) {
  int nt = blockIdx.x, b = blockIdx.y;   // 64 n per block
  int n0 = nt << 6;
  int t = threadIdx.x;
  __shared__ unsigned short tl[64 * 132];
  const float* qb = qkv + ((size_t)b * 1024 + n0) * 384;
  for (int it = 0; it < 16; ++it) {
    int idx = it * 256 + t;
    int n = idx >> 6, c4 = idx & 63;     // c = c4*4 in [0,256)
    float4 v = *(const float4*)(qb + (size_t)n * 384 + c4 * 4);
    int c = c4 << 2;
    int kind = c >> 7, h = (c >> 5) & 3, d = c & 31;
    uint2 u;
    u.x = (unsigned int)f2bf(v.x) | ((unsigned int)f2bf(v.y) << 16);
    u.y = (unsigned int)f2bf(v.z) | ((unsigned int)f2bf(v.w) << 16);
    *(uint2*)(qkb + ((((size_t)b * 4 + h) * 2 + kind) * 1024 + n0 + n) * 32 + d) = u;
  }
  const float* vb = yv + ((size_t)b * 1024 + n0) * 128;
  for (int it = 0; it < 8; ++it) {
    int idx = it * 256 + t;
    int n = idx >> 5, c4 = idx & 31;
    float4 v = *(const float4*)(vb + (size_t)n * 128 + c4 * 4);
    unsigned short* o = tl + n * 132 + c4 * 4;
    o[0] = f2bf(v.x); o[1] = f2bf(v.y); o[2] = f2bf(v.z); o[3] = f2bf(v.w);
  }
  __syncthreads();
  int c = t >> 1, half = t & 1;          // c = h*32+d in [0,128)
  unsigned short* orow = vtb + (((size_t)b * 4 + (c >> 5)) * 32 + (c & 31)) * 1024 + n0 + half * 32;
#pragma unroll
  for (int k = 0; k < 4; ++k) {
    short8 pack;
#pragma unroll
    for (int j = 0; j < 8; ++j)
      pack[j] = (short)tl[(half * 32 + k * 8 + j) * 132 + c];
    *(short8*)(orow + k * 8) = pack;
  }
}

// K6 (MFMA): flash attention. v4: swapped QK^T (S = mfma(K,Q)) puts a full
// q-row's scores lane-local -> softmax reduce = VALU tree + 2 shfl; P write =
// 4x b64. P layout & PV path unchanged.
__global__ __launch_bounds__(256) void k_attn(const float* __restrict__ qkv,
                                              const unsigned short* __restrict__ qkb,
                                              const unsigned short* __restrict__ vtb,
                                              float* __restrict__ att) {
  int qt = blockIdx.x, h = blockIdx.y, b = blockIdx.z;
  __shared__ unsigned short Qs[64 * 40];
  __shared__ unsigned short Ks[64 * 40];
  __shared__ unsigned short Vt[32 * 72];
  __shared__ unsigned short Pw[4 * 16 * 68];  // per-wave [q16][key64], stride 68
  int t = threadIdx.x;
  int lane = t & 63, w = t >> 6;
  int quad = lane >> 4, l16 = lane & 15;
  const float* qbase = qkv + (size_t)b * 1024 * 384;   // epilogue v residual (f32)
  const unsigned short* qrow = qkb + (((size_t)b * 4 + h) * 2 + 0) * 1024 * 32;
  const unsigned short* krow = qkb + (((size_t)b * 4 + h) * 2 + 1) * 1024 * 32;
  const unsigned short* vrow = vtb + ((size_t)b * 4 + h) * 32 * 1024;
  int q0 = qt << 6;
  int hd = h * 32;

  {
    int r = t >> 2, cq = t & 3;
    short8 v = *(const short8*)(qrow + (size_t)(q0 + r) * 32 + cq * 8);
    *(short8*)(Qs + r * 40 + cq * 8) = v;
  }
  __syncthreads();
  short8 aq = *(const short8*)(Qs + (w * 16 + l16) * 40 + quad * 8);

  f32x4 O[2];
  O[0] = (f32x4){0.f, 0.f, 0.f, 0.f};
  O[1] = (f32x4){0.f, 0.f, 0.f, 0.f};
  float mi0 = -1e30f, li0 = 0.f;       // per-lane, q = l16 (uniform across quads)
  unsigned short* Pme = Pw + w * (16 * 68);
  const float scl = 0.17677669529663688f;

  for (int ci = 0; ci < 16; ++ci) {
    __syncthreads();
    int kn0 = ci << 6;
    {
      int r = t >> 2, cq = t & 3;
      short8 kv = *(const short8*)(krow + (size_t)(kn0 + r) * 32 + cq * 8);
      *(short8*)(Ks + r * 40 + cq * 8) = kv;
      int d = t >> 3, cc = t & 7;
      short8 vv = *(const short8*)(vrow + (size_t)d * 1024 + kn0 + cc * 8);
      *(short8*)(Vt + d * 72 + cc * 8) = vv;
    }
    __syncthreads();

    // swapped: S[nt] row = key(quad*4+reg), col = q(l16)
    f32x4 S[4];
#pragma unroll
    for (int nt = 0; nt < 4; ++nt) S[nt] = (f32x4){0.f, 0.f, 0.f, 0.f};
#pragma unroll
    for (int nt = 0; nt < 4; ++nt) {
      short8 bk = *(const short8*)(Ks + (nt * 16 + l16) * 40 + quad * 8);
      S[nt] = __builtin_amdgcn_mfma_f32_16x16x32_bf16(bk, aq, S[nt], 0, 0, 0);
    }

    // lane-local 16 scores of q-row l16: key = nt*16 + quad*4 + reg
    float sv[16];
#pragma unroll
    for (int nt = 0; nt < 4; ++nt)
#pragma unroll
      for (int r = 0; r < 4; ++r) sv[nt * 4 + r] = S[nt][r] * scl;
    float m0 = fmaxf(fmaxf(sv[0], sv[1]), fmaxf(sv[2], sv[3]));
    float m1 = fmaxf(fmaxf(sv[4], sv[5]), fmaxf(sv[6], sv[7]));
    float m2 = fmaxf(fmaxf(sv[8], sv[9]), fmaxf(sv[10], sv[11]));
    float m3 = fmaxf(fmaxf(sv[12], sv[13]), fmaxf(sv[14], sv[15]));
    float rm = fmaxf(fmaxf(m0, m1), fmaxf(m2, m3));
    rm = fmaxf(rm, __shfl_xor(rm, 16));
    rm = fmaxf(rm, __shfl_xor(rm, 32));
    float nm = fmaxf(mi0, rm);
    float alpha = __expf(mi0 - nm);
    mi0 = nm;

    float psnt[4];
    unsigned short* pwr = Pme + l16 * 68 + quad * 4;
#pragma unroll
    for (int nt = 0; nt < 4; ++nt) {
      float p0 = __expf(sv[nt * 4 + 0] - nm);
      float p1 = __expf(sv[nt * 4 + 1] - nm);
      float p2 = __expf(sv[nt * 4 + 2] - nm);
      float p3 = __expf(sv[nt * 4 + 3] - nm);
      psnt[nt] = (p0 + p1) + (p2 + p3);
      uint2 u;
      u.x = (unsigned int)f2bf(p0) | ((unsigned int)f2bf(p1) << 16);
      u.y = (unsigned int)f2bf(p2) | ((unsigned int)f2bf(p3) << 16);
      *(uint2*)(pwr + nt * 16) = u;
    }
    float ps = (psnt[0] + psnt[1]) + (psnt[2] + psnt[3]);
    ps += __shfl_xor(ps, 16);
    ps += __shfl_xor(ps, 32);
    li0 = li0 * alpha + ps;

    // transpose alpha from q=l16 domain to q=quad*4+reg (O row domain)
    float al0 = __shfl(alpha, quad * 4 + 0);
    float al1 = __shfl(alpha, quad * 4 + 1);
    float al2 = __shfl(alpha, quad * 4 + 2);
    float al3 = __shfl(alpha, quad * 4 + 3);
    O[0][0] *= al0; O[1][0] *= al0;
    O[0][1] *= al1; O[1][1] *= al1;
    O[0][2] *= al2; O[1][2] *= al2;
    O[0][3] *= al3; O[1][3] *= al3;

#pragma unroll
    for (int kc = 0; kc < 2; ++kc) {
      short8 bv0 = *(const short8*)(Vt + l16 * 72 + kc * 32 + quad * 8);
      short8 bv1 = *(const short8*)(Vt + (16 + l16) * 72 + kc * 32 + quad * 8);
      short8 ap = *(const short8*)(Pme + l16 * 68 + kc * 32 + quad * 8);
      O[0] = __builtin_amdgcn_mfma_f32_16x16x32_bf16(ap, bv0, O[0], 0, 0, 0);
      O[1] = __builtin_amdgcn_mfma_f32_16x16x32_bf16(ap, bv1, O[1], 0, 0, 0);
    }
  }

#pragma unroll
  for (int reg = 0; reg < 4; ++reg) {
    float lit = __shfl(li0, quad * 4 + reg);
    int n = q0 + w * 16 + quad * 4 + reg;
    float inv = 1.f / lit;
#pragma unroll
    for (int nt = 0; nt < 2; ++nt) {
      int dd = hd + nt * 16 + l16;
      float val = O[nt][reg] * inv + qbase[(size_t)n * 384 + 256 + dd];
      att[((size_t)b * 1024 + n) * 128 + dd] = val;
    }
  }
}

// K7: proj GEMM + bias + ori residual, write transposed xv2[b][c][n]
__global__ __launch_bounds__(256) void k_proj(
    const float* __restrict__ att, const float* __restrict__ proj_w,
    const float* __restrict__ proj_b, const float* __restrict__ ori,
    float* __restrict__ xv2) {
  int nt = blockIdx.x, b = blockIdx.y;
  int n0 = nt << 6;
  __shared__ float Al[64 * 67], Wl[128 * 67];
  int t = threadIdx.x, tn = t & 15, tc = t >> 4;
  float acc[4][8];
#pragma unroll
  for (int i = 0; i < 4; ++i)
#pragma unroll
    for (int j = 0; j < 8; ++j) acc[i][j] = 0.f;
  const float* Ab = att + ((size_t)b * 1024 + n0) * 128;
  for (int kc = 0; kc < 2; ++kc) {
    __syncthreads();
    for (int idx = t; idx < 4096; idx += 256) {
      int r = idx >> 6, kk = idx & 63;
      Al[r * 67 + kk] = Ab[(size_t)r * 128 + kc * 64 + kk];
    }
    for (int idx = t; idx < 8192; idx += 256) {
      int r = idx >> 6, kk = idx & 63;
      Wl[r * 67 + kk] = proj_w[(size_t)r * 128 + kc * 64 + kk];
    }
    __syncthreads();
    for (int kk = 0; kk < 64; ++kk) {
      float a[4], w[8];
#pragma unroll
      for (int i = 0; i < 4; ++i) a[i] = Al[(tn * 4 + i) * 67 + kk];
#pragma unroll
      for (int j = 0; j < 8; ++j) w[j] = Wl[(tc * 8 + j) * 67 + kk];
#pragma unroll
      for (int i = 0; i < 4; ++i)
#pragma unroll
        for (int j = 0; j < 8; ++j) acc[i][j] = fmaf(a[i], w[j], acc[i][j]);
    }
  }
#pragma unroll
  for (int j = 0; j < 8; ++j) {
    int c = tc * 8 + j;
    float pb = proj_b[c];
    float4 vv;
    vv.x = acc[0][j] + pb + ori[((size_t)b * 1024 + n0 + tn * 4 + 0) * 128 + c];
    vv.y = acc[1][j] + pb + ori[((size_t)b * 1024 + n0 + tn * 4 + 1) * 128 + c];
    vv.z = acc[2][j] + pb + ori[((size_t)b * 1024 + n0 + tn * 4 + 2) * 128 + c];
    vv.w = acc[3][j] + pb + ori[((size_t)b * 1024 + n0 + tn * 4 + 3) * 128 + c];
    *(float4*)(xv2 + ((size_t)b * 128 + c) * 1024 + n0 + tn * 4) = vv;
  }
}

// K8: conv1d over n (128->128 channels, K=5, pad=2) + residual.
// v7: NB=32 (weight-read amortization 2x) + double-buffered LDS weights with
// stage-after-barrier (next chunk's global_load_lds issues right after the
// barrier and lands under the current chunk's compute -> drain hidden).
__global__ __launch_bounds__(256) void k_conv1d(
    const float* __restrict__ xv2, const float* __restrict__ cwt,
    float* __restrict__ xv3) {
  extern __shared__ char cs[];
  float* xl  = (float*)cs;                  // [128][36], 18432 B
  float* wlA = (float*)(cs + 18432);        // [40][128], 20480 B
  float* wlB = (float*)(cs + 38912);        // [40][128], 20480 B
  int nt = blockIdx.x, b = blockIdx.y;
  int n0 = nt << 5;                         // 32 n per block
  int t = threadIdx.x;
  int lane = t & 63, w = t >> 6;
  const float* xb = xv2 + (size_t)b * 128 * 1024;
  for (int idx = t; idx < 4608; idx += 256) {
    int ic = idx / 36, j = idx - ic * 36;
    int n = n0 + j - 2;
    xl[idx] = (n >= 0 && n < 1024) ? xb[(size_t)ic * 1024 + n] : 0.f;
  }

#define STAGEW(DST, CH) do { \
  _Pragma("unroll") \
  for (int j = 0; j < 5; ++j) { \
    int seg = w * 5 + j; \
    gl_lds16((const char*)cwt + (size_t)(CH) * 20480 + (seg << 10) + lane * 16, \
             (char*)(DST) + (seg << 10)); \
  } } while (0)

  STAGEW(wlA, 0);

  int oc = t & 127, g = t >> 7;             // g in {0,1}: n-half (16 each)
  float acc[16];
#pragma unroll
  for (int i = 0; i < 16; ++i) acc[i] = 0.f;

#pragma unroll 1
  for (int ch = 0; ch < 16; ++ch) {
    __syncthreads();                        // drains stage -> cur ready (xl too at ch=0)
    const float* wl = (ch & 1) ? wlB : wlA;
    if (ch < 15) {
      float* nb = (ch & 1) ? wlA : wlB;
      STAGEW(nb, ch + 1);                   // lands under this chunk's compute
    }
#pragma unroll
    for (int icl = 0; icl < 8; ++icl) {
      int ic = ch * 8 + icl;
      const float* xr = xl + ic * 36 + (g << 4);   // wave-uniform, 16B aligned
      float xw[20];
#pragma unroll
      for (int q2 = 0; q2 < 5; ++q2) {
        float4 v = *(const float4*)(xr + q2 * 4);
        xw[q2 * 4] = v.x; xw[q2 * 4 + 1] = v.y; xw[q2 * 4 + 2] = v.z; xw[q2 * 4 + 3] = v.w;
      }
      const float* wr = wl + icl * 5 * 128 + oc;   // lanes consecutive oc: conflict-free
      float w0 = wr[0], w1 = wr[128], w2 = wr[256], w3 = wr[384], w4 = wr[512];
#pragma unroll
      for (int i = 0; i < 16; ++i)
        acc[i] = fmaf(xw[i], w0, fmaf(xw[i + 1], w1, fmaf(xw[i + 2], w2,
                 fmaf(xw[i + 3], w3, fmaf(xw[i + 4], w4, acc[i])))));
    }
  }
#undef STAGEW

  const float* res = xb + (size_t)oc * 1024 + n0 + (g << 4);
  float* outp = xv3 + ((size_t)b * 128 + oc) * 1024 + n0 + (g << 4);
#pragma unroll
  for (int q2 = 0; q2 < 4; ++q2) {
    float4 r = *(const float4*)(res + q2 * 4);
    float4 o_;
    o_.x = r.x + acc[q2 * 4 + 0];
    o_.y = r.y + acc[q2 * 4 + 1];
    o_.z = r.z + acc[q2 * 4 + 2];
    o_.w = r.w + acc[q2 * 4 + 3];
    *(float4*)(outp + q2 * 4) = o_;
  }
}

// K9: bilinear 32->96 align_corners=True, f32 out
__global__ __launch_bounds__(256) void k_bilinear(const float* __restrict__ xv3,
                                                  float* __restrict__ out) {
  int idx = blockIdx.x * 256 + threadIdx.x;
  int X = idx % 96;
  int t2 = idx / 96;
  int Y = t2 % 96;
  int bc = t2 / 96;
  const float* src = xv3 + (size_t)bc * 1024;
  const float r = 31.f / 95.f;
  float py = Y * r, px = X * r;
  int y0 = (int)py, x0 = (int)px;
  float wy = py - y0, wx = px - x0;
  int y1 = y0 < 31 ? y0 + 1 : 31, x1 = x0 < 31 ? x0 + 1 : 31;
  float a = src[y0 * 32 + x0], b_ = src[y0 * 32 + x1];
  float c_ = src[y1 * 32 + x0], d_ = src[y1 * 32 + x1];
  float t0 = a * (1.f - wy) + c_ * wy;
  float t1 = b_ * (1.f - wy) + d_ * wy;
  out[idx] = t0 * (1.f - wx) + t1 * wx;
}

extern "C" void kernel_launch(void* const* d_in, const int* in_sizes, int n_in,
                              void* d_out, int out_size, void* d_ws, size_t ws_size,
                              hipStream_t stream) {
  (void)in_sizes; (void)n_in; (void)out_size; (void)ws_size;
  const float* s1    = (const float*)d_in[0];
  const float* o     = (const float*)d_in[1];
  const int*   indx  = (const int*)d_in[2];
  const float* pe_w  = (const float*)d_in[3];
  const float* bn_g  = (const float*)d_in[4];
  const float* bn_b  = (const float*)d_in[5];
  const float* bn_m  = (const float*)d_in[6];
  const float* bn_v  = (const float*)d_in[7];
  const float* lnx_g = (const float*)d_in[8];
  const float* lnx_b = (const float*)d_in[9];
  const float* lny_g = (const float*)d_in[10];
  const float* lny_b = (const float*)d_in[11];
  const float* qkv_w = (const float*)d_in[12];
  const float* qkv_b = (const float*)d_in[13];
  const float* yv_w  = (const float*)d_in[14];
  const float* yv_b  = (const float*)d_in[15];
  const float* proj_w = (const float*)d_in[16];
  const float* proj_b = (const float*)d_in[17];
  const float* c1d_w  = (const float*)d_in[18];

  char* ws = (char*)d_ws;
  // Phase 1: xTn bf16 [ws+0, 37.7MB) [f][ic] swizzled, ymh bf16 [ws+37.7MB, 75.5MB).
  unsigned short* xTh = (unsigned short*)ws;
  unsigned short* ymh = (unsigned short*)(ws + 37748736);
  // d_out scratch (overwritten only by k_bilinear at the very end):
  //   wpk  (41KB packed conv_pe weights) at +0
  //   cwt  (328KB transposed conv1d weights) at +64KB
  unsigned short* wpk = (unsigned short*)d_out;
  float* cwt = (float*)((char*)d_out + 65536);
  // Phase 2 (xTh dead after k_conv_pe): region A = [ws+0, 37.7MB)
  float* ori  = (float*)ws;                 // [0, 8.4MB)
  float* sn   = (float*)(ws + 8388608);     // dead after yv gemm
  float* ofl  = (float*)(ws + 16777216);    // dead after qkv gemm
  float* attb = (float*)(ws + 25165824);    // [25.2MB, 33.6MB)
  // Phase 3 (ymh dead after k_pool9ln): region B = [ws+37.7MB, 75.5MB)
  float* qkvb  = (float*)(ws + 37748736);   // 25.2MB
  float* yvbuf = (float*)(ws + 62914560);   // 8.4MB, dead after k_cvt
  // bf16 attn operands:
  unsigned short* qkb = (unsigned short*)(ws + 16777216);  // alias ofl, 8.4MB
  unsigned short* vtb = (unsigned short*)(ws + 71303168);  // tail, 4.2MB
  float* xv2   = (float*)(ws + 37748736);   // alias qkvb (dead after k_attn)
  float* xv3   = (float*)(ws + 46137344);

  hipLaunchKernelGGL(k_prep, dim3(8), dim3(256), 0, stream, pe_w, wpk);
  hipLaunchKernelGGL(k_prepc, dim3(80), dim3(256), 0, stream, c1d_w, cwt);
  hipLaunchKernelGGL(k_transpose, dim3(128, 16), dim3(256), 0, stream, s1, xTh);
  hipLaunchKernelGGL(k_conv_pe, dim3(36, 16), dim3(256), 75008, stream,
                     xTh, wpk, bn_g, bn_b, bn_m, bn_v, indx, ymh);
  hipLaunchKernelGGL(k_pool9ln, dim3(64, 16), dim3(256), 0, stream, ymh, lny_g, lny_b, ori, sn);
  hipLaunchKernelGGL(k_poolo_ln, dim3(32, 16), dim3(256), 0, stream, o, lnx_g, lnx_b, ofl);
  hipLaunchKernelGGL(k_gemm, dim3(256, 6), dim3(256), 0, stream, ofl, qkv_w, qkv_b, qkvb, 384);
  hipLaunchKernelGGL(k_gemm, dim3(256, 2), dim3(256), 0, stream, sn, yv_w, yv_b, yvbuf, 128);
  hipLaunchKernelGGL(k_cvt, dim3(16, 16), dim3(256), 0, stream, qkvb, yvbuf, qkb, vtb);
  hipLaunchKernelGGL(k_attn, dim3(16, 4, 16), dim3(256), 0, stream, qkvb, qkb, vtb, attb);
  hipLaunchKernelGGL(k_proj, dim3(16, 16), dim3(256), 0, stream, attb, proj_w, proj_b, ori, xv2);
  hipLaunchKernelGGL(k_conv1d, dim3(32, 16), dim3(256), 59392, stream, xv2, cwt, xv3);
  hipLaunchKernelGGL(k_bilinear, dim3(73728), dim3(256), 0, stream, xv3, (float*)d_out);
}

// Round 12
// 468.156 us; speedup vs baseline: 1.2683x; 1.0058x over previous
//
#include <hip/hip_runtime.h>

#define FEAT 18432

typedef __attribute__((ext_vector_type(8))) short short8;
typedef __attribute__((ext_vector_type(4))) float f32x4;

__device__ __forceinline__ float b2f(unsigned short s) {
  union { unsigned int u; float f; } v; v.u = ((unsigned int)s) << 16; return v.f;
}
__device__ __forceinline__ unsigned short f2bf(float x) {
  union { float f; unsigned int u; } v; v.f = x;
  unsigned int u = v.u;
  unsigned int r = (u + 0x7FFFu + ((u >> 16) & 1u)) >> 16;
  return (unsigned short)r;
}

// async global->LDS, 16B per lane; LDS dest = base + lane*16 (wave-uniform base)
__device__ __forceinline__ void gl_lds16(const void* g, void* l) {
  __builtin_amdgcn_global_load_lds(
      (const __attribute__((address_space(1))) unsigned int*)g,
      (__attribute__((address_space(3))) unsigned int*)l, 16, 0, 0);
}

// K0: s1[b][c][96][96] (f32) -> xTn[b][f][ic] bf16, ic contiguous (128B rows),
// with 16B chunks swizzled within each row: pos = chunk ^ (f&7)  (f&7 == c&7).
__global__ __launch_bounds__(256) void k_transpose(const float* __restrict__ s1,
                                                   unsigned short* __restrict__ xT) {
  int c = blockIdx.x, b = blockIdx.y;
  __shared__ float lds[96 * 99];            // plane [h][w], pad 99
  int t = threadIdx.x;
  const float* src = s1 + ((size_t)b * 128 + c) * 9216;
  for (int idx = t; idx < 2304; idx += 256) {
    float4 v = ((const float4*)src)[idx];
    int h = idx / 24, w0 = (idx - h * 24) * 4;
    float* p = lds + h * 99 + w0;
    p[0] = v.x; p[1] = v.y; p[2] = v.z; p[3] = v.w;
  }
  __syncthreads();
  unsigned short* dstb = xT + (size_t)b * FEAT * 64;
  int sw = c & 7;
  for (int idx = t; idx < 1152; idx += 256) {
    int p1p2 = idx >> 3, gh = idx & 7;
    int p1 = p1p2 / 12, p2 = p1p2 - p1 * 12;
    const float* row = lds + (gh * 12 + p1) * 99 + p2;
    uint4 u;
    u.x = f2bf(row[0])  | ((unsigned int)f2bf(row[12]) << 16);
    u.y = f2bf(row[24]) | ((unsigned int)f2bf(row[36]) << 16);
    u.z = f2bf(row[48]) | ((unsigned int)f2bf(row[60]) << 16);
    u.w = f2bf(row[72]) | ((unsigned int)f2bf(row[84]) << 16);
    int f = p1p2 * 128 + c;
    int pos = gh ^ sw;
    *(uint4*)(dstb + (size_t)f * 64 + pos * 8) = u;
  }
}

// K_prep: pack pe_w -> wpk[oc][320] bf16 with chunk swizzle
__global__ __launch_bounds__(256) void k_prep(const float* __restrict__ pe_w,
                                              unsigned short* __restrict__ wpk) {
  int oc0 = blockIdx.x * 8;
  for (int e = threadIdx.x; e < 2560; e += 256) {
    int oc = oc0 + e / 320;
    int kL = e - (e / 320) * 320;
    int ic = kL & 63, kk = kL >> 6;
    float v = pe_w[(oc * 64 + ic) * 5 + kk];
    int LC = kL >> 3;
    int pos = (LC & 56) | ((LC & 7) ^ (oc & 7));
    wpk[oc * 320 + (pos << 3) + (kL & 7)] = f2bf(v);
  }
}

// K_prepc: transpose conv1d weights cw[oc][640] -> cwt[r640][oc] (oc contiguous)
__global__ __launch_bounds__(256) void k_prepc(const float* __restrict__ cw,
                                               float* __restrict__ cwt) {
  int e0 = (blockIdx.x * 256 + threadIdx.x) * 4;   // 80 blocks x 256 x 4 = 81920
#pragma unroll
  for (int j = 0; j < 4; ++j) {
    int e = e0 + j;
    int r = e >> 7, oc = e & 127;
    cwt[e] = cw[(size_t)oc * 640 + r];
  }
}

// K1 (MFMA): conv1d over f as GEMM M=64(oc) x N=18432(f) x K=320
// + BN(eval) + ReLU + selective square. Staging via global_load_lds (16B),
// swizzled LDS reads (conflict-free b128).
__global__ __launch_bounds__(256) void k_conv_pe(
    const unsigned short* __restrict__ xT, const unsigned short* __restrict__ wpk,
    const float* __restrict__ bn_g, const float* __restrict__ bn_b,
    const float* __restrict__ bn_m, const float* __restrict__ bn_v,
    const int* __restrict__ indexp, unsigned short* __restrict__ ym) {
  extern __shared__ char smem[];
  unsigned short* Wl = (unsigned short*)smem;            // 64*320*2 = 40960 B
  unsigned short* xl = (unsigned short*)(smem + 40960);  // 260*64*2 = 33280 B
  float* scf = (float*)(smem + 74240);
  float* shf = (float*)(smem + 74496);
  int*   sli = (int*)(smem + 74752);
  int t = threadIdx.x;
  int b = blockIdx.y;
  int blk_f0 = blockIdx.x << 9;
  int lane = t & 63, w = t >> 6;
  int n16 = lane & 15, q = lane >> 4;

  for (int j = 0; j < 10; ++j) {
    int seg = w * 10 + j;
    gl_lds16((const char*)wpk + (seg << 10) + lane * 16, (char*)Wl + (seg << 10));
  }
  if (t < 64) {
    float sc = bn_g[t] * rsqrtf(bn_v[t] + 1e-5f);
    scf[t] = sc;
    shf[t] = bn_b[t] - bn_m[t] * sc;
    int i0 = indexp[0] / 12 * 8 + indexp[1] / 12;
    int i1 = indexp[2] / 12 * 8 + indexp[3] / 12;
    int i2 = indexp[4] / 12 * 8 + indexp[5] / 12;
    int i3 = indexp[6] / 12 * 8 + indexp[7] / 12;
    sli[t] = (t == i0 || t == i1 || t == i2 || t == i3) ? 1 : 0;
  }

  const unsigned short* xb = xT + (size_t)b * FEAT * 64;
  const unsigned int* xbu = (const unsigned int*)xb;

  for (int wnd = 0; wnd < 2; ++wnd) {
    int F0 = blk_f0 + (wnd << 8);
    __syncthreads();
    int flA = (F0 == 0) ? 2 : 0;
    for (int j = 0; j < 8; ++j) {
      int seg = (w << 3) + j;
      int gRow = F0 - 2 + flA + (seg << 3);
      gl_lds16((const char*)xb + (size_t)gRow * 128 + lane * 16,
               (char*)xl + flA * 128 + (seg << 10));
    }
    if (t < 128) {
      int r0 = (flA == 2) ? 0 : 256;
      int fl = (t < 64) ? (r0 + (t >> 5)) : (258 + ((t >> 5) & 1));
      int j = t & 31;
      int f = F0 - 2 + fl;
      unsigned int v = 0;
      if (f >= 0 && f < FEAT) v = xbu[(size_t)f * 32 + j];
      ((unsigned int*)xl)[fl * 32 + j] = v;
    }
    __syncthreads();

    f32x4 acc[4][4];
#pragma unroll
    for (int mt = 0; mt < 4; ++mt)
#pragma unroll
      for (int nt = 0; nt < 4; ++nt) acc[mt][nt] = (f32x4){0.f, 0.f, 0.f, 0.f};

    int rowB = w * 64 + n16;
#pragma unroll
    for (int kk = 0; kk < 5; ++kk) {
      int swb = (n16 + kk + 6) & 7;
#pragma unroll
      for (int ih = 0; ih < 2; ++ih) {
        int ca = (ih << 2) | q;
        const unsigned short* Ap = Wl + kk * 64 + ((ca ^ (n16 & 7)) << 3) + n16 * 320;
        short8 a0 = *(const short8*)(Ap);
        short8 a1 = *(const short8*)(Ap + 16 * 320);
        short8 a2 = *(const short8*)(Ap + 32 * 320);
        short8 a3 = *(const short8*)(Ap + 48 * 320);
        const unsigned short* Bp = xl + ((ca ^ swb) << 3) + (rowB + kk) * 64;
        short8 b0 = *(const short8*)(Bp);
        short8 b1 = *(const short8*)(Bp + 16 * 64);
        short8 b2 = *(const short8*)(Bp + 32 * 64);
        short8 b3 = *(const short8*)(Bp + 48 * 64);
        acc[0][0] = __builtin_amdgcn_mfma_f32_16x16x32_bf16(a0, b0, acc[0][0], 0, 0, 0);
        acc[0][1] = __builtin_amdgcn_mfma_f32_16x16x32_bf16(a0, b1, acc[0][1], 0, 0, 0);
        acc[0][2] = __builtin_amdgcn_mfma_f32_16x16x32_bf16(a0, b2, acc[0][2], 0, 0, 0);
        acc[0][3] = __builtin_amdgcn_mfma_f32_16x16x32_bf16(a0, b3, acc[0][3], 0, 0, 0);
        acc[1][0] = __builtin_amdgcn_mfma_f32_16x16x32_bf16(a1, b0, acc[1][0], 0, 0, 0);
        acc[1][1] = __builtin_amdgcn_mfma_f32_16x16x32_bf16(a1, b1, acc[1][1], 0, 0, 0);
        acc[1][2] = __builtin_amdgcn_mfma_f32_16x16x32_bf16(a1, b2, acc[1][2], 0, 0, 0);
        acc[1][3] = __builtin_amdgcn_mfma_f32_16x16x32_bf16(a1, b3, acc[1][3], 0, 0, 0);
        acc[2][0] = __builtin_amdgcn_mfma_f32_16x16x32_bf16(a2, b0, acc[2][0], 0, 0, 0);
        acc[2][1] = __builtin_amdgcn_mfma_f32_16x16x32_bf16(a2, b1, acc[2][1], 0, 0, 0);
        acc[2][2] = __builtin_amdgcn_mfma_f32_16x16x32_bf16(a2, b2, acc[2][2], 0, 0, 0);
        acc[2][3] = __builtin_amdgcn_mfma_f32_16x16x32_bf16(a2, b3, acc[2][3], 0, 0, 0);
        acc[3][0] = __builtin_amdgcn_mfma_f32_16x16x32_bf16(a3, b0, acc[3][0], 0, 0, 0);
        acc[3][1] = __builtin_amdgcn_mfma_f32_16x16x32_bf16(a3, b1, acc[3][1], 0, 0, 0);
        acc[3][2] = __builtin_amdgcn_mfma_f32_16x16x32_bf16(a3, b2, acc[3][2], 0, 0, 0);
        acc[3][3] = __builtin_amdgcn_mfma_f32_16x16x32_bf16(a3, b3, acc[3][3], 0, 0, 0);
      }
    }

#pragma unroll
    for (int mt = 0; mt < 4; ++mt) {
#pragma unroll
      for (int i = 0; i < 4; ++i) {
        int oc = mt * 16 + q * 4 + i;
        float sc = scf[oc], sh = shf[oc];
        bool sel = sli[oc] != 0;
        unsigned short* yo = ym + ((size_t)b * 64 + oc) * FEAT + F0 + w * 64 + n16;
#pragma unroll
        for (int nt = 0; nt < 4; ++nt) {
          float y = fmaf(acc[mt][nt][i], sc, sh);
          y = fmaxf(y, 0.f);
          if (!sel) y *= y;
          yo[nt * 16] = f2bf(y);
        }
      }
    }
  }
}

// K2: 3x3 avg pool 96->32 + fused LayerNorm over C. Writes ori (raw pooled)
// and sn (LN'd).
__global__ __launch_bounds__(256) void k_pool9ln(
    const unsigned short* __restrict__ ym, const float* __restrict__ lng,
    const float* __restrict__ lnb, float* __restrict__ ori, float* __restrict__ sn) {
  int oc = blockIdx.x, b = blockIdx.y;
  const unsigned short* src = ym + ((size_t)b * 64 + oc) * FEAT;
  int oh0 = (oc >> 3) << 2, ow0 = (oc & 7) << 2;
  __shared__ float red[8];
  int t = threadIdx.x;
  int c = t & 127, hr = t >> 7, wv = t >> 6, l64 = t & 63;
  float g = lng[c], bb = lnb[c];
  for (int p = 0; p < 8; ++p) {
    int nl = p * 2 + hr;
    int pg1 = nl >> 2, pg2 = nl & 3;
    int pbase = (pg1 * 36 + pg2 * 3) * 128 + c;
    float s = 0.f;
#pragma unroll
    for (int dy = 0; dy < 3; ++dy)
#pragma unroll
      for (int dx = 0; dx < 3; ++dx)
        s += b2f(src[pbase + (dy * 12 + dx) * 128]);
    float val = s * (1.f / 9.f);
    float su = val, q = val * val;
#pragma unroll
    for (int off = 32; off > 0; off >>= 1) {
      su += __shfl_xor(su, off, 64);
      q += __shfl_xor(q, off, 64);
    }
    if (l64 == 0) { red[wv * 2] = su; red[wv * 2 + 1] = q; }
    __syncthreads();
    float S = red[hr * 4 + 0] + red[hr * 4 + 2];
    float Q = red[hr * 4 + 1] + red[hr * 4 + 3];
    float mean = S * (1.f / 128.f);
    float var = Q * (1.f / 128.f) - mean * mean;
    float inv = rsqrtf(var + 1e-5f);
    int n = (oh0 + pg1) * 32 + ow0 + pg2;
    size_t base = ((size_t)b * 1024 + n) * 128 + c;
    ori[base] = val;
    sn[base] = (val - mean) * inv * g + bb;
    __syncthreads();   // red reuse next pass
  }
}

// K3: 2x2 avg pool of o (f32, 64->32) + LayerNorm over C -> ofl[b][n][c]
__global__ __launch_bounds__(256) void k_poolo_ln(
    const float* __restrict__ o, const float* __restrict__ lng,
    const float* __restrict__ lnb, float* __restrict__ ofl) {
  int y = blockIdx.x, b = blockIdx.y;
  __shared__ float pl[128 * 33];
  int t = threadIdx.x;
  for (int idx = t; idx < 4096; idx += 256) {
    int xo = idx & 31, c = idx >> 5;
    const float* p = o + (((size_t)b * 128 + c) * 64 + 2 * y) * 64 + 2 * xo;
    float2 a = *(const float2*)p;
    float2 d = *(const float2*)(p + 64);
    pl[c * 33 + xo] = 0.25f * (a.x + a.y + d.x + d.y);
  }
  __syncthreads();
  int xo = t >> 3, l8 = t & 7;
  float v[16]; float s = 0.f, q = 0.f;
#pragma unroll
  for (int i = 0; i < 16; ++i) {
    float x = pl[(l8 * 16 + i) * 33 + xo];
    v[i] = x; s += x; q += x * x;
  }
#pragma unroll
  for (int off = 1; off < 8; off <<= 1) {
    s += __shfl_xor(s, off, 8);
    q += __shfl_xor(q, off, 8);
  }
  float mean = s * (1.f / 128.f);
  float var = q * (1.f / 128.f) - mean * mean;
  float inv = rsqrtf(var + 1e-5f);
  float* dst = ofl + ((size_t)b * 1024 + y * 32 + xo) * 128 + l8 * 16;
#pragma unroll
  for (int i = 0; i < 16; ++i)
    dst[i] = (v[i] - mean) * inv * lng[l8 * 16 + i] + lnb[l8 * 16 + i];
}

// K5: out[M][Ncols] = A[M][128] @ W[Ncols][128]^T + bias
__global__ __launch_bounds__(256) void k_gemm(
    const float* __restrict__ A, const float* __restrict__ W,
    const float* __restrict__ bias, float* __restrict__ out, int Ncols) {
  int mt = blockIdx.x, ct = blockIdx.y;
  int m0 = mt << 6, c0 = ct << 6;
  __shared__ float Al[64 * 67], Wl[64 * 67];
  int t = threadIdx.x, tm = t & 15, tc = t >> 4;
  float acc[4][4];
#pragma unroll
  for (int i = 0; i < 4; ++i)
#pragma unroll
    for (int j = 0; j < 4; ++j) acc[i][j] = 0.f;
  for (int kc = 0; kc < 2; ++kc) {
    __syncthreads();
    for (int idx = t; idx < 4096; idx += 256) {
      int r = idx >> 6, kk = idx & 63;
      Al[r * 67 + kk] = A[(size_t)(m0 + r) * 128 + kc * 64 + kk];
      Wl[r * 67 + kk] = W[(size_t)(c0 + r) * 128 + kc * 64 + kk];
    }
    __syncthreads();
    for (int kk = 0; kk < 64; ++kk) {
      float a[4], w[4];
#pragma unroll
      for (int i = 0; i < 4; ++i) a[i] = Al[(tm * 4 + i) * 67 + kk];
#pragma unroll
      for (int j = 0; j < 4; ++j) w[j] = Wl[(tc * 4 + j) * 67 + kk];
#pragma unroll
      for (int i = 0; i < 4; ++i)
#pragma unroll
        for (int j = 0; j < 4; ++j) acc[i][j] = fmaf(a[i], w[j], acc[i][j]);
    }
  }
#pragma unroll
  for (int i = 0; i < 4; ++i) {
    float4 vv;
    vv.x = acc[i][0] + bias[c0 + tc * 4 + 0];
    vv.y = acc[i][1] + bias[c0 + tc * 4 + 1];
    vv.z = acc[i][2] + bias[c0 + tc * 4 + 2];
    vv.w = acc[i][3] + bias[c0 + tc * 4 + 3];
    *(float4*)(out + (size_t)(m0 + tm * 4 + i) * Ncols + c0 + tc * 4) = vv;
  }
}

// K_cvt: qkvb f32 [b][1024][384] -> qkb bf16 [b][h][{q,k}][1024][32];
//        yvbuf f32 [b][1024][128] -> vtb bf16 [b][h][32][1024] (V transposed).
__global__ __launch_bounds__(256) void k_cvt(const float* __restrict__ qkv,
                                             const float* __restrict__ yv,
                                             unsigned short* __restrict__ qkb,
                                             unsigned short* __restrict__ vtb) {
  int nt = blockIdx.x, b = blockIdx.y;   // 64 n per block
  int n0 = nt << 6;
  int t = threadIdx.x;
  __shared__ unsigned short tl[64 * 132];
  const float* qb = qkv + ((size_t)b * 1024 + n0) * 384;
  for (int it = 0; it < 16; ++it) {
    int idx = it * 256 + t;
    int n = idx >> 6, c4 = idx & 63;     // c = c4*4 in [0,256)
    float4 v = *(const float4*)(qb + (size_t)n * 384 + c4 * 4);
    int c = c4 << 2;
    int kind = c >> 7, h = (c >> 5) & 3, d = c & 31;
    uint2 u;
    u.x = (unsigned int)f2bf(v.x) | ((unsigned int)f2bf(v.y) << 16);
    u.y = (unsigned int)f2bf(v.z) | ((unsigned int)f2bf(v.w) << 16);
    *(uint2*)(qkb + ((((size_t)b * 4 + h) * 2 + kind) * 1024 + n0 + n) * 32 + d) = u;
  }
  const float* vb = yv + ((size_t)b * 1024 + n0) * 128;
  for (int it = 0; it < 8; ++it) {
    int idx = it * 256 + t;
    int n = idx >> 5, c4 = idx & 31;
    float4 v = *(const float4*)(vb + (size_t)n * 128 + c4 * 4);
    unsigned short* o = tl + n * 132 + c4 * 4;
    o[0] = f2bf(v.x); o[1] = f2bf(v.y); o[2] = f2bf(v.z); o[3] = f2bf(v.w);
  }
  __syncthreads();
  int c = t >> 1, half = t & 1;          // c = h*32+d in [0,128)
  unsigned short* orow = vtb + (((size_t)b * 4 + (c >> 5)) * 32 + (c & 31)) * 1024 + n0 + half * 32;
#pragma unroll
  for (int k = 0; k < 4; ++k) {
    short8 pack;
#pragma unroll
    for (int j = 0; j < 8; ++j)
      pack[j] = (short)tl[(half * 32 + k * 8 + j) * 132 + c];
    *(short8*)(orow + k * 8) = pack;
  }
}

// K6 (MFMA): flash attention. swapped QK^T (S = mfma(K,Q)) puts a full
// q-row's scores lane-local -> softmax reduce = VALU tree + 2 shfl; P write =
// 4x b64. P layout & PV path unchanged.
__global__ __launch_bounds__(256) void k_attn(const float* __restrict__ qkv,
                                              const unsigned short* __restrict__ qkb,
                                              const unsigned short* __restrict__ vtb,
                                              float* __restrict__ att) {
  int qt = blockIdx.x, h = blockIdx.y, b = blockIdx.z;
  __shared__ unsigned short Qs[64 * 40];
  __shared__ unsigned short Ks[64 * 40];
  __shared__ unsigned short Vt[32 * 72];
  __shared__ unsigned short Pw[4 * 16 * 68];  // per-wave [q16][key64], stride 68
  int t = threadIdx.x;
  int lane = t & 63, w = t >> 6;
  int quad = lane >> 4, l16 = lane & 15;
  const float* qbase = qkv + (size_t)b * 1024 * 384;   // epilogue v residual (f32)
  const unsigned short* qrow = qkb + (((size_t)b * 4 + h) * 2 + 0) * 1024 * 32;
  const unsigned short* krow = qkb + (((size_t)b * 4 + h) * 2 + 1) * 1024 * 32;
  const unsigned short* vrow = vtb + ((size_t)b * 4 + h) * 32 * 1024;
  int q0 = qt << 6;
  int hd = h * 32;

  {
    int r = t >> 2, cq = t & 3;
    short8 v = *(const short8*)(qrow + (size_t)(q0 + r) * 32 + cq * 8);
    *(short8*)(Qs + r * 40 + cq * 8) = v;
  }
  __syncthreads();
  short8 aq = *(const short8*)(Qs + (w * 16 + l16) * 40 + quad * 8);

  f32x4 O[2];
  O[0] = (f32x4){0.f, 0.f, 0.f, 0.f};
  O[1] = (f32x4){0.f, 0.f, 0.f, 0.f};
  float mi0 = -1e30f, li0 = 0.f;       // per-lane, q = l16 (uniform across quads)
  unsigned short* Pme = Pw + w * (16 * 68);
  const float scl = 0.17677669529663688f;

  for (int ci = 0; ci < 16; ++ci) {
    __syncthreads();
    int kn0 = ci << 6;
    {
      int r = t >> 2, cq = t & 3;
      short8 kv = *(const short8*)(krow + (size_t)(kn0 + r) * 32 + cq * 8);
      *(short8*)(Ks + r * 40 + cq * 8) = kv;
      int d = t >> 3, cc = t & 7;
      short8 vv = *(const short8*)(vrow + (size_t)d * 1024 + kn0 + cc * 8);
      *(short8*)(Vt + d * 72 + cc * 8) = vv;
    }
    __syncthreads();

    // swapped: S[nt] row = key(quad*4+reg), col = q(l16)
    f32x4 S[4];
#pragma unroll
    for (int nt = 0; nt < 4; ++nt) S[nt] = (f32x4){0.f, 0.f, 0.f, 0.f};
#pragma unroll
    for (int nt = 0; nt < 4; ++nt) {
      short8 bk = *(const short8*)(Ks + (nt * 16 + l16) * 40 + quad * 8);
      S[nt] = __builtin_amdgcn_mfma_f32_16x16x32_bf16(bk, aq, S[nt], 0, 0, 0);
    }

    // lane-local 16 scores of q-row l16: key = nt*16 + quad*4 + reg
    float sv[16];
#pragma unroll
    for (int nt = 0; nt < 4; ++nt)
#pragma unroll
      for (int r = 0; r < 4; ++r) sv[nt * 4 + r] = S[nt][r] * scl;
    float m0 = fmaxf(fmaxf(sv[0], sv[1]), fmaxf(sv[2], sv[3]));
    float m1 = fmaxf(fmaxf(sv[4], sv[5]), fmaxf(sv[6], sv[7]));
    float m2 = fmaxf(fmaxf(sv[8], sv[9]), fmaxf(sv[10], sv[11]));
    float m3 = fmaxf(fmaxf(sv[12], sv[13]), fmaxf(sv[14], sv[15]));
    float rm = fmaxf(fmaxf(m0, m1), fmaxf(m2, m3));
    rm = fmaxf(rm, __shfl_xor(rm, 16));
    rm = fmaxf(rm, __shfl_xor(rm, 32));
    float nm = fmaxf(mi0, rm);
    float alpha = __expf(mi0 - nm);
    mi0 = nm;

    float psnt[4];
    unsigned short* pwr = Pme + l16 * 68 + quad * 4;
#pragma unroll
    for (int nt = 0; nt < 4; ++nt) {
      float p0 = __expf(sv[nt * 4 + 0] - nm);
      float p1 = __expf(sv[nt * 4 + 1] - nm);
      float p2 = __expf(sv[nt * 4 + 2] - nm);
      float p3 = __expf(sv[nt * 4 + 3] - nm);
      psnt[nt] = (p0 + p1) + (p2 + p3);
      uint2 u;
      u.x = (unsigned int)f2bf(p0) | ((unsigned int)f2bf(p1) << 16);
      u.y = (unsigned int)f2bf(p2) | ((unsigned int)f2bf(p3) << 16);
      *(uint2*)(pwr + nt * 16) = u;
    }
    float ps = (psnt[0] + psnt[1]) + (psnt[2] + psnt[3]);
    ps += __shfl_xor(ps, 16);
    ps += __shfl_xor(ps, 32);
    li0 = li0 * alpha + ps;

    // transpose alpha from q=l16 domain to q=quad*4+reg (O row domain)
    float al0 = __shfl(alpha, quad * 4 + 0);
    float al1 = __shfl(alpha, quad * 4 + 1);
    float al2 = __shfl(alpha, quad * 4 + 2);
    float al3 = __shfl(alpha, quad * 4 + 3);
    O[0][0] *= al0; O[1][0] *= al0;
    O[0][1] *= al1; O[1][1] *= al1;
    O[0][2] *= al2; O[1][2] *= al2;
    O[0][3] *= al3; O[1][3] *= al3;

#pragma unroll
    for (int kc = 0; kc < 2; ++kc) {
      short8 bv0 = *(const short8*)(Vt + l16 * 72 + kc * 32 + quad * 8);
      short8 bv1 = *(const short8*)(Vt + (16 + l16) * 72 + kc * 32 + quad * 8);
      short8 ap = *(const short8*)(Pme + l16 * 68 + kc * 32 + quad * 8);
      O[0] = __builtin_amdgcn_mfma_f32_16x16x32_bf16(ap, bv0, O[0], 0, 0, 0);
      O[1] = __builtin_amdgcn_mfma_f32_16x16x32_bf16(ap, bv1, O[1], 0, 0, 0);
    }
  }

#pragma unroll
  for (int reg = 0; reg < 4; ++reg) {
    float lit = __shfl(li0, quad * 4 + reg);
    int n = q0 + w * 16 + quad * 4 + reg;
    float inv = 1.f / lit;
#pragma unroll
    for (int nt = 0; nt < 2; ++nt) {
      int dd = hd + nt * 16 + l16;
      float val = O[nt][reg] * inv + qbase[(size_t)n * 384 + 256 + dd];
      att[((size_t)b * 1024 + n) * 128 + dd] = val;
    }
  }
}

// K7: proj GEMM + bias + ori residual, write transposed xv2[b][c][n]
__global__ __launch_bounds__(256) void k_proj(
    const float* __restrict__ att, const float* __restrict__ proj_w,
    const float* __restrict__ proj_b, const float* __restrict__ ori,
    float* __restrict__ xv2) {
  int nt = blockIdx.x, b = blockIdx.y;
  int n0 = nt << 6;
  __shared__ float Al[64 * 67], Wl[128 * 67];
  int t = threadIdx.x, tn = t & 15, tc = t >> 4;
  float acc[4][8];
#pragma unroll
  for (int i = 0; i < 4; ++i)
#pragma unroll
    for (int j = 0; j < 8; ++j) acc[i][j] = 0.f;
  const float* Ab = att + ((size_t)b * 1024 + n0) * 128;
  for (int kc = 0; kc < 2; ++kc) {
    __syncthreads();
    for (int idx = t; idx < 4096; idx += 256) {
      int r = idx >> 6, kk = idx & 63;
      Al[r * 67 + kk] = Ab[(size_t)r * 128 + kc * 64 + kk];
    }
    for (int idx = t; idx < 8192; idx += 256) {
      int r = idx >> 6, kk = idx & 63;
      Wl[r * 67 + kk] = proj_w[(size_t)r * 128 + kc * 64 + kk];
    }
    __syncthreads();
    for (int kk = 0; kk < 64; ++kk) {
      float a[4], w[8];
#pragma unroll
      for (int i = 0; i < 4; ++i) a[i] = Al[(tn * 4 + i) * 67 + kk];
#pragma unroll
      for (int j = 0; j < 8; ++j) w[j] = Wl[(tc * 8 + j) * 67 + kk];
#pragma unroll
      for (int i = 0; i < 4; ++i)
#pragma unroll
        for (int j = 0; j < 8; ++j) acc[i][j] = fmaf(a[i], w[j], acc[i][j]);
    }
  }
#pragma unroll
  for (int j = 0; j < 8; ++j) {
    int c = tc * 8 + j;
    float pb = proj_b[c];
    float4 vv;
    vv.x = acc[0][j] + pb + ori[((size_t)b * 1024 + n0 + tn * 4 + 0) * 128 + c];
    vv.y = acc[1][j] + pb + ori[((size_t)b * 1024 + n0 + tn * 4 + 1) * 128 + c];
    vv.z = acc[2][j] + pb + ori[((size_t)b * 1024 + n0 + tn * 4 + 2) * 128 + c];
    vv.w = acc[3][j] + pb + ori[((size_t)b * 1024 + n0 + tn * 4 + 3) * 128 + c];
    *(float4*)(xv2 + ((size_t)b * 128 + c) * 1024 + n0 + tn * 4) = vv;
  }
}

// K8: conv1d over n (128->128 channels, K=5, pad=2) + residual.
// v8: NB=32 + SINGLE-buffered LDS weights (38.9 KB -> 4 blocks/CU, 16 waves/CU).
// r10's double-buffer halved occupancy (2 blocks/CU) and lost more to weak
// inter-block overlap than it saved in drain hiding; block-level TLP (m114)
// hides the per-chunk vmcnt drain better.
__global__ __launch_bounds__(256) void k_conv1d(
    const float* __restrict__ xv2, const float* __restrict__ cwt,
    float* __restrict__ xv3) {
  extern __shared__ char cs[];
  float* xl = (float*)cs;                   // [128][36], 18432 B
  float* wl = (float*)(cs + 18432);         // [40][128], 20480 B
  int nt = blockIdx.x, b = blockIdx.y;
  int n0 = nt << 5;                         // 32 n per block
  int t = threadIdx.x;
  int lane = t & 63, w = t >> 6;
  const float* xb = xv2 + (size_t)b * 128 * 1024;
  for (int idx = t; idx < 4608; idx += 256) {
    int ic = idx / 36, j = idx - ic * 36;
    int n = n0 + j - 2;
    xl[idx] = (n >= 0 && n < 1024) ? xb[(size_t)ic * 1024 + n] : 0.f;
  }

  int oc = t & 127, g = t >> 7;             // g in {0,1}: n-half (16 each)
  float acc[16];
#pragma unroll
  for (int i = 0; i < 16; ++i) acc[i] = 0.f;

#pragma unroll 1
  for (int ch = 0; ch < 16; ++ch) {
    __syncthreads();                        // wl free (prev consumed); xl ready at ch=0
#pragma unroll
    for (int j = 0; j < 5; ++j) {
      int seg = w * 5 + j;                  // 20 segs x 1KiB = 20480 B
      gl_lds16((const char*)cwt + (size_t)ch * 20480 + (seg << 10) + lane * 16,
               (char*)wl + (seg << 10));
    }
    __syncthreads();                        // staging complete

#pragma unroll
    for (int icl = 0; icl < 8; ++icl) {
      int ic = ch * 8 + icl;
      const float* xr = xl + ic * 36 + (g << 4);   // wave-uniform, 16B aligned
      float xw[20];
#pragma unroll
      for (int q2 = 0; q2 < 5; ++q2) {
        float4 v = *(const float4*)(xr + q2 * 4);
        xw[q2 * 4] = v.x; xw[q2 * 4 + 1] = v.y; xw[q2 * 4 + 2] = v.z; xw[q2 * 4 + 3] = v.w;
      }
      const float* wr = wl + icl * 5 * 128 + oc;   // lanes consecutive oc: conflict-free
      float w0 = wr[0], w1 = wr[128], w2 = wr[256], w3 = wr[384], w4 = wr[512];
#pragma unroll
      for (int i = 0; i < 16; ++i)
        acc[i] = fmaf(xw[i], w0, fmaf(xw[i + 1], w1, fmaf(xw[i + 2], w2,
                 fmaf(xw[i + 3], w3, fmaf(xw[i + 4], w4, acc[i])))));
    }
  }

  const float* res = xb + (size_t)oc * 1024 + n0 + (g << 4);
  float* outp = xv3 + ((size_t)b * 128 + oc) * 1024 + n0 + (g << 4);
#pragma unroll
  for (int q2 = 0; q2 < 4; ++q2) {
    float4 r = *(const float4*)(res + q2 * 4);
    float4 o_;
    o_.x = r.x + acc[q2 * 4 + 0];
    o_.y = r.y + acc[q2 * 4 + 1];
    o_.z = r.z + acc[q2 * 4 + 2];
    o_.w = r.w + acc[q2 * 4 + 3];
    *(float4*)(outp + q2 * 4) = o_;
  }
}

// K9: bilinear 32->96 align_corners=True, f32 out
__global__ __launch_bounds__(256) void k_bilinear(const float* __restrict__ xv3,
                                                  float* __restrict__ out) {
  int idx = blockIdx.x * 256 + threadIdx.x;
  int X = idx % 96;
  int t2 = idx / 96;
  int Y = t2 % 96;
  int bc = t2 / 96;
  const float* src = xv3 + (size_t)bc * 1024;
  const float r = 31.f / 95.f;
  float py = Y * r, px = X * r;
  int y0 = (int)py, x0 = (int)px;
  float wy = py - y0, wx = px - x0;
  int y1 = y0 < 31 ? y0 + 1 : 31, x1 = x0 < 31 ? x0 + 1 : 31;
  float a = src[y0 * 32 + x0], b_ = src[y0 * 32 + x1];
  float c_ = src[y1 * 32 + x0], d_ = src[y1 * 32 + x1];
  float t0 = a * (1.f - wy) + c_ * wy;
  float t1 = b_ * (1.f - wy) + d_ * wy;
  out[idx] = t0 * (1.f - wx) + t1 * wx;
}

extern "C" void kernel_launch(void* const* d_in, const int* in_sizes, int n_in,
                              void* d_out, int out_size, void* d_ws, size_t ws_size,
                              hipStream_t stream) {
  (void)in_sizes; (void)n_in; (void)out_size; (void)ws_size;
  const float* s1    = (const float*)d_in[0];
  const float* o     = (const float*)d_in[1];
  const int*   indx  = (const int*)d_in[2];
  const float* pe_w  = (const float*)d_in[3];
  const float* bn_g  = (const float*)d_in[4];
  const float* bn_b  = (const float*)d_in[5];
  const float* bn_m  = (const float*)d_in[6];
  const float* bn_v  = (const float*)d_in[7];
  const float* lnx_g = (const float*)d_in[8];
  const float* lnx_b = (const float*)d_in[9];
  const float* lny_g = (const float*)d_in[10];
  const float* lny_b = (const float*)d_in[11];
  const float* qkv_w = (const float*)d_in[12];
  const float* qkv_b = (const float*)d_in[13];
  const float* yv_w  = (const float*)d_in[14];
  const float* yv_b  = (const float*)d_in[15];
  const float* proj_w = (const float*)d_in[16];
  const float* proj_b = (const float*)d_in[17];
  const float* c1d_w  = (const float*)d_in[18];

  char* ws = (char*)d_ws;
  // Phase 1: xTn bf16 [ws+0, 37.7MB) [f][ic] swizzled, ymh bf16 [ws+37.7MB, 75.5MB).
  unsigned short* xTh = (unsigned short*)ws;
  unsigned short* ymh = (unsigned short*)(ws + 37748736);
  // d_out scratch (overwritten only by k_bilinear at the very end):
  //   wpk  (41KB packed conv_pe weights) at +0
  //   cwt  (328KB transposed conv1d weights) at +64KB
  unsigned short* wpk = (unsigned short*)d_out;
  float* cwt = (float*)((char*)d_out + 65536);
  // Phase 2 (xTh dead after k_conv_pe): region A = [ws+0, 37.7MB)
  float* ori  = (float*)ws;                 // [0, 8.4MB)
  float* sn   = (float*)(ws + 8388608);     // dead after yv gemm
  float* ofl  = (float*)(ws + 16777216);    // dead after qkv gemm
  float* attb = (float*)(ws + 25165824);    // [25.2MB, 33.6MB)
  // Phase 3 (ymh dead after k_pool9ln): region B = [ws+37.7MB, 75.5MB)
  float* qkvb  = (float*)(ws + 37748736);   // 25.2MB
  float* yvbuf = (float*)(ws + 62914560);   // 8.4MB, dead after k_cvt
  // bf16 attn operands:
  unsigned short* qkb = (unsigned short*)(ws + 16777216);  // alias ofl, 8.4MB
  unsigned short* vtb = (unsigned short*)(ws + 71303168);  // tail, 4.2MB
  float* xv2   = (float*)(ws + 37748736);   // alias qkvb (dead after k_attn)
  float* xv3   = (float*)(ws + 46137344);

  hipLaunchKernelGGL(k_prep, dim3(8), dim3(256), 0, stream, pe_w, wpk);
  hipLaunchKernelGGL(k_prepc, dim3(80), dim3(256), 0, stream, c1d_w, cwt);
  hipLaunchKernelGGL(k_transpose, dim3(128, 16), dim3(256), 0, stream, s1, xTh);
  hipLaunchKernelGGL(k_conv_pe, dim3(36, 16), dim3(256), 75008, stream,
                     xTh, wpk, bn_g, bn_b, bn_m, bn_v, indx, ymh);
  hipLaunchKernelGGL(k_pool9ln, dim3(64, 16), dim3(256), 0, stream, ymh, lny_g, lny_b, ori, sn);
  hipLaunchKernelGGL(k_poolo_ln, dim3(32, 16), dim3(256), 0, stream, o, lnx_g, lnx_b, ofl);
  hipLaunchKernelGGL(k_gemm, dim3(256, 6), dim3(256), 0, stream, ofl, qkv_w, qkv_b, qkvb, 384);
  hipLaunchKernelGGL(k_gemm, dim3(256, 2), dim3(256), 0, stream, sn, yv_w, yv_b, yvbuf, 128);
  hipLaunchKernelGGL(k_cvt, dim3(16, 16), dim3(256), 0, stream, qkvb, yvbuf, qkb, vtb);
  hipLaunchKernelGGL(k_attn, dim3(16, 4, 16), dim3(256), 0, stream, qkvb, qkb, vtb, attb);
  hipLaunchKernelGGL(k_proj, dim3(16, 16), dim3(256), 0, stream, attb, proj_w, proj_b, ori, xv2);
  hipLaunchKernelGGL(k_conv1d, dim3(32, 16), dim3(256), 38912, stream, xv2, cwt, xv3);
  hipLaunchKernelGGL(k_bilinear, dim3(73728), dim3(256), 0, stream, xv3, (float*)d_out);
}

// Round 13
// 411.892 us; speedup vs baseline: 1.4416x; 1.1366x over previous
//
#include <hip/hip_runtime.h>

#define FEAT 18432

typedef __attribute__((ext_vector_type(8))) short short8;
typedef __attribute__((ext_vector_type(4))) float f32x4;

__device__ __forceinline__ float b2f(unsigned short s) {
  union { unsigned int u; float f; } v; v.u = ((unsigned int)s) << 16; return v.f;
}
__device__ __forceinline__ unsigned short f2bf(float x) {
  union { float f; unsigned int u; } v; v.f = x;
  unsigned int u = v.u;
  unsigned int r = (u + 0x7FFFu + ((u >> 16) & 1u)) >> 16;
  return (unsigned short)r;
}

// async global->LDS, 16B per lane; LDS dest = base + lane*16 (wave-uniform base)
__device__ __forceinline__ void gl_lds16(const void* g, void* l) {
  __builtin_amdgcn_global_load_lds(
      (const __attribute__((address_space(1))) unsigned int*)g,
      (__attribute__((address_space(3))) unsigned int*)l, 16, 0, 0);
}

// K0: s1[b][c][96][96] (f32) -> xTn[b][f][ic] bf16, ic contiguous (128B rows),
// with 16B chunks swizzled within each row: pos = chunk ^ (f&7)  (f&7 == c&7).
__global__ __launch_bounds__(256) void k_transpose(const float* __restrict__ s1,
                                                   unsigned short* __restrict__ xT) {
  int c = blockIdx.x, b = blockIdx.y;
  __shared__ float lds[96 * 99];            // plane [h][w], pad 99
  int t = threadIdx.x;
  const float* src = s1 + ((size_t)b * 128 + c) * 9216;
  for (int idx = t; idx < 2304; idx += 256) {
    float4 v = ((const float4*)src)[idx];
    int h = idx / 24, w0 = (idx - h * 24) * 4;
    float* p = lds + h * 99 + w0;
    p[0] = v.x; p[1] = v.y; p[2] = v.z; p[3] = v.w;
  }
  __syncthreads();
  unsigned short* dstb = xT + (size_t)b * FEAT * 64;
  int sw = c & 7;
  for (int idx = t; idx < 1152; idx += 256) {
    int p1p2 = idx >> 3, gh = idx & 7;
    int p1 = p1p2 / 12, p2 = p1p2 - p1 * 12;
    const float* row = lds + (gh * 12 + p1) * 99 + p2;
    uint4 u;
    u.x = f2bf(row[0])  | ((unsigned int)f2bf(row[12]) << 16);
    u.y = f2bf(row[24]) | ((unsigned int)f2bf(row[36]) << 16);
    u.z = f2bf(row[48]) | ((unsigned int)f2bf(row[60]) << 16);
    u.w = f2bf(row[72]) | ((unsigned int)f2bf(row[84]) << 16);
    int f = p1p2 * 128 + c;
    int pos = gh ^ sw;
    *(uint4*)(dstb + (size_t)f * 64 + pos * 8) = u;
  }
}

// K_prep: pack pe_w -> wpk[oc][320] bf16 with chunk swizzle
__global__ __launch_bounds__(256) void k_prep(const float* __restrict__ pe_w,
                                              unsigned short* __restrict__ wpk) {
  int oc0 = blockIdx.x * 8;
  for (int e = threadIdx.x; e < 2560; e += 256) {
    int oc = oc0 + e / 320;
    int kL = e - (e / 320) * 320;
    int ic = kL & 63, kk = kL >> 6;
    float v = pe_w[(oc * 64 + ic) * 5 + kk];
    int LC = kL >> 3;
    int pos = (LC & 56) | ((LC & 7) ^ (oc & 7));
    wpk[oc * 320 + (pos << 3) + (kL & 7)] = f2bf(v);
  }
}

// K_prepc: transpose conv1d weights cw[oc][640] -> cwt[r640][oc] (oc contiguous)
__global__ __launch_bounds__(256) void k_prepc(const float* __restrict__ cw,
                                               float* __restrict__ cwt) {
  int e0 = (blockIdx.x * 256 + threadIdx.x) * 4;   // 80 blocks x 256 x 4 = 81920
#pragma unroll
  for (int j = 0; j < 4; ++j) {
    int e = e0 + j;
    int r = e >> 7, oc = e & 127;
    cwt[e] = cw[(size_t)oc * 640 + r];
  }
}

// K_prepw: pack GEMM weights W[ncols][128] f32 -> bf16 [n][128] rows with
// 16B-chunk swizzle: slot = (c&8) | ((c&7) ^ (n&7)).
__global__ __launch_bounds__(256) void k_prepw(const float* __restrict__ W,
                                               unsigned short* __restrict__ dst,
                                               int ncols) {
  int idx = blockIdx.x * 256 + threadIdx.x;       // one 8-elem chunk per thread
  if (idx >= ncols * 16) return;
  int n = idx >> 4, c = idx & 15;
  int slot = (c & 8) | ((c & 7) ^ (n & 7));
  const float* s = W + (size_t)n * 128 + c * 8;
  uint4 u;
  u.x = (unsigned int)f2bf(s[0]) | ((unsigned int)f2bf(s[1]) << 16);
  u.y = (unsigned int)f2bf(s[2]) | ((unsigned int)f2bf(s[3]) << 16);
  u.z = (unsigned int)f2bf(s[4]) | ((unsigned int)f2bf(s[5]) << 16);
  u.w = (unsigned int)f2bf(s[6]) | ((unsigned int)f2bf(s[7]) << 16);
  *(uint4*)(dst + (size_t)n * 128 + slot * 8) = u;
}

// K1 (MFMA): conv1d over f as GEMM M=64(oc) x N=18432(f) x K=320
// + BN(eval) + ReLU + selective square.
__global__ __launch_bounds__(256) void k_conv_pe(
    const unsigned short* __restrict__ xT, const unsigned short* __restrict__ wpk,
    const float* __restrict__ bn_g, const float* __restrict__ bn_b,
    const float* __restrict__ bn_m, const float* __restrict__ bn_v,
    const int* __restrict__ indexp, unsigned short* __restrict__ ym) {
  extern __shared__ char smem[];
  unsigned short* Wl = (unsigned short*)smem;            // 64*320*2 = 40960 B
  unsigned short* xl = (unsigned short*)(smem + 40960);  // 260*64*2 = 33280 B
  float* scf = (float*)(smem + 74240);
  float* shf = (float*)(smem + 74496);
  int*   sli = (int*)(smem + 74752);
  int t = threadIdx.x;
  int b = blockIdx.y;
  int blk_f0 = blockIdx.x << 9;
  int lane = t & 63, w = t >> 6;
  int n16 = lane & 15, q = lane >> 4;

  for (int j = 0; j < 10; ++j) {
    int seg = w * 10 + j;
    gl_lds16((const char*)wpk + (seg << 10) + lane * 16, (char*)Wl + (seg << 10));
  }
  if (t < 64) {
    float sc = bn_g[t] * rsqrtf(bn_v[t] + 1e-5f);
    scf[t] = sc;
    shf[t] = bn_b[t] - bn_m[t] * sc;
    int i0 = indexp[0] / 12 * 8 + indexp[1] / 12;
    int i1 = indexp[2] / 12 * 8 + indexp[3] / 12;
    int i2 = indexp[4] / 12 * 8 + indexp[5] / 12;
    int i3 = indexp[6] / 12 * 8 + indexp[7] / 12;
    sli[t] = (t == i0 || t == i1 || t == i2 || t == i3) ? 1 : 0;
  }

  const unsigned short* xb = xT + (size_t)b * FEAT * 64;
  const unsigned int* xbu = (const unsigned int*)xb;

  for (int wnd = 0; wnd < 2; ++wnd) {
    int F0 = blk_f0 + (wnd << 8);
    __syncthreads();
    int flA = (F0 == 0) ? 2 : 0;
    for (int j = 0; j < 8; ++j) {
      int seg = (w << 3) + j;
      int gRow = F0 - 2 + flA + (seg << 3);
      gl_lds16((const char*)xb + (size_t)gRow * 128 + lane * 16,
               (char*)xl + flA * 128 + (seg << 10));
    }
    if (t < 128) {
      int r0 = (flA == 2) ? 0 : 256;
      int fl = (t < 64) ? (r0 + (t >> 5)) : (258 + ((t >> 5) & 1));
      int j = t & 31;
      int f = F0 - 2 + fl;
      unsigned int v = 0;
      if (f >= 0 && f < FEAT) v = xbu[(size_t)f * 32 + j];
      ((unsigned int*)xl)[fl * 32 + j] = v;
    }
    __syncthreads();

    f32x4 acc[4][4];
#pragma unroll
    for (int mt = 0; mt < 4; ++mt)
#pragma unroll
      for (int nt = 0; nt < 4; ++nt) acc[mt][nt] = (f32x4){0.f, 0.f, 0.f, 0.f};

    int rowB = w * 64 + n16;
#pragma unroll
    for (int kk = 0; kk < 5; ++kk) {
      int swb = (n16 + kk + 6) & 7;
#pragma unroll
      for (int ih = 0; ih < 2; ++ih) {
        int ca = (ih << 2) | q;
        const unsigned short* Ap = Wl + kk * 64 + ((ca ^ (n16 & 7)) << 3) + n16 * 320;
        short8 a0 = *(const short8*)(Ap);
        short8 a1 = *(const short8*)(Ap + 16 * 320);
        short8 a2 = *(const short8*)(Ap + 32 * 320);
        short8 a3 = *(const short8*)(Ap + 48 * 320);
        const unsigned short* Bp = xl + ((ca ^ swb) << 3) + (rowB + kk) * 64;
        short8 b0 = *(const short8*)(Bp);
        short8 b1 = *(const short8*)(Bp + 16 * 64);
        short8 b2 = *(const short8*)(Bp + 32 * 64);
        short8 b3 = *(const short8*)(Bp + 48 * 64);
        acc[0][0] = __builtin_amdgcn_mfma_f32_16x16x32_bf16(a0, b0, acc[0][0], 0, 0, 0);
        acc[0][1] = __builtin_amdgcn_mfma_f32_16x16x32_bf16(a0, b1, acc[0][1], 0, 0, 0);
        acc[0][2] = __builtin_amdgcn_mfma_f32_16x16x32_bf16(a0, b2, acc[0][2], 0, 0, 0);
        acc[0][3] = __builtin_amdgcn_mfma_f32_16x16x32_bf16(a0, b3, acc[0][3], 0, 0, 0);
        acc[1][0] = __builtin_amdgcn_mfma_f32_16x16x32_bf16(a1, b0, acc[1][0], 0, 0, 0);
        acc[1][1] = __builtin_amdgcn_mfma_f32_16x16x32_bf16(a1, b1, acc[1][1], 0, 0, 0);
        acc[1][2] = __builtin_amdgcn_mfma_f32_16x16x32_bf16(a1, b2, acc[1][2], 0, 0, 0);
        acc[1][3] = __builtin_amdgcn_mfma_f32_16x16x32_bf16(a1, b3, acc[1][3], 0, 0, 0);
        acc[2][0] = __builtin_amdgcn_mfma_f32_16x16x32_bf16(a2, b0, acc[2][0], 0, 0, 0);
        acc[2][1] = __builtin_amdgcn_mfma_f32_16x16x32_bf16(a2, b1, acc[2][1], 0, 0, 0);
        acc[2][2] = __builtin_amdgcn_mfma_f32_16x16x32_bf16(a2, b2, acc[2][2], 0, 0, 0);
        acc[2][3] = __builtin_amdgcn_mfma_f32_16x16x32_bf16(a2, b3, acc[2][3], 0, 0, 0);
        acc[3][0] = __builtin_amdgcn_mfma_f32_16x16x32_bf16(a3, b0, acc[3][0], 0, 0, 0);
        acc[3][1] = __builtin_amdgcn_mfma_f32_16x16x32_bf16(a3, b1, acc[3][1], 0, 0, 0);
        acc[3][2] = __builtin_amdgcn_mfma_f32_16x16x32_bf16(a3, b2, acc[3][2], 0, 0, 0);
        acc[3][3] = __builtin_amdgcn_mfma_f32_16x16x32_bf16(a3, b3, acc[3][3], 0, 0, 0);
      }
    }

#pragma unroll
    for (int mt = 0; mt < 4; ++mt) {
#pragma unroll
      for (int i = 0; i < 4; ++i) {
        int oc = mt * 16 + q * 4 + i;
        float sc = scf[oc], sh = shf[oc];
        bool sel = sli[oc] != 0;
        unsigned short* yo = ym + ((size_t)b * 64 + oc) * FEAT + F0 + w * 64 + n16;
#pragma unroll
        for (int nt = 0; nt < 4; ++nt) {
          float y = fmaf(acc[mt][nt][i], sc, sh);
          y = fmaxf(y, 0.f);
          if (!sel) y *= y;
          yo[nt * 16] = f2bf(y);
        }
      }
    }
  }
}

// K2: 3x3 avg pool 96->32 + fused LayerNorm over C. Writes ori (raw pooled f32)
// and snh (LN'd bf16, swizzled A-operand layout for MFMA GEMM).
__global__ __launch_bounds__(256) void k_pool9ln(
    const unsigned short* __restrict__ ym, const float* __restrict__ lng,
    const float* __restrict__ lnb, float* __restrict__ ori,
    unsigned short* __restrict__ snh) {
  int oc = blockIdx.x, b = blockIdx.y;
  const unsigned short* src = ym + ((size_t)b * 64 + oc) * FEAT;
  int oh0 = (oc >> 3) << 2, ow0 = (oc & 7) << 2;
  __shared__ float red[8];
  int t = threadIdx.x;
  int c = t & 127, hr = t >> 7, wv = t >> 6, l64 = t & 63;
  float g = lng[c], bb = lnb[c];
  for (int p = 0; p < 8; ++p) {
    int nl = p * 2 + hr;
    int pg1 = nl >> 2, pg2 = nl & 3;
    int pbase = (pg1 * 36 + pg2 * 3) * 128 + c;
    float s = 0.f;
#pragma unroll
    for (int dy = 0; dy < 3; ++dy)
#pragma unroll
      for (int dx = 0; dx < 3; ++dx)
        s += b2f(src[pbase + (dy * 12 + dx) * 128]);
    float val = s * (1.f / 9.f);
    float su = val, q = val * val;
#pragma unroll
    for (int off = 32; off > 0; off >>= 1) {
      su += __shfl_xor(su, off, 64);
      q += __shfl_xor(q, off, 64);
    }
    if (l64 == 0) { red[wv * 2] = su; red[wv * 2 + 1] = q; }
    __syncthreads();
    float S = red[hr * 4 + 0] + red[hr * 4 + 2];
    float Q = red[hr * 4 + 1] + red[hr * 4 + 3];
    float mean = S * (1.f / 128.f);
    float var = Q * (1.f / 128.f) - mean * mean;
    float inv = rsqrtf(var + 1e-5f);
    int n = (oh0 + pg1) * 32 + ow0 + pg2;
    size_t base = ((size_t)b * 1024 + n) * 128;
    ori[base + c] = val;
    float lnv = (val - mean) * inv * g + bb;
    int ch = c >> 3;
    int slot = (ch & 8) | ((ch & 7) ^ (n & 7));
    snh[base + slot * 8 + (c & 7)] = f2bf(lnv);
    __syncthreads();   // red reuse next pass
  }
}

// K3: 2x2 avg pool of o (f32, 64->32) + LayerNorm over C -> oflh bf16 swizzled
__global__ __launch_bounds__(256) void k_poolo_ln(
    const float* __restrict__ o, const float* __restrict__ lng,
    const float* __restrict__ lnb, unsigned short* __restrict__ oflh) {
  int y = blockIdx.x, b = blockIdx.y;
  __shared__ float pl[128 * 33];
  int t = threadIdx.x;
  for (int idx = t; idx < 4096; idx += 256) {
    int xo = idx & 31, c = idx >> 5;
    const float* p = o + (((size_t)b * 128 + c) * 64 + 2 * y) * 64 + 2 * xo;
    float2 a = *(const float2*)p;
    float2 d = *(const float2*)(p + 64);
    pl[c * 33 + xo] = 0.25f * (a.x + a.y + d.x + d.y);
  }
  __syncthreads();
  int xo = t >> 3, l8 = t & 7;
  float v[16]; float s = 0.f, q = 0.f;
#pragma unroll
  for (int i = 0; i < 16; ++i) {
    float x = pl[(l8 * 16 + i) * 33 + xo];
    v[i] = x; s += x; q += x * x;
  }
#pragma unroll
  for (int off = 1; off < 8; off <<= 1) {
    s += __shfl_xor(s, off, 8);
    q += __shfl_xor(q, off, 8);
  }
  float mean = s * (1.f / 128.f);
  float var = q * (1.f / 128.f) - mean * mean;
  float inv = rsqrtf(var + 1e-5f);
  int n = y * 32 + xo;
  unsigned short* dst = oflh + ((size_t)b * 1024 + n) * 128;
  int m7 = n & 7;
#pragma unroll
  for (int h = 0; h < 2; ++h) {
    int c = l8 * 2 + h;
    int slot = (c & 8) | ((c & 7) ^ m7);
    uint4 u;
    float w0 = (v[h * 8 + 0] - mean) * inv * lng[c * 8 + 0] + lnb[c * 8 + 0];
    float w1 = (v[h * 8 + 1] - mean) * inv * lng[c * 8 + 1] + lnb[c * 8 + 1];
    float w2 = (v[h * 8 + 2] - mean) * inv * lng[c * 8 + 2] + lnb[c * 8 + 2];
    float w3 = (v[h * 8 + 3] - mean) * inv * lng[c * 8 + 3] + lnb[c * 8 + 3];
    float w4 = (v[h * 8 + 4] - mean) * inv * lng[c * 8 + 4] + lnb[c * 8 + 4];
    float w5 = (v[h * 8 + 5] - mean) * inv * lng[c * 8 + 5] + lnb[c * 8 + 5];
    float w6 = (v[h * 8 + 6] - mean) * inv * lng[c * 8 + 6] + lnb[c * 8 + 6];
    float w7 = (v[h * 8 + 7] - mean) * inv * lng[c * 8 + 7] + lnb[c * 8 + 7];
    u.x = (unsigned int)f2bf(w0) | ((unsigned int)f2bf(w1) << 16);
    u.y = (unsigned int)f2bf(w2) | ((unsigned int)f2bf(w3) << 16);
    u.z = (unsigned int)f2bf(w4) | ((unsigned int)f2bf(w5) << 16);
    u.w = (unsigned int)f2bf(w6) | ((unsigned int)f2bf(w7) << 16);
    *(uint4*)(dst + slot * 8) = u;
  }
}

// K5 (MFMA): out[M][Ncols] = A[M][128] @ W[Ncols][128]^T + bias, f32 out.
// A,W bf16 swizzled rows. Block tile M=128 x N=64; 4 waves 2Mx2N (64x32 each).
__global__ __launch_bounds__(256) void k_gemm_mfma(
    const unsigned short* __restrict__ A, const unsigned short* __restrict__ W,
    const float* __restrict__ bias, float* __restrict__ out, int Ncols) {
  __shared__ unsigned short Al[128 * 128];   // 32KB
  __shared__ unsigned short Bl[64 * 128];    // 16KB
  int m0 = blockIdx.x << 7, n0 = blockIdx.y << 6;
  int t = threadIdx.x;
  int lane = t & 63, w = t >> 6;
  int n16 = lane & 15, q = lane >> 4;

  for (int j = 0; j < 8; ++j) {
    int seg = w * 8 + j;                    // 32 segs x 1KiB A
    gl_lds16((const char*)A + (size_t)m0 * 256 + (seg << 10) + lane * 16,
             (char*)Al + (seg << 10));
  }
  for (int j = 0; j < 4; ++j) {
    int seg = w * 4 + j;                    // 16 segs x 1KiB B
    gl_lds16((const char*)W + (size_t)n0 * 256 + (seg << 10) + lane * 16,
             (char*)Bl + (seg << 10));
  }
  __syncthreads();

  int wm = w >> 1, wn = w & 1;
  f32x4 acc[4][2];
#pragma unroll
  for (int mt = 0; mt < 4; ++mt)
#pragma unroll
    for (int nt = 0; nt < 2; ++nt) acc[mt][nt] = (f32x4){0.f, 0.f, 0.f, 0.f};

#pragma unroll
  for (int kf = 0; kf < 4; ++kf) {
    int ca = kf * 4 + q;
    int rA0 = wm * 64 + n16;
    const unsigned short* Ap0 = Al + (size_t)rA0 * 128;
    int slotA = (ca & 8) | ((ca & 7) ^ (rA0 & 7));   // rA0&7 == n16&7 (wm*64 mult of 8)
    short8 a0 = *(const short8*)(Ap0 + slotA * 8);
    short8 a1 = *(const short8*)(Ap0 + 16 * 128 + slotA * 8);
    short8 a2 = *(const short8*)(Ap0 + 32 * 128 + slotA * 8);
    short8 a3 = *(const short8*)(Ap0 + 48 * 128 + slotA * 8);
    int rB0 = wn * 32 + n16;
    const unsigned short* Bp0 = Bl + (size_t)rB0 * 128;
    int slotB = (ca & 8) | ((ca & 7) ^ (rB0 & 7));
    short8 b0 = *(const short8*)(Bp0 + slotB * 8);
    short8 b1 = *(const short8*)(Bp0 + 16 * 128 + slotB * 8);
    acc[0][0] = __builtin_amdgcn_mfma_f32_16x16x32_bf16(a0, b0, acc[0][0], 0, 0, 0);
    acc[0][1] = __builtin_amdgcn_mfma_f32_16x16x32_bf16(a0, b1, acc[0][1], 0, 0, 0);
    acc[1][0] = __builtin_amdgcn_mfma_f32_16x16x32_bf16(a1, b0, acc[1][0], 0, 0, 0);
    acc[1][1] = __builtin_amdgcn_mfma_f32_16x16x32_bf16(a1, b1, acc[1][1], 0, 0, 0);
    acc[2][0] = __builtin_amdgcn_mfma_f32_16x16x32_bf16(a2, b0, acc[2][0], 0, 0, 0);
    acc[2][1] = __builtin_amdgcn_mfma_f32_16x16x32_bf16(a2, b1, acc[2][1], 0, 0, 0);
    acc[3][0] = __builtin_amdgcn_mfma_f32_16x16x32_bf16(a3, b0, acc[3][0], 0, 0, 0);
    acc[3][1] = __builtin_amdgcn_mfma_f32_16x16x32_bf16(a3, b1, acc[3][1], 0, 0, 0);
  }

#pragma unroll
  for (int mt = 0; mt < 4; ++mt) {
#pragma unroll
    for (int i = 0; i < 4; ++i) {
      int m = m0 + wm * 64 + mt * 16 + q * 4 + i;
#pragma unroll
      for (int nt = 0; nt < 2; ++nt) {
        int n = n0 + wn * 32 + nt * 16 + n16;
        out[(size_t)m * Ncols + n] = acc[mt][nt][i] + bias[n];
      }
    }
  }
}

// K_cvt: qkvb f32 [b][1024][384] -> qkb bf16 [b][h][{q,k}][1024][32];
//        yvbuf f32 [b][1024][128] -> vtb bf16 [b][h][32][1024] (V transposed).
__global__ __launch_bounds__(256) void k_cvt(const float* __restrict__ qkv,
                                             const float* __restrict__ yv,
                                             unsigned short* __restrict__ qkb,
                                             unsigned short* __restrict__ vtb) {
  int nt = blockIdx.x, b = blockIdx.y;   // 64 n per block
  int n0 = nt << 6;
  int t = threadIdx.x;
  __shared__ unsigned short tl[64 * 132];
  const float* qb = qkv + ((size_t)b * 1024 + n0) * 384;
  for (int it = 0; it < 16; ++it) {
    int idx = it * 256 + t;
    int n = idx >> 6, c4 = idx & 63;     // c = c4*4 in [0,256)
    float4 v = *(const float4*)(qb + (size_t)n * 384 + c4 * 4);
    int c = c4 << 2;
    int kind = c >> 7, h = (c >> 5) & 3, d = c & 31;
    uint2 u;
    u.x = (unsigned int)f2bf(v.x) | ((unsigned int)f2bf(v.y) << 16);
    u.y = (unsigned int)f2bf(v.z) | ((unsigned int)f2bf(v.w) << 16);
    *(uint2*)(qkb + ((((size_t)b * 4 + h) * 2 + kind) * 1024 + n0 + n) * 32 + d) = u;
  }
  const float* vb = yv + ((size_t)b * 1024 + n0) * 128;
  for (int it = 0; it < 8; ++it) {
    int idx = it * 256 + t;
    int n = idx >> 5, c4 = idx & 31;
    float4 v = *(const float4*)(vb + (size_t)n * 128 + c4 * 4);
    unsigned short* o = tl + n * 132 + c4 * 4;
    o[0] = f2bf(v.x); o[1] = f2bf(v.y); o[2] = f2bf(v.z); o[3] = f2bf(v.w);
  }
  __syncthreads();
  int c = t >> 1, half = t & 1;          // c = h*32+d in [0,128)
  unsigned short* orow = vtb + (((size_t)b * 4 + (c >> 5)) * 32 + (c & 31)) * 1024 + n0 + half * 32;
#pragma unroll
  for (int k = 0; k < 4; ++k) {
    short8 pack;
#pragma unroll
    for (int j = 0; j < 8; ++j)
      pack[j] = (short)tl[(half * 32 + k * 8 + j) * 132 + c];
    *(short8*)(orow + k * 8) = pack;
  }
}

// K6 (MFMA): flash attention. swapped QK^T (S = mfma(K,Q)) puts a full
// q-row's scores lane-local.
__global__ __launch_bounds__(256) void k_attn(const float* __restrict__ qkv,
                                              const unsigned short* __restrict__ qkb,
                                              const unsigned short* __restrict__ vtb,
                                              float* __restrict__ att) {
  int qt = blockIdx.x, h = blockIdx.y, b = blockIdx.z;
  __shared__ unsigned short Qs[64 * 40];
  __shared__ unsigned short Ks[64 * 40];
  __shared__ unsigned short Vt[32 * 72];
  __shared__ unsigned short Pw[4 * 16 * 68];  // per-wave [q16][key64], stride 68
  int t = threadIdx.x;
  int lane = t & 63, w = t >> 6;
  int quad = lane >> 4, l16 = lane & 15;
  const float* qbase = qkv + (size_t)b * 1024 * 384;   // epilogue v residual (f32)
  const unsigned short* qrow = qkb + (((size_t)b * 4 + h) * 2 + 0) * 1024 * 32;
  const unsigned short* krow = qkb + (((size_t)b * 4 + h) * 2 + 1) * 1024 * 32;
  const unsigned short* vrow = vtb + ((size_t)b * 4 + h) * 32 * 1024;
  int q0 = qt << 6;
  int hd = h * 32;

  {
    int r = t >> 2, cq = t & 3;
    short8 v = *(const short8*)(qrow + (size_t)(q0 + r) * 32 + cq * 8);
    *(short8*)(Qs + r * 40 + cq * 8) = v;
  }
  __syncthreads();
  short8 aq = *(const short8*)(Qs + (w * 16 + l16) * 40 + quad * 8);

  f32x4 O[2];
  O[0] = (f32x4){0.f, 0.f, 0.f, 0.f};
  O[1] = (f32x4){0.f, 0.f, 0.f, 0.f};
  float mi0 = -1e30f, li0 = 0.f;       // per-lane, q = l16 (uniform across quads)
  unsigned short* Pme = Pw + w * (16 * 68);
  const float scl = 0.17677669529663688f;

  for (int ci = 0; ci < 16; ++ci) {
    __syncthreads();
    int kn0 = ci << 6;
    {
      int r = t >> 2, cq = t & 3;
      short8 kv = *(const short8*)(krow + (size_t)(kn0 + r) * 32 + cq * 8);
      *(short8*)(Ks + r * 40 + cq * 8) = kv;
      int d = t >> 3, cc = t & 7;
      short8 vv = *(const short8*)(vrow + (size_t)d * 1024 + kn0 + cc * 8);
      *(short8*)(Vt + d * 72 + cc * 8) = vv;
    }
    __syncthreads();

    // swapped: S[nt] row = key(quad*4+reg), col = q(l16)
    f32x4 S[4];
#pragma unroll
    for (int nt = 0; nt < 4; ++nt) S[nt] = (f32x4){0.f, 0.f, 0.f, 0.f};
#pragma unroll
    for (int nt = 0; nt < 4; ++nt) {
      short8 bk = *(const short8*)(Ks + (nt * 16 + l16) * 40 + quad * 8);
      S[nt] = __builtin_amdgcn_mfma_f32_16x16x32_bf16(bk, aq, S[nt], 0, 0, 0);
    }

    // lane-local 16 scores of q-row l16: key = nt*16 + quad*4 + reg
    float sv[16];
#pragma unroll
    for (int nt = 0; nt < 4; ++nt)
#pragma unroll
      for (int r = 0; r < 4; ++r) sv[nt * 4 + r] = S[nt][r] * scl;
    float m0 = fmaxf(fmaxf(sv[0], sv[1]), fmaxf(sv[2], sv[3]));
    float m1 = fmaxf(fmaxf(sv[4], sv[5]), fmaxf(sv[6], sv[7]));
    float m2 = fmaxf(fmaxf(sv[8], sv[9]), fmaxf(sv[10], sv[11]));
    float m3 = fmaxf(fmaxf(sv[12], sv[13]), fmaxf(sv[14], sv[15]));
    float rm = fmaxf(fmaxf(m0, m1), fmaxf(m2, m3));
    rm = fmaxf(rm, __shfl_xor(rm, 16));
    rm = fmaxf(rm, __shfl_xor(rm, 32));
    float nm = fmaxf(mi0, rm);
    float alpha = __expf(mi0 - nm);
    mi0 = nm;

    float psnt[4];
    unsigned short* pwr = Pme + l16 * 68 + quad * 4;
#pragma unroll
    for (int nt = 0; nt < 4; ++nt) {
      float p0 = __expf(sv[nt * 4 + 0] - nm);
      float p1 = __expf(sv[nt * 4 + 1] - nm);
      float p2 = __expf(sv[nt * 4 + 2] - nm);
      float p3 = __expf(sv[nt * 4 + 3] - nm);
      psnt[nt] = (p0 + p1) + (p2 + p3);
      uint2 u;
      u.x = (unsigned int)f2bf(p0) | ((unsigned int)f2bf(p1) << 16);
      u.y = (unsigned int)f2bf(p2) | ((unsigned int)f2bf(p3) << 16);
      *(uint2*)(pwr + nt * 16) = u;
    }
    float ps = (psnt[0] + psnt[1]) + (psnt[2] + psnt[3]);
    ps += __shfl_xor(ps, 16);
    ps += __shfl_xor(ps, 32);
    li0 = li0 * alpha + ps;

    // transpose alpha from q=l16 domain to q=quad*4+reg (O row domain)
    float al0 = __shfl(alpha, quad * 4 + 0);
    float al1 = __shfl(alpha, quad * 4 + 1);
    float al2 = __shfl(alpha, quad * 4 + 2);
    float al3 = __shfl(alpha, quad * 4 + 3);
    O[0][0] *= al0; O[1][0] *= al0;
    O[0][1] *= al1; O[1][1] *= al1;
    O[0][2] *= al2; O[1][2] *= al2;
    O[0][3] *= al3; O[1][3] *= al3;

#pragma unroll
    for (int kc = 0; kc < 2; ++kc) {
      short8 bv0 = *(const short8*)(Vt + l16 * 72 + kc * 32 + quad * 8);
      short8 bv1 = *(const short8*)(Vt + (16 + l16) * 72 + kc * 32 + quad * 8);
      short8 ap = *(const short8*)(Pme + l16 * 68 + kc * 32 + quad * 8);
      O[0] = __builtin_amdgcn_mfma_f32_16x16x32_bf16(ap, bv0, O[0], 0, 0, 0);
      O[1] = __builtin_amdgcn_mfma_f32_16x16x32_bf16(ap, bv1, O[1], 0, 0, 0);
    }
  }

#pragma unroll
  for (int reg = 0; reg < 4; ++reg) {
    float lit = __shfl(li0, quad * 4 + reg);
    int n = q0 + w * 16 + quad * 4 + reg;
    float inv = 1.f / lit;
#pragma unroll
    for (int nt = 0; nt < 2; ++nt) {
      int dd = hd + nt * 16 + l16;
      float val = O[nt][reg] * inv + qbase[(size_t)n * 384 + 256 + dd];
      att[((size_t)b * 1024 + n) * 128 + dd] = val;
    }
  }
}

// K7: proj GEMM + bias + ori residual, write transposed xv2[b][c][n]
__global__ __launch_bounds__(256) void k_proj(
    const float* __restrict__ att, const float* __restrict__ proj_w,
    const float* __restrict__ proj_b, const float* __restrict__ ori,
    float* __restrict__ xv2) {
  int nt = blockIdx.x, b = blockIdx.y;
  int n0 = nt << 6;
  __shared__ float Al[64 * 67], Wl[128 * 67];
  int t = threadIdx.x, tn = t & 15, tc = t >> 4;
  float acc[4][8];
#pragma unroll
  for (int i = 0; i < 4; ++i)
#pragma unroll
    for (int j = 0; j < 8; ++j) acc[i][j] = 0.f;
  const float* Ab = att + ((size_t)b * 1024 + n0) * 128;
  for (int kc = 0; kc < 2; ++kc) {
    __syncthreads();
    for (int idx = t; idx < 4096; idx += 256) {
      int r = idx >> 6, kk = idx & 63;
      Al[r * 67 + kk] = Ab[(size_t)r * 128 + kc * 64 + kk];
    }
    for (int idx = t; idx < 8192; idx += 256) {
      int r = idx >> 6, kk = idx & 63;
      Wl[r * 67 + kk] = proj_w[(size_t)r * 128 + kc * 64 + kk];
    }
    __syncthreads();
    for (int kk = 0; kk < 64; ++kk) {
      float a[4], w[8];
#pragma unroll
      for (int i = 0; i < 4; ++i) a[i] = Al[(tn * 4 + i) * 67 + kk];
#pragma unroll
      for (int j = 0; j < 8; ++j) w[j] = Wl[(tc * 8 + j) * 67 + kk];
#pragma unroll
      for (int i = 0; i < 4; ++i)
#pragma unroll
        for (int j = 0; j < 8; ++j) acc[i][j] = fmaf(a[i], w[j], acc[i][j]);
    }
  }
#pragma unroll
  for (int j = 0; j < 8; ++j) {
    int c = tc * 8 + j;
    float pb = proj_b[c];
    float4 vv;
    vv.x = acc[0][j] + pb + ori[((size_t)b * 1024 + n0 + tn * 4 + 0) * 128 + c];
    vv.y = acc[1][j] + pb + ori[((size_t)b * 1024 + n0 + tn * 4 + 1) * 128 + c];
    vv.z = acc[2][j] + pb + ori[((size_t)b * 1024 + n0 + tn * 4 + 2) * 128 + c];
    vv.w = acc[3][j] + pb + ori[((size_t)b * 1024 + n0 + tn * 4 + 3) * 128 + c];
    *(float4*)(xv2 + ((size_t)b * 128 + c) * 1024 + n0 + tn * 4) = vv;
  }
}

// K8: conv1d over n (128->128 channels, K=5, pad=2) + residual.
// NB=32 + single-buffered LDS weights.
__global__ __launch_bounds__(256) void k_conv1d(
    const float* __restrict__ xv2, const float* __restrict__ cwt,
    float* __restrict__ xv3) {
  extern __shared__ char cs[];
  float* xl = (float*)cs;                   // [128][36], 18432 B
  float* wl = (float*)(cs + 18432);         // [40][128], 20480 B
  int nt = blockIdx.x, b = blockIdx.y;
  int n0 = nt << 5;                         // 32 n per block
  int t = threadIdx.x;
  int lane = t & 63, w = t >> 6;
  const float* xb = xv2 + (size_t)b * 128 * 1024;
  for (int idx = t; idx < 4608; idx += 256) {
    int ic = idx / 36, j = idx - ic * 36;
    int n = n0 + j - 2;
    xl[idx] = (n >= 0 && n < 1024) ? xb[(size_t)ic * 1024 + n] : 0.f;
  }

  int oc = t & 127, g = t >> 7;             // g in {0,1}: n-half (16 each)
  float acc[16];
#pragma unroll
  for (int i = 0; i < 16; ++i) acc[i] = 0.f;

#pragma unroll 1
  for (int ch = 0; ch < 16; ++ch) {
    __syncthreads();
#pragma unroll
    for (int j = 0; j < 5; ++j) {
      int seg = w * 5 + j;
      gl_lds16((const char*)cwt + (size_t)ch * 20480 + (seg << 10) + lane * 16,
               (char*)wl + (seg << 10));
    }
    __syncthreads();

#pragma unroll
    for (int icl = 0; icl < 8; ++icl) {
      int ic = ch * 8 + icl;
      const float* xr = xl + ic * 36 + (g << 4);
      float xw[20];
#pragma unroll
      for (int q2 = 0; q2 < 5; ++q2) {
        float4 v = *(const float4*)(xr + q2 * 4);
        xw[q2 * 4] = v.x; xw[q2 * 4 + 1] = v.y; xw[q2 * 4 + 2] = v.z; xw[q2 * 4 + 3] = v.w;
      }
      const float* wr = wl + icl * 5 * 128 + oc;
      float w0 = wr[0], w1 = wr[128], w2 = wr[256], w3 = wr[384], w4 = wr[512];
#pragma unroll
      for (int i = 0; i < 16; ++i)
        acc[i] = fmaf(xw[i], w0, fmaf(xw[i + 1], w1, fmaf(xw[i + 2], w2,
                 fmaf(xw[i + 3], w3, fmaf(xw[i + 4], w4, acc[i])))));
    }
  }

  const float* res = xb + (size_t)oc * 1024 + n0 + (g << 4);
  float* outp = xv3 + ((size_t)b * 128 + oc) * 1024 + n0 + (g << 4);
#pragma unroll
  for (int q2 = 0; q2 < 4; ++q2) {
    float4 r = *(const float4*)(res + q2 * 4);
    float4 o_;
    o_.x = r.x + acc[q2 * 4 + 0];
    o_.y = r.y + acc[q2 * 4 + 1];
    o_.z = r.z + acc[q2 * 4 + 2];
    o_.w = r.w + acc[q2 * 4 + 3];
    *(float4*)(outp + q2 * 4) = o_;
  }
}

// K9: bilinear 32->96 align_corners=True, f32 out
__global__ __launch_bounds__(256) void k_bilinear(const float* __restrict__ xv3,
                                                  float* __restrict__ out) {
  int idx = blockIdx.x * 256 + threadIdx.x;
  int X = idx % 96;
  int t2 = idx / 96;
  int Y = t2 % 96;
  int bc = t2 / 96;
  const float* src = xv3 + (size_t)bc * 1024;
  const float r = 31.f / 95.f;
  float py = Y * r, px = X * r;
  int y0 = (int)py, x0 = (int)px;
  float wy = py - y0, wx = px - x0;
  int y1 = y0 < 31 ? y0 + 1 : 31, x1 = x0 < 31 ? x0 + 1 : 31;
  float a = src[y0 * 32 + x0], b_ = src[y0 * 32 + x1];
  float c_ = src[y1 * 32 + x0], d_ = src[y1 * 32 + x1];
  float t0 = a * (1.f - wy) + c_ * wy;
  float t1 = b_ * (1.f - wy) + d_ * wy;
  out[idx] = t0 * (1.f - wx) + t1 * wx;
}

extern "C" void kernel_launch(void* const* d_in, const int* in_sizes, int n_in,
                              void* d_out, int out_size, void* d_ws, size_t ws_size,
                              hipStream_t stream) {
  (void)in_sizes; (void)n_in; (void)out_size; (void)ws_size;
  const float* s1    = (const float*)d_in[0];
  const float* o     = (const float*)d_in[1];
  const int*   indx  = (const int*)d_in[2];
  const float* pe_w  = (const float*)d_in[3];
  const float* bn_g  = (const float*)d_in[4];
  const float* bn_b  = (const float*)d_in[5];
  const float* bn_m  = (const float*)d_in[6];
  const float* bn_v  = (const float*)d_in[7];
  const float* lnx_g = (const float*)d_in[8];
  const float* lnx_b = (const float*)d_in[9];
  const float* lny_g = (const float*)d_in[10];
  const float* lny_b = (const float*)d_in[11];
  const float* qkv_w = (const float*)d_in[12];
  const float* qkv_b = (const float*)d_in[13];
  const float* yv_w  = (const float*)d_in[14];
  const float* yv_b  = (const float*)d_in[15];
  const float* proj_w = (const float*)d_in[16];
  const float* proj_b = (const float*)d_in[17];
  const float* c1d_w  = (const float*)d_in[18];

  char* ws = (char*)d_ws;
  // Phase 1: xTn bf16 [ws+0, 37.7MB), ymh bf16 [ws+37.7MB, 75.5MB).
  unsigned short* xTh = (unsigned short*)ws;
  unsigned short* ymh = (unsigned short*)(ws + 37748736);
  // d_out scratch (overwritten only by k_bilinear at the very end):
  //   wpk (41KB) at +0; cwt (328KB) at +64KB; wqkh (98KB bf16) at +448KB;
  //   wyvh (32KB bf16) at +560KB.
  unsigned short* wpk = (unsigned short*)d_out;
  float* cwt = (float*)((char*)d_out + 65536);
  unsigned short* wqkh = (unsigned short*)((char*)d_out + 458752);
  unsigned short* wyvh = (unsigned short*)((char*)d_out + 573440);
  // Phase 2 (xTh dead after k_conv_pe): region A = [ws+0, 37.7MB)
  float* ori  = (float*)ws;                 // [0, 8.4MB)
  unsigned short* snh  = (unsigned short*)(ws + 8388608);   // 4.2MB bf16, dead after yv gemm
  unsigned short* oflh = (unsigned short*)(ws + 16777216);  // 4.2MB bf16, dead after qkv gemm
  float* attb = (float*)(ws + 25165824);    // [25.2MB, 33.6MB)
  // Phase 3 (ymh dead after k_pool9ln): region B = [ws+37.7MB, 75.5MB)
  float* qkvb  = (float*)(ws + 37748736);   // 25.2MB
  float* yvbuf = (float*)(ws + 62914560);   // 8.4MB, dead after k_cvt
  // bf16 attn operands:
  unsigned short* qkb = (unsigned short*)(ws + 16777216);  // alias oflh (dead), 8.4MB
  unsigned short* vtb = (unsigned short*)(ws + 71303168);  // tail, 4.2MB
  float* xv2   = (float*)(ws + 37748736);   // alias qkvb (dead after k_attn)
  float* xv3   = (float*)(ws + 46137344);

  hipLaunchKernelGGL(k_prep, dim3(8), dim3(256), 0, stream, pe_w, wpk);
  hipLaunchKernelGGL(k_prepc, dim3(80), dim3(256), 0, stream, c1d_w, cwt);
  hipLaunchKernelGGL(k_prepw, dim3(24), dim3(256), 0, stream, qkv_w, wqkh, 384);
  hipLaunchKernelGGL(k_prepw, dim3(8), dim3(256), 0, stream, yv_w, wyvh, 128);
  hipLaunchKernelGGL(k_transpose, dim3(128, 16), dim3(256), 0, stream, s1, xTh);
  hipLaunchKernelGGL(k_conv_pe, dim3(36, 16), dim3(256), 75008, stream,
                     xTh, wpk, bn_g, bn_b, bn_m, bn_v, indx, ymh);
  hipLaunchKernelGGL(k_pool9ln, dim3(64, 16), dim3(256), 0, stream, ymh, lny_g, lny_b, ori, snh);
  hipLaunchKernelGGL(k_poolo_ln, dim3(32, 16), dim3(256), 0, stream, o, lnx_g, lnx_b, oflh);
  hipLaunchKernelGGL(k_gemm_mfma, dim3(128, 6), dim3(256), 0, stream, oflh, wqkh, qkv_b, qkvb, 384);
  hipLaunchKernelGGL(k_gemm_mfma, dim3(128, 2), dim3(256), 0, stream, snh, wyvh, yv_b, yvbuf, 128);
  hipLaunchKernelGGL(k_cvt, dim3(16, 16), dim3(256), 0, stream, qkvb, yvbuf, qkb, vtb);
  hipLaunchKernelGGL(k_attn, dim3(16, 4, 16), dim3(256), 0, stream, qkvb, qkb, vtb, attb);
  hipLaunchKernelGGL(k_proj, dim3(16, 16), dim3(256), 0, stream, attb, proj_w, proj_b, ori, xv2);
  hipLaunchKernelGGL(k_conv1d, dim3(32, 16), dim3(256), 38912, stream, xv2, cwt, xv3);
  hipLaunchKernelGGL(k_bilinear, dim3(73728), dim3(256), 0, stream, xv3, (float*)d_out);
}

// Round 14
// 393.639 us; speedup vs baseline: 1.5084x; 1.0464x over previous
//
#include <hip/hip_runtime.h>

#define FEAT 18432

typedef __attribute__((ext_vector_type(8))) short short8;
typedef __attribute__((ext_vector_type(4))) float f32x4;

__device__ __forceinline__ float b2f(unsigned short s) {
  union { unsigned int u; float f; } v; v.u = ((unsigned int)s) << 16; return v.f;
}
__device__ __forceinline__ unsigned short f2bf(float x) {
  union { float f; unsigned int u; } v; v.f = x;
  unsigned int u = v.u;
  unsigned int r = (u + 0x7FFFu + ((u >> 16) & 1u)) >> 16;
  return (unsigned short)r;
}

// async global->LDS, 16B per lane; LDS dest = base + lane*16 (wave-uniform base)
__device__ __forceinline__ void gl_lds16(const void* g, void* l) {
  __builtin_amdgcn_global_load_lds(
      (const __attribute__((address_space(1))) unsigned int*)g,
      (__attribute__((address_space(3))) unsigned int*)l, 16, 0, 0);
}

// K0: s1[b][c][96][96] (f32) -> xTn[b][f][ic] bf16, swizzled 16B chunks.
__global__ __launch_bounds__(256) void k_transpose(const float* __restrict__ s1,
                                                   unsigned short* __restrict__ xT) {
  int c = blockIdx.x, b = blockIdx.y;
  __shared__ float lds[96 * 99];            // plane [h][w], pad 99
  int t = threadIdx.x;
  const float* src = s1 + ((size_t)b * 128 + c) * 9216;
  for (int idx = t; idx < 2304; idx += 256) {
    float4 v = ((const float4*)src)[idx];
    int h = idx / 24, w0 = (idx - h * 24) * 4;
    float* p = lds + h * 99 + w0;
    p[0] = v.x; p[1] = v.y; p[2] = v.z; p[3] = v.w;
  }
  __syncthreads();
  unsigned short* dstb = xT + (size_t)b * FEAT * 64;
  int sw = c & 7;
  for (int idx = t; idx < 1152; idx += 256) {
    int p1p2 = idx >> 3, gh = idx & 7;
    int p1 = p1p2 / 12, p2 = p1p2 - p1 * 12;
    const float* row = lds + (gh * 12 + p1) * 99 + p2;
    uint4 u;
    u.x = f2bf(row[0])  | ((unsigned int)f2bf(row[12]) << 16);
    u.y = f2bf(row[24]) | ((unsigned int)f2bf(row[36]) << 16);
    u.z = f2bf(row[48]) | ((unsigned int)f2bf(row[60]) << 16);
    u.w = f2bf(row[72]) | ((unsigned int)f2bf(row[84]) << 16);
    int f = p1p2 * 128 + c;
    int pos = gh ^ sw;
    *(uint4*)(dstb + (size_t)f * 64 + pos * 8) = u;
  }
}

// K_prep: pack pe_w -> wpk[oc][320] bf16 with chunk swizzle
__global__ __launch_bounds__(256) void k_prep(const float* __restrict__ pe_w,
                                              unsigned short* __restrict__ wpk) {
  int oc0 = blockIdx.x * 8;
  for (int e = threadIdx.x; e < 2560; e += 256) {
    int oc = oc0 + e / 320;
    int kL = e - (e / 320) * 320;
    int ic = kL & 63, kk = kL >> 6;
    float v = pe_w[(oc * 64 + ic) * 5 + kk];
    int LC = kL >> 3;
    int pos = (LC & 56) | ((LC & 7) ^ (oc & 7));
    wpk[oc * 320 + (pos << 3) + (kL & 7)] = f2bf(v);
  }
}

// K_prepc: transpose conv1d weights cw[oc][640] -> cwt[r640][oc] (oc contiguous)
__global__ __launch_bounds__(256) void k_prepc(const float* __restrict__ cw,
                                               float* __restrict__ cwt) {
  int e0 = (blockIdx.x * 256 + threadIdx.x) * 4;
#pragma unroll
  for (int j = 0; j < 4; ++j) {
    int e = e0 + j;
    int r = e >> 7, oc = e & 127;
    cwt[e] = cw[(size_t)oc * 640 + r];
  }
}

// K_prepw: pack GEMM weights W[ncols][128] f32 -> bf16 swizzled rows.
__global__ __launch_bounds__(256) void k_prepw(const float* __restrict__ W,
                                               unsigned short* __restrict__ dst,
                                               int ncols) {
  int idx = blockIdx.x * 256 + threadIdx.x;
  if (idx >= ncols * 16) return;
  int n = idx >> 4, c = idx & 15;
  int slot = (c & 8) | ((c & 7) ^ (n & 7));
  const float* s = W + (size_t)n * 128 + c * 8;
  uint4 u;
  u.x = (unsigned int)f2bf(s[0]) | ((unsigned int)f2bf(s[1]) << 16);
  u.y = (unsigned int)f2bf(s[2]) | ((unsigned int)f2bf(s[3]) << 16);
  u.z = (unsigned int)f2bf(s[4]) | ((unsigned int)f2bf(s[5]) << 16);
  u.w = (unsigned int)f2bf(s[6]) | ((unsigned int)f2bf(s[7]) << 16);
  *(uint4*)(dst + (size_t)n * 128 + slot * 8) = u;
}

// K1 (MFMA): conv1d over f as GEMM + BN(eval) + ReLU + selective square.
__global__ __launch_bounds__(256) void k_conv_pe(
    const unsigned short* __restrict__ xT, const unsigned short* __restrict__ wpk,
    const float* __restrict__ bn_g, const float* __restrict__ bn_b,
    const float* __restrict__ bn_m, const float* __restrict__ bn_v,
    const int* __restrict__ indexp, unsigned short* __restrict__ ym) {
  extern __shared__ char smem[];
  unsigned short* Wl = (unsigned short*)smem;
  unsigned short* xl = (unsigned short*)(smem + 40960);
  float* scf = (float*)(smem + 74240);
  float* shf = (float*)(smem + 74496);
  int*   sli = (int*)(smem + 74752);
  int t = threadIdx.x;
  int b = blockIdx.y;
  int blk_f0 = blockIdx.x << 9;
  int lane = t & 63, w = t >> 6;
  int n16 = lane & 15, q = lane >> 4;

  for (int j = 0; j < 10; ++j) {
    int seg = w * 10 + j;
    gl_lds16((const char*)wpk + (seg << 10) + lane * 16, (char*)Wl + (seg << 10));
  }
  if (t < 64) {
    float sc = bn_g[t] * rsqrtf(bn_v[t] + 1e-5f);
    scf[t] = sc;
    shf[t] = bn_b[t] - bn_m[t] * sc;
    int i0 = indexp[0] / 12 * 8 + indexp[1] / 12;
    int i1 = indexp[2] / 12 * 8 + indexp[3] / 12;
    int i2 = indexp[4] / 12 * 8 + indexp[5] / 12;
    int i3 = indexp[6] / 12 * 8 + indexp[7] / 12;
    sli[t] = (t == i0 || t == i1 || t == i2 || t == i3) ? 1 : 0;
  }

  const unsigned short* xb = xT + (size_t)b * FEAT * 64;
  const unsigned int* xbu = (const unsigned int*)xb;

  for (int wnd = 0; wnd < 2; ++wnd) {
    int F0 = blk_f0 + (wnd << 8);
    __syncthreads();
    int flA = (F0 == 0) ? 2 : 0;
    for (int j = 0; j < 8; ++j) {
      int seg = (w << 3) + j;
      int gRow = F0 - 2 + flA + (seg << 3);
      gl_lds16((const char*)xb + (size_t)gRow * 128 + lane * 16,
               (char*)xl + flA * 128 + (seg << 10));
    }
    if (t < 128) {
      int r0 = (flA == 2) ? 0 : 256;
      int fl = (t < 64) ? (r0 + (t >> 5)) : (258 + ((t >> 5) & 1));
      int j = t & 31;
      int f = F0 - 2 + fl;
      unsigned int v = 0;
      if (f >= 0 && f < FEAT) v = xbu[(size_t)f * 32 + j];
      ((unsigned int*)xl)[fl * 32 + j] = v;
    }
    __syncthreads();

    f32x4 acc[4][4];
#pragma unroll
    for (int mt = 0; mt < 4; ++mt)
#pragma unroll
      for (int nt = 0; nt < 4; ++nt) acc[mt][nt] = (f32x4){0.f, 0.f, 0.f, 0.f};

    int rowB = w * 64 + n16;
#pragma unroll
    for (int kk = 0; kk < 5; ++kk) {
      int swb = (n16 + kk + 6) & 7;
#pragma unroll
      for (int ih = 0; ih < 2; ++ih) {
        int ca = (ih << 2) | q;
        const unsigned short* Ap = Wl + kk * 64 + ((ca ^ (n16 & 7)) << 3) + n16 * 320;
        short8 a0 = *(const short8*)(Ap);
        short8 a1 = *(const short8*)(Ap + 16 * 320);
        short8 a2 = *(const short8*)(Ap + 32 * 320);
        short8 a3 = *(const short8*)(Ap + 48 * 320);
        const unsigned short* Bp = xl + ((ca ^ swb) << 3) + (rowB + kk) * 64;
        short8 b0 = *(const short8*)(Bp);
        short8 b1 = *(const short8*)(Bp + 16 * 64);
        short8 b2 = *(const short8*)(Bp + 32 * 64);
        short8 b3 = *(const short8*)(Bp + 48 * 64);
        acc[0][0] = __builtin_amdgcn_mfma_f32_16x16x32_bf16(a0, b0, acc[0][0], 0, 0, 0);
        acc[0][1] = __builtin_amdgcn_mfma_f32_16x16x32_bf16(a0, b1, acc[0][1], 0, 0, 0);
        acc[0][2] = __builtin_amdgcn_mfma_f32_16x16x32_bf16(a0, b2, acc[0][2], 0, 0, 0);
        acc[0][3] = __builtin_amdgcn_mfma_f32_16x16x32_bf16(a0, b3, acc[0][3], 0, 0, 0);
        acc[1][0] = __builtin_amdgcn_mfma_f32_16x16x32_bf16(a1, b0, acc[1][0], 0, 0, 0);
        acc[1][1] = __builtin_amdgcn_mfma_f32_16x16x32_bf16(a1, b1, acc[1][1], 0, 0, 0);
        acc[1][2] = __builtin_amdgcn_mfma_f32_16x16x32_bf16(a1, b2, acc[1][2], 0, 0, 0);
        acc[1][3] = __builtin_amdgcn_mfma_f32_16x16x32_bf16(a1, b3, acc[1][3], 0, 0, 0);
        acc[2][0] = __builtin_amdgcn_mfma_f32_16x16x32_bf16(a2, b0, acc[2][0], 0, 0, 0);
        acc[2][1] = __builtin_amdgcn_mfma_f32_16x16x32_bf16(a2, b1, acc[2][1], 0, 0, 0);
        acc[2][2] = __builtin_amdgcn_mfma_f32_16x16x32_bf16(a2, b2, acc[2][2], 0, 0, 0);
        acc[2][3] = __builtin_amdgcn_mfma_f32_16x16x32_bf16(a2, b3, acc[2][3], 0, 0, 0);
        acc[3][0] = __builtin_amdgcn_mfma_f32_16x16x32_bf16(a3, b0, acc[3][0], 0, 0, 0);
        acc[3][1] = __builtin_amdgcn_mfma_f32_16x16x32_bf16(a3, b1, acc[3][1], 0, 0, 0);
        acc[3][2] = __builtin_amdgcn_mfma_f32_16x16x32_bf16(a3, b2, acc[3][2], 0, 0, 0);
        acc[3][3] = __builtin_amdgcn_mfma_f32_16x16x32_bf16(a3, b3, acc[3][3], 0, 0, 0);
      }
    }

#pragma unroll
    for (int mt = 0; mt < 4; ++mt) {
#pragma unroll
      for (int i = 0; i < 4; ++i) {
        int oc = mt * 16 + q * 4 + i;
        float sc = scf[oc], sh = shf[oc];
        bool sel = sli[oc] != 0;
        unsigned short* yo = ym + ((size_t)b * 64 + oc) * FEAT + F0 + w * 64 + n16;
#pragma unroll
        for (int nt = 0; nt < 4; ++nt) {
          float y = fmaf(acc[mt][nt][i], sc, sh);
          y = fmaxf(y, 0.f);
          if (!sel) y *= y;
          yo[nt * 16] = f2bf(y);
        }
      }
    }
  }
}

// K2: 3x3 avg pool 96->32 + fused LayerNorm. Writes ori (f32) + snh (bf16 swz).
__global__ __launch_bounds__(256) void k_pool9ln(
    const unsigned short* __restrict__ ym, const float* __restrict__ lng,
    const float* __restrict__ lnb, float* __restrict__ ori,
    unsigned short* __restrict__ snh) {
  int oc = blockIdx.x, b = blockIdx.y;
  const unsigned short* src = ym + ((size_t)b * 64 + oc) * FEAT;
  int oh0 = (oc >> 3) << 2, ow0 = (oc & 7) << 2;
  __shared__ float red[8];
  int t = threadIdx.x;
  int c = t & 127, hr = t >> 7, wv = t >> 6, l64 = t & 63;
  float g = lng[c], bb = lnb[c];
  for (int p = 0; p < 8; ++p) {
    int nl = p * 2 + hr;
    int pg1 = nl >> 2, pg2 = nl & 3;
    int pbase = (pg1 * 36 + pg2 * 3) * 128 + c;
    float s = 0.f;
#pragma unroll
    for (int dy = 0; dy < 3; ++dy)
#pragma unroll
      for (int dx = 0; dx < 3; ++dx)
        s += b2f(src[pbase + (dy * 12 + dx) * 128]);
    float val = s * (1.f / 9.f);
    float su = val, q = val * val;
#pragma unroll
    for (int off = 32; off > 0; off >>= 1) {
      su += __shfl_xor(su, off, 64);
      q += __shfl_xor(q, off, 64);
    }
    if (l64 == 0) { red[wv * 2] = su; red[wv * 2 + 1] = q; }
    __syncthreads();
    float S = red[hr * 4 + 0] + red[hr * 4 + 2];
    float Q = red[hr * 4 + 1] + red[hr * 4 + 3];
    float mean = S * (1.f / 128.f);
    float var = Q * (1.f / 128.f) - mean * mean;
    float inv = rsqrtf(var + 1e-5f);
    int n = (oh0 + pg1) * 32 + ow0 + pg2;
    size_t base = ((size_t)b * 1024 + n) * 128;
    ori[base + c] = val;
    float lnv = (val - mean) * inv * g + bb;
    int ch = c >> 3;
    int slot = (ch & 8) | ((ch & 7) ^ (n & 7));
    snh[base + slot * 8 + (c & 7)] = f2bf(lnv);
    __syncthreads();
  }
}

// K3: 2x2 avg pool of o + LayerNorm -> oflh bf16 swizzled
__global__ __launch_bounds__(256) void k_poolo_ln(
    const float* __restrict__ o, const float* __restrict__ lng,
    const float* __restrict__ lnb, unsigned short* __restrict__ oflh) {
  int y = blockIdx.x, b = blockIdx.y;
  __shared__ float pl[128 * 33];
  int t = threadIdx.x;
  for (int idx = t; idx < 4096; idx += 256) {
    int xo = idx & 31, c = idx >> 5;
    const float* p = o + (((size_t)b * 128 + c) * 64 + 2 * y) * 64 + 2 * xo;
    float2 a = *(const float2*)p;
    float2 d = *(const float2*)(p + 64);
    pl[c * 33 + xo] = 0.25f * (a.x + a.y + d.x + d.y);
  }
  __syncthreads();
  int xo = t >> 3, l8 = t & 7;
  float v[16]; float s = 0.f, q = 0.f;
#pragma unroll
  for (int i = 0; i < 16; ++i) {
    float x = pl[(l8 * 16 + i) * 33 + xo];
    v[i] = x; s += x; q += x * x;
  }
#pragma unroll
  for (int off = 1; off < 8; off <<= 1) {
    s += __shfl_xor(s, off, 8);
    q += __shfl_xor(q, off, 8);
  }
  float mean = s * (1.f / 128.f);
  float var = q * (1.f / 128.f) - mean * mean;
  float inv = rsqrtf(var + 1e-5f);
  int n = y * 32 + xo;
  unsigned short* dst = oflh + ((size_t)b * 1024 + n) * 128;
  int m7 = n & 7;
#pragma unroll
  for (int h = 0; h < 2; ++h) {
    int c = l8 * 2 + h;
    int slot = (c & 8) | ((c & 7) ^ m7);
    uint4 u;
    float w0 = (v[h * 8 + 0] - mean) * inv * lng[c * 8 + 0] + lnb[c * 8 + 0];
    float w1 = (v[h * 8 + 1] - mean) * inv * lng[c * 8 + 1] + lnb[c * 8 + 1];
    float w2 = (v[h * 8 + 2] - mean) * inv * lng[c * 8 + 2] + lnb[c * 8 + 2];
    float w3 = (v[h * 8 + 3] - mean) * inv * lng[c * 8 + 3] + lnb[c * 8 + 3];
    float w4 = (v[h * 8 + 4] - mean) * inv * lng[c * 8 + 4] + lnb[c * 8 + 4];
    float w5 = (v[h * 8 + 5] - mean) * inv * lng[c * 8 + 5] + lnb[c * 8 + 5];
    float w6 = (v[h * 8 + 6] - mean) * inv * lng[c * 8 + 6] + lnb[c * 8 + 6];
    float w7 = (v[h * 8 + 7] - mean) * inv * lng[c * 8 + 7] + lnb[c * 8 + 7];
    u.x = (unsigned int)f2bf(w0) | ((unsigned int)f2bf(w1) << 16);
    u.y = (unsigned int)f2bf(w2) | ((unsigned int)f2bf(w3) << 16);
    u.z = (unsigned int)f2bf(w4) | ((unsigned int)f2bf(w5) << 16);
    u.w = (unsigned int)f2bf(w6) | ((unsigned int)f2bf(w7) << 16);
    *(uint4*)(dst + slot * 8) = u;
  }
}

// K5 (MFMA): out[M][Ncols] = A @ W^T + bias, f32 out. A,W bf16 swizzled.
__global__ __launch_bounds__(256) void k_gemm_mfma(
    const unsigned short* __restrict__ A, const unsigned short* __restrict__ W,
    const float* __restrict__ bias, float* __restrict__ out, int Ncols) {
  __shared__ unsigned short Al[128 * 128];
  __shared__ unsigned short Bl[64 * 128];
  int m0 = blockIdx.x << 7, n0 = blockIdx.y << 6;
  int t = threadIdx.x;
  int lane = t & 63, w = t >> 6;
  int n16 = lane & 15, q = lane >> 4;

  for (int j = 0; j < 8; ++j) {
    int seg = w * 8 + j;
    gl_lds16((const char*)A + (size_t)m0 * 256 + (seg << 10) + lane * 16,
             (char*)Al + (seg << 10));
  }
  for (int j = 0; j < 4; ++j) {
    int seg = w * 4 + j;
    gl_lds16((const char*)W + (size_t)n0 * 256 + (seg << 10) + lane * 16,
             (char*)Bl + (seg << 10));
  }
  __syncthreads();

  int wm = w >> 1, wn = w & 1;
  f32x4 acc[4][2];
#pragma unroll
  for (int mt = 0; mt < 4; ++mt)
#pragma unroll
    for (int nt = 0; nt < 2; ++nt) acc[mt][nt] = (f32x4){0.f, 0.f, 0.f, 0.f};

#pragma unroll
  for (int kf = 0; kf < 4; ++kf) {
    int ca = kf * 4 + q;
    int rA0 = wm * 64 + n16;
    const unsigned short* Ap0 = Al + (size_t)rA0 * 128;
    int slotA = (ca & 8) | ((ca & 7) ^ (rA0 & 7));
    short8 a0 = *(const short8*)(Ap0 + slotA * 8);
    short8 a1 = *(const short8*)(Ap0 + 16 * 128 + slotA * 8);
    short8 a2 = *(const short8*)(Ap0 + 32 * 128 + slotA * 8);
    short8 a3 = *(const short8*)(Ap0 + 48 * 128 + slotA * 8);
    int rB0 = wn * 32 + n16;
    const unsigned short* Bp0 = Bl + (size_t)rB0 * 128;
    int slotB = (ca & 8) | ((ca & 7) ^ (rB0 & 7));
    short8 b0 = *(const short8*)(Bp0 + slotB * 8);
    short8 b1 = *(const short8*)(Bp0 + 16 * 128 + slotB * 8);
    acc[0][0] = __builtin_amdgcn_mfma_f32_16x16x32_bf16(a0, b0, acc[0][0], 0, 0, 0);
    acc[0][1] = __builtin_amdgcn_mfma_f32_16x16x32_bf16(a0, b1, acc[0][1], 0, 0, 0);
    acc[1][0] = __builtin_amdgcn_mfma_f32_16x16x32_bf16(a1, b0, acc[1][0], 0, 0, 0);
    acc[1][1] = __builtin_amdgcn_mfma_f32_16x16x32_bf16(a1, b1, acc[1][1], 0, 0, 0);
    acc[2][0] = __builtin_amdgcn_mfma_f32_16x16x32_bf16(a2, b0, acc[2][0], 0, 0, 0);
    acc[2][1] = __builtin_amdgcn_mfma_f32_16x16x32_bf16(a2, b1, acc[2][1], 0, 0, 0);
    acc[3][0] = __builtin_amdgcn_mfma_f32_16x16x32_bf16(a3, b0, acc[3][0], 0, 0, 0);
    acc[3][1] = __builtin_amdgcn_mfma_f32_16x16x32_bf16(a3, b1, acc[3][1], 0, 0, 0);
  }

#pragma unroll
  for (int mt = 0; mt < 4; ++mt) {
#pragma unroll
    for (int i = 0; i < 4; ++i) {
      int m = m0 + wm * 64 + mt * 16 + q * 4 + i;
#pragma unroll
      for (int nt = 0; nt < 2; ++nt) {
        int n = n0 + wn * 32 + nt * 16 + n16;
        out[(size_t)m * Ncols + n] = acc[mt][nt][i] + bias[n];
      }
    }
  }
}

// K_projm (MFMA): xv2[b][c][n] = (atth @ proj_w^T)[m][c] + proj_b[c] + ori[m][c]
// atth bf16 swizzled rows (m = b*1024+n). Transposed float4 epilogue.
__global__ __launch_bounds__(256) void k_proj_mfma(
    const unsigned short* __restrict__ A, const unsigned short* __restrict__ W,
    const float* __restrict__ bias, const float* __restrict__ ori,
    float* __restrict__ xv2) {
  __shared__ unsigned short Al[128 * 128];
  __shared__ unsigned short Bl[64 * 128];
  int m0 = blockIdx.x << 7, n0 = blockIdx.y << 6;
  int t = threadIdx.x;
  int lane = t & 63, w = t >> 6;
  int n16 = lane & 15, q = lane >> 4;

  for (int j = 0; j < 8; ++j) {
    int seg = w * 8 + j;
    gl_lds16((const char*)A + (size_t)m0 * 256 + (seg << 10) + lane * 16,
             (char*)Al + (seg << 10));
  }
  for (int j = 0; j < 4; ++j) {
    int seg = w * 4 + j;
    gl_lds16((const char*)W + (size_t)n0 * 256 + (seg << 10) + lane * 16,
             (char*)Bl + (seg << 10));
  }
  __syncthreads();

  int wm = w >> 1, wn = w & 1;
  f32x4 acc[4][2];
#pragma unroll
  for (int mt = 0; mt < 4; ++mt)
#pragma unroll
    for (int nt = 0; nt < 2; ++nt) acc[mt][nt] = (f32x4){0.f, 0.f, 0.f, 0.f};

#pragma unroll
  for (int kf = 0; kf < 4; ++kf) {
    int ca = kf * 4 + q;
    int rA0 = wm * 64 + n16;
    const unsigned short* Ap0 = Al + (size_t)rA0 * 128;
    int slotA = (ca & 8) | ((ca & 7) ^ (rA0 & 7));
    short8 a0 = *(const short8*)(Ap0 + slotA * 8);
    short8 a1 = *(const short8*)(Ap0 + 16 * 128 + slotA * 8);
    short8 a2 = *(const short8*)(Ap0 + 32 * 128 + slotA * 8);
    short8 a3 = *(const short8*)(Ap0 + 48 * 128 + slotA * 8);
    int rB0 = wn * 32 + n16;
    const unsigned short* Bp0 = Bl + (size_t)rB0 * 128;
    int slotB = (ca & 8) | ((ca & 7) ^ (rB0 & 7));
    short8 b0 = *(const short8*)(Bp0 + slotB * 8);
    short8 b1 = *(const short8*)(Bp0 + 16 * 128 + slotB * 8);
    acc[0][0] = __builtin_amdgcn_mfma_f32_16x16x32_bf16(a0, b0, acc[0][0], 0, 0, 0);
    acc[0][1] = __builtin_amdgcn_mfma_f32_16x16x32_bf16(a0, b1, acc[0][1], 0, 0, 0);
    acc[1][0] = __builtin_amdgcn_mfma_f32_16x16x32_bf16(a1, b0, acc[1][0], 0, 0, 0);
    acc[1][1] = __builtin_amdgcn_mfma_f32_16x16x32_bf16(a1, b1, acc[1][1], 0, 0, 0);
    acc[2][0] = __builtin_amdgcn_mfma_f32_16x16x32_bf16(a2, b0, acc[2][0], 0, 0, 0);
    acc[2][1] = __builtin_amdgcn_mfma_f32_16x16x32_bf16(a2, b1, acc[2][1], 0, 0, 0);
    acc[3][0] = __builtin_amdgcn_mfma_f32_16x16x32_bf16(a3, b0, acc[3][0], 0, 0, 0);
    acc[3][1] = __builtin_amdgcn_mfma_f32_16x16x32_bf16(a3, b1, acc[3][1], 0, 0, 0);
  }

  int bb = m0 >> 10;                       // 1024 % 128 == 0: b fixed per tile
  int nbase = (m0 & 1023) + wm * 64;
#pragma unroll
  for (int mt = 0; mt < 4; ++mt) {
    int nloc = nbase + mt * 16 + q * 4;
    const float* orow = ori + ((size_t)bb * 1024 + nloc) * 128;
#pragma unroll
    for (int nt = 0; nt < 2; ++nt) {
      int c = n0 + wn * 32 + nt * 16 + n16;
      float pb = bias[c];
      float4 vv;
      vv.x = acc[mt][nt][0] + pb + orow[c];
      vv.y = acc[mt][nt][1] + pb + orow[128 + c];
      vv.z = acc[mt][nt][2] + pb + orow[256 + c];
      vv.w = acc[mt][nt][3] + pb + orow[384 + c];
      *(float4*)(xv2 + ((size_t)bb * 128 + c) * 1024 + nloc) = vv;
    }
  }
}

// K_cvt: qkvb f32 -> qkb bf16 [b][h][{q,k}][1024][32]; yvbuf -> vtb bf16 transposed.
__global__ __launch_bounds__(256) void k_cvt(const float* __restrict__ qkv,
                                             const float* __restrict__ yv,
                                             unsigned short* __restrict__ qkb,
                                             unsigned short* __restrict__ vtb) {
  int nt = blockIdx.x, b = blockIdx.y;
  int n0 = nt << 6;
  int t = threadIdx.x;
  __shared__ unsigned short tl[64 * 132];
  const float* qb = qkv + ((size_t)b * 1024 + n0) * 384;
  for (int it = 0; it < 16; ++it) {
    int idx = it * 256 + t;
    int n = idx >> 6, c4 = idx & 63;
    float4 v = *(const float4*)(qb + (size_t)n * 384 + c4 * 4);
    int c = c4 << 2;
    int kind = c >> 7, h = (c >> 5) & 3, d = c & 31;
    uint2 u;
    u.x = (unsigned int)f2bf(v.x) | ((unsigned int)f2bf(v.y) << 16);
    u.y = (unsigned int)f2bf(v.z) | ((unsigned int)f2bf(v.w) << 16);
    *(uint2*)(qkb + ((((size_t)b * 4 + h) * 2 + kind) * 1024 + n0 + n) * 32 + d) = u;
  }
  const float* vb = yv + ((size_t)b * 1024 + n0) * 128;
  for (int it = 0; it < 8; ++it) {
    int idx = it * 256 + t;
    int n = idx >> 5, c4 = idx & 31;
    float4 v = *(const float4*)(vb + (size_t)n * 128 + c4 * 4);
    unsigned short* o = tl + n * 132 + c4 * 4;
    o[0] = f2bf(v.x); o[1] = f2bf(v.y); o[2] = f2bf(v.z); o[3] = f2bf(v.w);
  }
  __syncthreads();
  int c = t >> 1, half = t & 1;
  unsigned short* orow = vtb + (((size_t)b * 4 + (c >> 5)) * 32 + (c & 31)) * 1024 + n0 + half * 32;
#pragma unroll
  for (int k = 0; k < 4; ++k) {
    short8 pack;
#pragma unroll
    for (int j = 0; j < 8; ++j)
      pack[j] = (short)tl[(half * 32 + k * 8 + j) * 132 + c];
    *(short8*)(orow + k * 8) = pack;
  }
}

// K6 (MFMA): flash attention; swapped QK^T. Epilogue writes bf16 swizzled atth.
__global__ __launch_bounds__(256) void k_attn(const float* __restrict__ qkv,
                                              const unsigned short* __restrict__ qkb,
                                              const unsigned short* __restrict__ vtb,
                                              unsigned short* __restrict__ atth) {
  int qt = blockIdx.x, h = blockIdx.y, b = blockIdx.z;
  __shared__ unsigned short Qs[64 * 40];
  __shared__ unsigned short Ks[64 * 40];
  __shared__ unsigned short Vt[32 * 72];
  __shared__ unsigned short Pw[4 * 16 * 68];
  int t = threadIdx.x;
  int lane = t & 63, w = t >> 6;
  int quad = lane >> 4, l16 = lane & 15;
  const float* qbase = qkv + (size_t)b * 1024 * 384;
  const unsigned short* qrow = qkb + (((size_t)b * 4 + h) * 2 + 0) * 1024 * 32;
  const unsigned short* krow = qkb + (((size_t)b * 4 + h) * 2 + 1) * 1024 * 32;
  const unsigned short* vrow = vtb + ((size_t)b * 4 + h) * 32 * 1024;
  int q0 = qt << 6;
  int hd = h * 32;

  {
    int r = t >> 2, cq = t & 3;
    short8 v = *(const short8*)(qrow + (size_t)(q0 + r) * 32 + cq * 8);
    *(short8*)(Qs + r * 40 + cq * 8) = v;
  }
  __syncthreads();
  short8 aq = *(const short8*)(Qs + (w * 16 + l16) * 40 + quad * 8);

  f32x4 O[2];
  O[0] = (f32x4){0.f, 0.f, 0.f, 0.f};
  O[1] = (f32x4){0.f, 0.f, 0.f, 0.f};
  float mi0 = -1e30f, li0 = 0.f;
  unsigned short* Pme = Pw + w * (16 * 68);
  const float scl = 0.17677669529663688f;

  for (int ci = 0; ci < 16; ++ci) {
    __syncthreads();
    int kn0 = ci << 6;
    {
      int r = t >> 2, cq = t & 3;
      short8 kv = *(const short8*)(krow + (size_t)(kn0 + r) * 32 + cq * 8);
      *(short8*)(Ks + r * 40 + cq * 8) = kv;
      int d = t >> 3, cc = t & 7;
      short8 vv = *(const short8*)(vrow + (size_t)d * 1024 + kn0 + cc * 8);
      *(short8*)(Vt + d * 72 + cc * 8) = vv;
    }
    __syncthreads();

    f32x4 S[4];
#pragma unroll
    for (int nt = 0; nt < 4; ++nt) S[nt] = (f32x4){0.f, 0.f, 0.f, 0.f};
#pragma unroll
    for (int nt = 0; nt < 4; ++nt) {
      short8 bk = *(const short8*)(Ks + (nt * 16 + l16) * 40 + quad * 8);
      S[nt] = __builtin_amdgcn_mfma_f32_16x16x32_bf16(bk, aq, S[nt], 0, 0, 0);
    }

    float sv[16];
#pragma unroll
    for (int nt = 0; nt < 4; ++nt)
#pragma unroll
      for (int r = 0; r < 4; ++r) sv[nt * 4 + r] = S[nt][r] * scl;
    float m0 = fmaxf(fmaxf(sv[0], sv[1]), fmaxf(sv[2], sv[3]));
    float m1 = fmaxf(fmaxf(sv[4], sv[5]), fmaxf(sv[6], sv[7]));
    float m2 = fmaxf(fmaxf(sv[8], sv[9]), fmaxf(sv[10], sv[11]));
    float m3 = fmaxf(fmaxf(sv[12], sv[13]), fmaxf(sv[14], sv[15]));
    float rm = fmaxf(fmaxf(m0, m1), fmaxf(m2, m3));
    rm = fmaxf(rm, __shfl_xor(rm, 16));
    rm = fmaxf(rm, __shfl_xor(rm, 32));
    float nm = fmaxf(mi0, rm);
    float alpha = __expf(mi0 - nm);
    mi0 = nm;

    float psnt[4];
    unsigned short* pwr = Pme + l16 * 68 + quad * 4;
#pragma unroll
    for (int nt = 0; nt < 4; ++nt) {
      float p0 = __expf(sv[nt * 4 + 0] - nm);
      float p1 = __expf(sv[nt * 4 + 1] - nm);
      float p2 = __expf(sv[nt * 4 + 2] - nm);
      float p3 = __expf(sv[nt * 4 + 3] - nm);
      psnt[nt] = (p0 + p1) + (p2 + p3);
      uint2 u;
      u.x = (unsigned int)f2bf(p0) | ((unsigned int)f2bf(p1) << 16);
      u.y = (unsigned int)f2bf(p2) | ((unsigned int)f2bf(p3) << 16);
      *(uint2*)(pwr + nt * 16) = u;
    }
    float ps = (psnt[0] + psnt[1]) + (psnt[2] + psnt[3]);
    ps += __shfl_xor(ps, 16);
    ps += __shfl_xor(ps, 32);
    li0 = li0 * alpha + ps;

    float al0 = __shfl(alpha, quad * 4 + 0);
    float al1 = __shfl(alpha, quad * 4 + 1);
    float al2 = __shfl(alpha, quad * 4 + 2);
    float al3 = __shfl(alpha, quad * 4 + 3);
    O[0][0] *= al0; O[1][0] *= al0;
    O[0][1] *= al1; O[1][1] *= al1;
    O[0][2] *= al2; O[1][2] *= al2;
    O[0][3] *= al3; O[1][3] *= al3;

#pragma unroll
    for (int kc = 0; kc < 2; ++kc) {
      short8 bv0 = *(const short8*)(Vt + l16 * 72 + kc * 32 + quad * 8);
      short8 bv1 = *(const short8*)(Vt + (16 + l16) * 72 + kc * 32 + quad * 8);
      short8 ap = *(const short8*)(Pme + l16 * 68 + kc * 32 + quad * 8);
      O[0] = __builtin_amdgcn_mfma_f32_16x16x32_bf16(ap, bv0, O[0], 0, 0, 0);
      O[1] = __builtin_amdgcn_mfma_f32_16x16x32_bf16(ap, bv1, O[1], 0, 0, 0);
    }
  }

#pragma unroll
  for (int reg = 0; reg < 4; ++reg) {
    float lit = __shfl(li0, quad * 4 + reg);
    int n = q0 + w * 16 + quad * 4 + reg;
    float inv = 1.f / lit;
    size_t mrow = ((size_t)b * 1024 + n) * 128;
    int m7 = n & 7;
#pragma unroll
    for (int nt = 0; nt < 2; ++nt) {
      int dd = hd + nt * 16 + l16;
      float val = O[nt][reg] * inv + qbase[(size_t)n * 384 + 256 + dd];
      int ch = dd >> 3;
      int slot = (ch & 8) | ((ch & 7) ^ m7);
      atth[mrow + slot * 8 + (dd & 7)] = f2bf(val);
    }
  }
}

// K8: conv1d over n + residual. NB=32 + single-buffered LDS weights.
__global__ __launch_bounds__(256) void k_conv1d(
    const float* __restrict__ xv2, const float* __restrict__ cwt,
    float* __restrict__ xv3) {
  extern __shared__ char cs[];
  float* xl = (float*)cs;                   // [128][36], 18432 B
  float* wl = (float*)(cs + 18432);         // [40][128], 20480 B
  int nt = blockIdx.x, b = blockIdx.y;
  int n0 = nt << 5;
  int t = threadIdx.x;
  int lane = t & 63, w = t >> 6;
  const float* xb = xv2 + (size_t)b * 128 * 1024;
  for (int idx = t; idx < 4608; idx += 256) {
    int ic = idx / 36, j = idx - ic * 36;
    int n = n0 + j - 2;
    xl[idx] = (n >= 0 && n < 1024) ? xb[(size_t)ic * 1024 + n] : 0.f;
  }

  int oc = t & 127, g = t >> 7;
  float acc[16];
#pragma unroll
  for (int i = 0; i < 16; ++i) acc[i] = 0.f;

#pragma unroll 1
  for (int ch = 0; ch < 16; ++ch) {
    __syncthreads();
#pragma unroll
    for (int j = 0; j < 5; ++j) {
      int seg = w * 5 + j;
      gl_lds16((const char*)cwt + (size_t)ch * 20480 + (seg << 10) + lane * 16,
               (char*)wl + (seg << 10));
    }
    __syncthreads();

#pragma unroll
    for (int icl = 0; icl < 8; ++icl) {
      int ic = ch * 8 + icl;
      const float* xr = xl + ic * 36 + (g << 4);
      float xw[20];
#pragma unroll
      for (int q2 = 0; q2 < 5; ++q2) {
        float4 v = *(const float4*)(xr + q2 * 4);
        xw[q2 * 4] = v.x; xw[q2 * 4 + 1] = v.y; xw[q2 * 4 + 2] = v.z; xw[q2 * 4 + 3] = v.w;
      }
      const float* wr = wl + icl * 5 * 128 + oc;
      float w0 = wr[0], w1 = wr[128], w2 = wr[256], w3 = wr[384], w4 = wr[512];
#pragma unroll
      for (int i = 0; i < 16; ++i)
        acc[i] = fmaf(xw[i], w0, fmaf(xw[i + 1], w1, fmaf(xw[i + 2], w2,
                 fmaf(xw[i + 3], w3, fmaf(xw[i + 4], w4, acc[i])))));
    }
  }

  const float* res = xb + (size_t)oc * 1024 + n0 + (g << 4);
  float* outp = xv3 + ((size_t)b * 128 + oc) * 1024 + n0 + (g << 4);
#pragma unroll
  for (int q2 = 0; q2 < 4; ++q2) {
    float4 r = *(const float4*)(res + q2 * 4);
    float4 o_;
    o_.x = r.x + acc[q2 * 4 + 0];
    o_.y = r.y + acc[q2 * 4 + 1];
    o_.z = r.z + acc[q2 * 4 + 2];
    o_.w = r.w + acc[q2 * 4 + 3];
    *(float4*)(outp + q2 * 4) = o_;
  }
}

// K9: bilinear 32->96 align_corners=True, f32 out
__global__ __launch_bounds__(256) void k_bilinear(const float* __restrict__ xv3,
                                                  float* __restrict__ out) {
  int idx = blockIdx.x * 256 + threadIdx.x;
  int X = idx % 96;
  int t2 = idx / 96;
  int Y = t2 % 96;
  int bc = t2 / 96;
  const float* src = xv3 + (size_t)bc * 1024;
  const float r = 31.f / 95.f;
  float py = Y * r, px = X * r;
  int y0 = (int)py, x0 = (int)px;
  float wy = py - y0, wx = px - x0;
  int y1 = y0 < 31 ? y0 + 1 : 31, x1 = x0 < 31 ? x0 + 1 : 31;
  float a = src[y0 * 32 + x0], b_ = src[y0 * 32 + x1];
  float c_ = src[y1 * 32 + x0], d_ = src[y1 * 32 + x1];
  float t0 = a * (1.f - wy) + c_ * wy;
  float t1 = b_ * (1.f - wy) + d_ * wy;
  out[idx] = t0 * (1.f - wx) + t1 * wx;
}

extern "C" void kernel_launch(void* const* d_in, const int* in_sizes, int n_in,
                              void* d_out, int out_size, void* d_ws, size_t ws_size,
                              hipStream_t stream) {
  (void)in_sizes; (void)n_in; (void)out_size; (void)ws_size;
  const float* s1    = (const float*)d_in[0];
  const float* o     = (const float*)d_in[1];
  const int*   indx  = (const int*)d_in[2];
  const float* pe_w  = (const float*)d_in[3];
  const float* bn_g  = (const float*)d_in[4];
  const float* bn_b  = (const float*)d_in[5];
  const float* bn_m  = (const float*)d_in[6];
  const float* bn_v  = (const float*)d_in[7];
  const float* lnx_g = (const float*)d_in[8];
  const float* lnx_b = (const float*)d_in[9];
  const float* lny_g = (const float*)d_in[10];
  const float* lny_b = (const float*)d_in[11];
  const float* qkv_w = (const float*)d_in[12];
  const float* qkv_b = (const float*)d_in[13];
  const float* yv_w  = (const float*)d_in[14];
  const float* yv_b  = (const float*)d_in[15];
  const float* proj_w = (const float*)d_in[16];
  const float* proj_b = (const float*)d_in[17];
  const float* c1d_w  = (const float*)d_in[18];

  char* ws = (char*)d_ws;
  unsigned short* xTh = (unsigned short*)ws;
  unsigned short* ymh = (unsigned short*)(ws + 37748736);
  // d_out scratch: wpk +0 (41KB); cwt +64KB (328KB); wqkh +448KB (98KB);
  // wyvh +560KB (32KB); wprh +608KB (32KB).
  unsigned short* wpk = (unsigned short*)d_out;
  float* cwt = (float*)((char*)d_out + 65536);
  unsigned short* wqkh = (unsigned short*)((char*)d_out + 458752);
  unsigned short* wyvh = (unsigned short*)((char*)d_out + 573440);
  unsigned short* wprh = (unsigned short*)((char*)d_out + 622592);
  // Phase 2 (xTh dead after k_conv_pe): region A = [ws+0, 37.7MB)
  float* ori  = (float*)ws;                 // [0, 8.4MB)
  unsigned short* snh  = (unsigned short*)(ws + 8388608);   // 4.2MB bf16
  unsigned short* oflh = (unsigned short*)(ws + 16777216);  // 4.2MB bf16
  unsigned short* atth = (unsigned short*)(ws + 25165824);  // 4.2MB bf16
  // Phase 3 (ymh dead after k_pool9ln): region B = [ws+37.7MB, 75.5MB)
  float* qkvb  = (float*)(ws + 37748736);   // 25.2MB
  float* yvbuf = (float*)(ws + 62914560);   // 8.4MB, dead after k_cvt
  unsigned short* qkb = (unsigned short*)(ws + 16777216);  // alias oflh (dead), 8.4MB
  unsigned short* vtb = (unsigned short*)(ws + 71303168);  // tail, 4.2MB
  float* xv2   = (float*)(ws + 37748736);   // alias qkvb (dead after k_attn)
  float* xv3   = (float*)(ws + 46137344);

  hipLaunchKernelGGL(k_prep, dim3(8), dim3(256), 0, stream, pe_w, wpk);
  hipLaunchKernelGGL(k_prepc, dim3(80), dim3(256), 0, stream, c1d_w, cwt);
  hipLaunchKernelGGL(k_prepw, dim3(24), dim3(256), 0, stream, qkv_w, wqkh, 384);
  hipLaunchKernelGGL(k_prepw, dim3(8), dim3(256), 0, stream, yv_w, wyvh, 128);
  hipLaunchKernelGGL(k_prepw, dim3(8), dim3(256), 0, stream, proj_w, wprh, 128);
  hipLaunchKernelGGL(k_transpose, dim3(128, 16), dim3(256), 0, stream, s1, xTh);
  hipLaunchKernelGGL(k_conv_pe, dim3(36, 16), dim3(256), 75008, stream,
                     xTh, wpk, bn_g, bn_b, bn_m, bn_v, indx, ymh);
  hipLaunchKernelGGL(k_pool9ln, dim3(64, 16), dim3(256), 0, stream, ymh, lny_g, lny_b, ori, snh);
  hipLaunchKernelGGL(k_poolo_ln, dim3(32, 16), dim3(256), 0, stream, o, lnx_g, lnx_b, oflh);
  hipLaunchKernelGGL(k_gemm_mfma, dim3(128, 6), dim3(256), 0, stream, oflh, wqkh, qkv_b, qkvb, 384);
  hipLaunchKernelGGL(k_gemm_mfma, dim3(128, 2), dim3(256), 0, stream, snh, wyvh, yv_b, yvbuf, 128);
  hipLaunchKernelGGL(k_cvt, dim3(16, 16), dim3(256), 0, stream, qkvb, yvbuf, qkb, vtb);
  hipLaunchKernelGGL(k_attn, dim3(16, 4, 16), dim3(256), 0, stream, qkvb, qkb, vtb, atth);
  hipLaunchKernelGGL(k_proj_mfma, dim3(128, 2), dim3(256), 0, stream, atth, wprh, proj_b, ori, xv2);
  hipLaunchKernelGGL(k_conv1d, dim3(32, 16), dim3(256), 38912, stream, xv2, cwt, xv3);
  hipLaunchKernelGGL(k_bilinear, dim3(73728), dim3(256), 0, stream, xv3, (float*)d_out);
}

// Round 15
// 355.435 us; speedup vs baseline: 1.6706x; 1.1075x over previous
//
#include <hip/hip_runtime.h>

#define FEAT 18432

typedef __attribute__((ext_vector_type(8))) short short8;
typedef __attribute__((ext_vector_type(4))) float f32x4;

__device__ __forceinline__ float b2f(unsigned short s) {
  union { unsigned int u; float f; } v; v.u = ((unsigned int)s) << 16; return v.f;
}
__device__ __forceinline__ unsigned short f2bf(float x) {
  union { float f; unsigned int u; } v; v.f = x;
  unsigned int u = v.u;
  unsigned int r = (u + 0x7FFFu + ((u >> 16) & 1u)) >> 16;
  return (unsigned short)r;
}

// async global->LDS, 16B per lane; LDS dest = base + lane*16 (wave-uniform base)
__device__ __forceinline__ void gl_lds16(const void* g, void* l) {
  __builtin_amdgcn_global_load_lds(
      (const __attribute__((address_space(1))) unsigned int*)g,
      (__attribute__((address_space(3))) unsigned int*)l, 16, 0, 0);
}

// K0: s1[b][c][96][96] (f32) -> xTn[b][f][ic] bf16, swizzled 16B chunks.
__global__ __launch_bounds__(256) void k_transpose(const float* __restrict__ s1,
                                                   unsigned short* __restrict__ xT) {
  int c = blockIdx.x, b = blockIdx.y;
  __shared__ float lds[96 * 99];            // plane [h][w], pad 99
  int t = threadIdx.x;
  const float* src = s1 + ((size_t)b * 128 + c) * 9216;
  for (int idx = t; idx < 2304; idx += 256) {
    float4 v = ((const float4*)src)[idx];
    int h = idx / 24, w0 = (idx - h * 24) * 4;
    float* p = lds + h * 99 + w0;
    p[0] = v.x; p[1] = v.y; p[2] = v.z; p[3] = v.w;
  }
  __syncthreads();
  unsigned short* dstb = xT + (size_t)b * FEAT * 64;
  int sw = c & 7;
  for (int idx = t; idx < 1152; idx += 256) {
    int p1p2 = idx >> 3, gh = idx & 7;
    int p1 = p1p2 / 12, p2 = p1p2 - p1 * 12;
    const float* row = lds + (gh * 12 + p1) * 99 + p2;
    uint4 u;
    u.x = f2bf(row[0])  | ((unsigned int)f2bf(row[12]) << 16);
    u.y = f2bf(row[24]) | ((unsigned int)f2bf(row[36]) << 16);
    u.z = f2bf(row[48]) | ((unsigned int)f2bf(row[60]) << 16);
    u.w = f2bf(row[72]) | ((unsigned int)f2bf(row[84]) << 16);
    int f = p1p2 * 128 + c;
    int pos = gh ^ sw;
    *(uint4*)(dstb + (size_t)f * 64 + pos * 8) = u;
  }
}

// K_prep: pack pe_w -> wpk[oc][320] bf16 with chunk swizzle
__global__ __launch_bounds__(256) void k_prep(const float* __restrict__ pe_w,
                                              unsigned short* __restrict__ wpk) {
  int oc0 = blockIdx.x * 8;
  for (int e = threadIdx.x; e < 2560; e += 256) {
    int oc = oc0 + e / 320;
    int kL = e - (e / 320) * 320;
    int ic = kL & 63, kk = kL >> 6;
    float v = pe_w[(oc * 64 + ic) * 5 + kk];
    int LC = kL >> 3;
    int pos = (LC & 56) | ((LC & 7) ^ (oc & 7));
    wpk[oc * 320 + (pos << 3) + (kL & 7)] = f2bf(v);
  }
}

// K_prepcw: pack c1d_w[oc][ic][5] f32 -> wch[ochalf][64][640] bf16, k=kk*128+ic,
// 16B-chunk swizzle: pos = (LC&120) | ((LC&7)^(oc&7)).
__global__ __launch_bounds__(256) void k_prepcw(const float* __restrict__ cw,
                                                unsigned short* __restrict__ wch) {
  int e = blockIdx.x * 256 + threadIdx.x;    // 320 blocks x 256 = 81920
  int oc = e / 640, kl = e - (e / 640) * 640;
  int kk = kl >> 7, ic = kl & 127;
  float v = cw[(size_t)oc * 640 + ic * 5 + kk];
  int LC = kl >> 3;
  int pos = (LC & 120) | ((LC & 7) ^ (oc & 7));
  wch[(size_t)oc * 640 + pos * 8 + (kl & 7)] = f2bf(v);
}

// K_prepw: pack GEMM weights W[ncols][128] f32 -> bf16 swizzled rows.
__global__ __launch_bounds__(256) void k_prepw(const float* __restrict__ W,
                                               unsigned short* __restrict__ dst,
                                               int ncols) {
  int idx = blockIdx.x * 256 + threadIdx.x;
  if (idx >= ncols * 16) return;
  int n = idx >> 4, c = idx & 15;
  int slot = (c & 8) | ((c & 7) ^ (n & 7));
  const float* s = W + (size_t)n * 128 + c * 8;
  uint4 u;
  u.x = (unsigned int)f2bf(s[0]) | ((unsigned int)f2bf(s[1]) << 16);
  u.y = (unsigned int)f2bf(s[2]) | ((unsigned int)f2bf(s[3]) << 16);
  u.z = (unsigned int)f2bf(s[4]) | ((unsigned int)f2bf(s[5]) << 16);
  u.w = (unsigned int)f2bf(s[6]) | ((unsigned int)f2bf(s[7]) << 16);
  *(uint4*)(dst + (size_t)n * 128 + slot * 8) = u;
}

// K1 (MFMA): conv1d over f as GEMM + BN(eval) + ReLU + selective square.
__global__ __launch_bounds__(256) void k_conv_pe(
    const unsigned short* __restrict__ xT, const unsigned short* __restrict__ wpk,
    const float* __restrict__ bn_g, const float* __restrict__ bn_b,
    const float* __restrict__ bn_m, const float* __restrict__ bn_v,
    const int* __restrict__ indexp, unsigned short* __restrict__ ym) {
  extern __shared__ char smem[];
  unsigned short* Wl = (unsigned short*)smem;
  unsigned short* xl = (unsigned short*)(smem + 40960);
  float* scf = (float*)(smem + 74240);
  float* shf = (float*)(smem + 74496);
  int*   sli = (int*)(smem + 74752);
  int t = threadIdx.x;
  int b = blockIdx.y;
  int blk_f0 = blockIdx.x << 9;
  int lane = t & 63, w = t >> 6;
  int n16 = lane & 15, q = lane >> 4;

  for (int j = 0; j < 10; ++j) {
    int seg = w * 10 + j;
    gl_lds16((const char*)wpk + (seg << 10) + lane * 16, (char*)Wl + (seg << 10));
  }
  if (t < 64) {
    float sc = bn_g[t] * rsqrtf(bn_v[t] + 1e-5f);
    scf[t] = sc;
    shf[t] = bn_b[t] - bn_m[t] * sc;
    int i0 = indexp[0] / 12 * 8 + indexp[1] / 12;
    int i1 = indexp[2] / 12 * 8 + indexp[3] / 12;
    int i2 = indexp[4] / 12 * 8 + indexp[5] / 12;
    int i3 = indexp[6] / 12 * 8 + indexp[7] / 12;
    sli[t] = (t == i0 || t == i1 || t == i2 || t == i3) ? 1 : 0;
  }

  const unsigned short* xb = xT + (size_t)b * FEAT * 64;
  const unsigned int* xbu = (const unsigned int*)xb;

  for (int wnd = 0; wnd < 2; ++wnd) {
    int F0 = blk_f0 + (wnd << 8);
    __syncthreads();
    int flA = (F0 == 0) ? 2 : 0;
    for (int j = 0; j < 8; ++j) {
      int seg = (w << 3) + j;
      int gRow = F0 - 2 + flA + (seg << 3);
      gl_lds16((const char*)xb + (size_t)gRow * 128 + lane * 16,
               (char*)xl + flA * 128 + (seg << 10));
    }
    if (t < 128) {
      int r0 = (flA == 2) ? 0 : 256;
      int fl = (t < 64) ? (r0 + (t >> 5)) : (258 + ((t >> 5) & 1));
      int j = t & 31;
      int f = F0 - 2 + fl;
      unsigned int v = 0;
      if (f >= 0 && f < FEAT) v = xbu[(size_t)f * 32 + j];
      ((unsigned int*)xl)[fl * 32 + j] = v;
    }
    __syncthreads();

    f32x4 acc[4][4];
#pragma unroll
    for (int mt = 0; mt < 4; ++mt)
#pragma unroll
      for (int nt = 0; nt < 4; ++nt) acc[mt][nt] = (f32x4){0.f, 0.f, 0.f, 0.f};

    int rowB = w * 64 + n16;
#pragma unroll
    for (int kk = 0; kk < 5; ++kk) {
      int swb = (n16 + kk + 6) & 7;
#pragma unroll
      for (int ih = 0; ih < 2; ++ih) {
        int ca = (ih << 2) | q;
        const unsigned short* Ap = Wl + kk * 64 + ((ca ^ (n16 & 7)) << 3) + n16 * 320;
        short8 a0 = *(const short8*)(Ap);
        short8 a1 = *(const short8*)(Ap + 16 * 320);
        short8 a2 = *(const short8*)(Ap + 32 * 320);
        short8 a3 = *(const short8*)(Ap + 48 * 320);
        const unsigned short* Bp = xl + ((ca ^ swb) << 3) + (rowB + kk) * 64;
        short8 b0 = *(const short8*)(Bp);
        short8 b1 = *(const short8*)(Bp + 16 * 64);
        short8 b2 = *(const short8*)(Bp + 32 * 64);
        short8 b3 = *(const short8*)(Bp + 48 * 64);
        acc[0][0] = __builtin_amdgcn_mfma_f32_16x16x32_bf16(a0, b0, acc[0][0], 0, 0, 0);
        acc[0][1] = __builtin_amdgcn_mfma_f32_16x16x32_bf16(a0, b1, acc[0][1], 0, 0, 0);
        acc[0][2] = __builtin_amdgcn_mfma_f32_16x16x32_bf16(a0, b2, acc[0][2], 0, 0, 0);
        acc[0][3] = __builtin_amdgcn_mfma_f32_16x16x32_bf16(a0, b3, acc[0][3], 0, 0, 0);
        acc[1][0] = __builtin_amdgcn_mfma_f32_16x16x32_bf16(a1, b0, acc[1][0], 0, 0, 0);
        acc[1][1] = __builtin_amdgcn_mfma_f32_16x16x32_bf16(a1, b1, acc[1][1], 0, 0, 0);
        acc[1][2] = __builtin_amdgcn_mfma_f32_16x16x32_bf16(a1, b2, acc[1][2], 0, 0, 0);
        acc[1][3] = __builtin_amdgcn_mfma_f32_16x16x32_bf16(a1, b3, acc[1][3], 0, 0, 0);
        acc[2][0] = __builtin_amdgcn_mfma_f32_16x16x32_bf16(a2, b0, acc[2][0], 0, 0, 0);
        acc[2][1] = __builtin_amdgcn_mfma_f32_16x16x32_bf16(a2, b1, acc[2][1], 0, 0, 0);
        acc[2][2] = __builtin_amdgcn_mfma_f32_16x16x32_bf16(a2, b2, acc[2][2], 0, 0, 0);
        acc[2][3] = __builtin_amdgcn_mfma_f32_16x16x32_bf16(a2, b3, acc[2][3], 0, 0, 0);
        acc[3][0] = __builtin_amdgcn_mfma_f32_16x16x32_bf16(a3, b0, acc[3][0], 0, 0, 0);
        acc[3][1] = __builtin_amdgcn_mfma_f32_16x16x32_bf16(a3, b1, acc[3][1], 0, 0, 0);
        acc[3][2] = __builtin_amdgcn_mfma_f32_16x16x32_bf16(a3, b2, acc[3][2], 0, 0, 0);
        acc[3][3] = __builtin_amdgcn_mfma_f32_16x16x32_bf16(a3, b3, acc[3][3], 0, 0, 0);
      }
    }

#pragma unroll
    for (int mt = 0; mt < 4; ++mt) {
#pragma unroll
      for (int i = 0; i < 4; ++i) {
        int oc = mt * 16 + q * 4 + i;
        float sc = scf[oc], sh = shf[oc];
        bool sel = sli[oc] != 0;
        unsigned short* yo = ym + ((size_t)b * 64 + oc) * FEAT + F0 + w * 64 + n16;
#pragma unroll
        for (int nt = 0; nt < 4; ++nt) {
          float y = fmaf(acc[mt][nt][i], sc, sh);
          y = fmaxf(y, 0.f);
          if (!sel) y *= y;
          yo[nt * 16] = f2bf(y);
        }
      }
    }
  }
}

// K2: 3x3 avg pool 96->32 + fused LayerNorm. Writes ori (f32) + snh (bf16 swz).
__global__ __launch_bounds__(256) void k_pool9ln(
    const unsigned short* __restrict__ ym, const float* __restrict__ lng,
    const float* __restrict__ lnb, float* __restrict__ ori,
    unsigned short* __restrict__ snh) {
  int oc = blockIdx.x, b = blockIdx.y;
  const unsigned short* src = ym + ((size_t)b * 64 + oc) * FEAT;
  int oh0 = (oc >> 3) << 2, ow0 = (oc & 7) << 2;
  __shared__ float red[8];
  int t = threadIdx.x;
  int c = t & 127, hr = t >> 7, wv = t >> 6, l64 = t & 63;
  float g = lng[c], bb = lnb[c];
  for (int p = 0; p < 8; ++p) {
    int nl = p * 2 + hr;
    int pg1 = nl >> 2, pg2 = nl & 3;
    int pbase = (pg1 * 36 + pg2 * 3) * 128 + c;
    float s = 0.f;
#pragma unroll
    for (int dy = 0; dy < 3; ++dy)
#pragma unroll
      for (int dx = 0; dx < 3; ++dx)
        s += b2f(src[pbase + (dy * 12 + dx) * 128]);
    float val = s * (1.f / 9.f);
    float su = val, q = val * val;
#pragma unroll
    for (int off = 32; off > 0; off >>= 1) {
      su += __shfl_xor(su, off, 64);
      q += __shfl_xor(q, off, 64);
    }
    if (l64 == 0) { red[wv * 2] = su; red[wv * 2 + 1] = q; }
    __syncthreads();
    float S = red[hr * 4 + 0] + red[hr * 4 + 2];
    float Q = red[hr * 4 + 1] + red[hr * 4 + 3];
    float mean = S * (1.f / 128.f);
    float var = Q * (1.f / 128.f) - mean * mean;
    float inv = rsqrtf(var + 1e-5f);
    int n = (oh0 + pg1) * 32 + ow0 + pg2;
    size_t base = ((size_t)b * 1024 + n) * 128;
    ori[base + c] = val;
    float lnv = (val - mean) * inv * g + bb;
    int ch = c >> 3;
    int slot = (ch & 8) | ((ch & 7) ^ (n & 7));
    snh[base + slot * 8 + (c & 7)] = f2bf(lnv);
    __syncthreads();
  }
}

// K3: 2x2 avg pool of o + LayerNorm -> oflh bf16 swizzled
__global__ __launch_bounds__(256) void k_poolo_ln(
    const float* __restrict__ o, const float* __restrict__ lng,
    const float* __restrict__ lnb, unsigned short* __restrict__ oflh) {
  int y = blockIdx.x, b = blockIdx.y;
  __shared__ float pl[128 * 33];
  int t = threadIdx.x;
  for (int idx = t; idx < 4096; idx += 256) {
    int xo = idx & 31, c = idx >> 5;
    const float* p = o + (((size_t)b * 128 + c) * 64 + 2 * y) * 64 + 2 * xo;
    float2 a = *(const float2*)p;
    float2 d = *(const float2*)(p + 64);
    pl[c * 33 + xo] = 0.25f * (a.x + a.y + d.x + d.y);
  }
  __syncthreads();
  int xo = t >> 3, l8 = t & 7;
  float v[16]; float s = 0.f, q = 0.f;
#pragma unroll
  for (int i = 0; i < 16; ++i) {
    float x = pl[(l8 * 16 + i) * 33 + xo];
    v[i] = x; s += x; q += x * x;
  }
#pragma unroll
  for (int off = 1; off < 8; off <<= 1) {
    s += __shfl_xor(s, off, 8);
    q += __shfl_xor(q, off, 8);
  }
  float mean = s * (1.f / 128.f);
  float var = q * (1.f / 128.f) - mean * mean;
  float inv = rsqrtf(var + 1e-5f);
  int n = y * 32 + xo;
  unsigned short* dst = oflh + ((size_t)b * 1024 + n) * 128;
  int m7 = n & 7;
#pragma unroll
  for (int h = 0; h < 2; ++h) {
    int c = l8 * 2 + h;
    int slot = (c & 8) | ((c & 7) ^ m7);
    uint4 u;
    float w0 = (v[h * 8 + 0] - mean) * inv * lng[c * 8 + 0] + lnb[c * 8 + 0];
    float w1 = (v[h * 8 + 1] - mean) * inv * lng[c * 8 + 1] + lnb[c * 8 + 1];
    float w2 = (v[h * 8 + 2] - mean) * inv * lng[c * 8 + 2] + lnb[c * 8 + 2];
    float w3 = (v[h * 8 + 3] - mean) * inv * lng[c * 8 + 3] + lnb[c * 8 + 3];
    float w4 = (v[h * 8 + 4] - mean) * inv * lng[c * 8 + 4] + lnb[c * 8 + 4];
    float w5 = (v[h * 8 + 5] - mean) * inv * lng[c * 8 + 5] + lnb[c * 8 + 5];
    float w6 = (v[h * 8 + 6] - mean) * inv * lng[c * 8 + 6] + lnb[c * 8 + 6];
    float w7 = (v[h * 8 + 7] - mean) * inv * lng[c * 8 + 7] + lnb[c * 8 + 7];
    u.x = (unsigned int)f2bf(w0) | ((unsigned int)f2bf(w1) << 16);
    u.y = (unsigned int)f2bf(w2) | ((unsigned int)f2bf(w3) << 16);
    u.z = (unsigned int)f2bf(w4) | ((unsigned int)f2bf(w5) << 16);
    u.w = (unsigned int)f2bf(w6) | ((unsigned int)f2bf(w7) << 16);
    *(uint4*)(dst + slot * 8) = u;
  }
}

// K5 (MFMA): out[M][Ncols] = A @ W^T + bias, f32 out. A,W bf16 swizzled.
__global__ __launch_bounds__(256) void k_gemm_mfma(
    const unsigned short* __restrict__ A, const unsigned short* __restrict__ W,
    const float* __restrict__ bias, float* __restrict__ out, int Ncols) {
  __shared__ unsigned short Al[128 * 128];
  __shared__ unsigned short Bl[64 * 128];
  int m0 = blockIdx.x << 7, n0 = blockIdx.y << 6;
  int t = threadIdx.x;
  int lane = t & 63, w = t >> 6;
  int n16 = lane & 15, q = lane >> 4;

  for (int j = 0; j < 8; ++j) {
    int seg = w * 8 + j;
    gl_lds16((const char*)A + (size_t)m0 * 256 + (seg << 10) + lane * 16,
             (char*)Al + (seg << 10));
  }
  for (int j = 0; j < 4; ++j) {
    int seg = w * 4 + j;
    gl_lds16((const char*)W + (size_t)n0 * 256 + (seg << 10) + lane * 16,
             (char*)Bl + (seg << 10));
  }
  __syncthreads();

  int wm = w >> 1, wn = w & 1;
  f32x4 acc[4][2];
#pragma unroll
  for (int mt = 0; mt < 4; ++mt)
#pragma unroll
    for (int nt = 0; nt < 2; ++nt) acc[mt][nt] = (f32x4){0.f, 0.f, 0.f, 0.f};

#pragma unroll
  for (int kf = 0; kf < 4; ++kf) {
    int ca = kf * 4 + q;
    int rA0 = wm * 64 + n16;
    const unsigned short* Ap0 = Al + (size_t)rA0 * 128;
    int slotA = (ca & 8) | ((ca & 7) ^ (rA0 & 7));
    short8 a0 = *(const short8*)(Ap0 + slotA * 8);
    short8 a1 = *(const short8*)(Ap0 + 16 * 128 + slotA * 8);
    short8 a2 = *(const short8*)(Ap0 + 32 * 128 + slotA * 8);
    short8 a3 = *(const short8*)(Ap0 + 48 * 128 + slotA * 8);
    int rB0 = wn * 32 + n16;
    const unsigned short* Bp0 = Bl + (size_t)rB0 * 128;
    int slotB = (ca & 8) | ((ca & 7) ^ (rB0 & 7));
    short8 b0 = *(const short8*)(Bp0 + slotB * 8);
    short8 b1 = *(const short8*)(Bp0 + 16 * 128 + slotB * 8);
    acc[0][0] = __builtin_amdgcn_mfma_f32_16x16x32_bf16(a0, b0, acc[0][0], 0, 0, 0);
    acc[0][1] = __builtin_amdgcn_mfma_f32_16x16x32_bf16(a0, b1, acc[0][1], 0, 0, 0);
    acc[1][0] = __builtin_amdgcn_mfma_f32_16x16x32_bf16(a1, b0, acc[1][0], 0, 0, 0);
    acc[1][1] = __builtin_amdgcn_mfma_f32_16x16x32_bf16(a1, b1, acc[1][1], 0, 0, 0);
    acc[2][0] = __builtin_amdgcn_mfma_f32_16x16x32_bf16(a2, b0, acc[2][0], 0, 0, 0);
    acc[2][1] = __builtin_amdgcn_mfma_f32_16x16x32_bf16(a2, b1, acc[2][1], 0, 0, 0);
    acc[3][0] = __builtin_amdgcn_mfma_f32_16x16x32_bf16(a3, b0, acc[3][0], 0, 0, 0);
    acc[3][1] = __builtin_amdgcn_mfma_f32_16x16x32_bf16(a3, b1, acc[3][1], 0, 0, 0);
  }

#pragma unroll
  for (int mt = 0; mt < 4; ++mt) {
#pragma unroll
    for (int i = 0; i < 4; ++i) {
      int m = m0 + wm * 64 + mt * 16 + q * 4 + i;
#pragma unroll
      for (int nt = 0; nt < 2; ++nt) {
        int n = n0 + wn * 32 + nt * 16 + n16;
        out[(size_t)m * Ncols + n] = acc[mt][nt][i] + bias[n];
      }
    }
  }
}

// K_projm (MFMA): xv2[b][c][n] f32 + xph[b][n][c] bf16 (swizzled rows) =
// (atth @ proj_w^T) + proj_b + ori.
__global__ __launch_bounds__(256) void k_proj_mfma(
    const unsigned short* __restrict__ A, const unsigned short* __restrict__ W,
    const float* __restrict__ bias, const float* __restrict__ ori,
    float* __restrict__ xv2, unsigned short* __restrict__ xph) {
  __shared__ unsigned short Al[128 * 128];
  __shared__ unsigned short Bl[64 * 128];
  int m0 = blockIdx.x << 7, n0 = blockIdx.y << 6;
  int t = threadIdx.x;
  int lane = t & 63, w = t >> 6;
  int n16 = lane & 15, q = lane >> 4;

  for (int j = 0; j < 8; ++j) {
    int seg = w * 8 + j;
    gl_lds16((const char*)A + (size_t)m0 * 256 + (seg << 10) + lane * 16,
             (char*)Al + (seg << 10));
  }
  for (int j = 0; j < 4; ++j) {
    int seg = w * 4 + j;
    gl_lds16((const char*)W + (size_t)n0 * 256 + (seg << 10) + lane * 16,
             (char*)Bl + (seg << 10));
  }
  __syncthreads();

  int wm = w >> 1, wn = w & 1;
  f32x4 acc[4][2];
#pragma unroll
  for (int mt = 0; mt < 4; ++mt)
#pragma unroll
    for (int nt = 0; nt < 2; ++nt) acc[mt][nt] = (f32x4){0.f, 0.f, 0.f, 0.f};

#pragma unroll
  for (int kf = 0; kf < 4; ++kf) {
    int ca = kf * 4 + q;
    int rA0 = wm * 64 + n16;
    const unsigned short* Ap0 = Al + (size_t)rA0 * 128;
    int slotA = (ca & 8) | ((ca & 7) ^ (rA0 & 7));
    short8 a0 = *(const short8*)(Ap0 + slotA * 8);
    short8 a1 = *(const short8*)(Ap0 + 16 * 128 + slotA * 8);
    short8 a2 = *(const short8*)(Ap0 + 32 * 128 + slotA * 8);
    short8 a3 = *(const short8*)(Ap0 + 48 * 128 + slotA * 8);
    int rB0 = wn * 32 + n16;
    const unsigned short* Bp0 = Bl + (size_t)rB0 * 128;
    int slotB = (ca & 8) | ((ca & 7) ^ (rB0 & 7));
    short8 b0 = *(const short8*)(Bp0 + slotB * 8);
    short8 b1 = *(const short8*)(Bp0 + 16 * 128 + slotB * 8);
    acc[0][0] = __builtin_amdgcn_mfma_f32_16x16x32_bf16(a0, b0, acc[0][0], 0, 0, 0);
    acc[0][1] = __builtin_amdgcn_mfma_f32_16x16x32_bf16(a0, b1, acc[0][1], 0, 0, 0);
    acc[1][0] = __builtin_amdgcn_mfma_f32_16x16x32_bf16(a1, b0, acc[1][0], 0, 0, 0);
    acc[1][1] = __builtin_amdgcn_mfma_f32_16x16x32_bf16(a1, b1, acc[1][1], 0, 0, 0);
    acc[2][0] = __builtin_amdgcn_mfma_f32_16x16x32_bf16(a2, b0, acc[2][0], 0, 0, 0);
    acc[2][1] = __builtin_amdgcn_mfma_f32_16x16x32_bf16(a2, b1, acc[2][1], 0, 0, 0);
    acc[3][0] = __builtin_amdgcn_mfma_f32_16x16x32_bf16(a3, b0, acc[3][0], 0, 0, 0);
    acc[3][1] = __builtin_amdgcn_mfma_f32_16x16x32_bf16(a3, b1, acc[3][1], 0, 0, 0);
  }

  int bb = m0 >> 10;                       // 1024 % 128 == 0: b fixed per tile
  int nbase = (m0 & 1023) + wm * 64;
#pragma unroll
  for (int mt = 0; mt < 4; ++mt) {
    int nloc = nbase + mt * 16 + q * 4;
    const float* orow = ori + ((size_t)bb * 1024 + nloc) * 128;
#pragma unroll
    for (int nt = 0; nt < 2; ++nt) {
      int c = n0 + wn * 32 + nt * 16 + n16;
      float pb = bias[c];
      float4 vv;
      vv.x = acc[mt][nt][0] + pb + orow[c];
      vv.y = acc[mt][nt][1] + pb + orow[128 + c];
      vv.z = acc[mt][nt][2] + pb + orow[256 + c];
      vv.w = acc[mt][nt][3] + pb + orow[384 + c];
      *(float4*)(xv2 + ((size_t)bb * 128 + c) * 1024 + nloc) = vv;
      // bf16 swizzled-row copy for conv1d's MFMA B-operand
      int ch = c >> 3, ce = c & 7;
#pragma unroll
      for (int i = 0; i < 4; ++i) {
        int nrow = nloc + i;
        int slot = (ch & 8) | ((ch & 7) ^ (nrow & 7));
        float val = (i == 0) ? vv.x : (i == 1) ? vv.y : (i == 2) ? vv.z : vv.w;
        xph[((size_t)bb * 1024 + nrow) * 128 + slot * 8 + ce] = f2bf(val);
      }
    }
  }
}

// K_cvt: qkvb f32 -> qkb bf16 [b][h][{q,k}][1024][32]; yvbuf -> vtb bf16 transposed.
__global__ __launch_bounds__(256) void k_cvt(const float* __restrict__ qkv,
                                             const float* __restrict__ yv,
                                             unsigned short* __restrict__ qkb,
                                             unsigned short* __restrict__ vtb) {
  int nt = blockIdx.x, b = blockIdx.y;
  int n0 = nt << 6;
  int t = threadIdx.x;
  __shared__ unsigned short tl[64 * 132];
  const float* qb = qkv + ((size_t)b * 1024 + n0) * 384;
  for (int it = 0; it < 16; ++it) {
    int idx = it * 256 + t;
    int n = idx >> 6, c4 = idx & 63;
    float4 v = *(const float4*)(qb + (size_t)n * 384 + c4 * 4);
    int c = c4 << 2;
    int kind = c >> 7, h = (c >> 5) & 3, d = c & 31;
    uint2 u;
    u.x = (unsigned int)f2bf(v.x) | ((unsigned int)f2bf(v.y) << 16);
    u.y = (unsigned int)f2bf(v.z) | ((unsigned int)f2bf(v.w) << 16);
    *(uint2*)(qkb + ((((size_t)b * 4 + h) * 2 + kind) * 1024 + n0 + n) * 32 + d) = u;
  }
  const float* vb = yv + ((size_t)b * 1024 + n0) * 128;
  for (int it = 0; it < 8; ++it) {
    int idx = it * 256 + t;
    int n = idx >> 5, c4 = idx & 31;
    float4 v = *(const float4*)(vb + (size_t)n * 128 + c4 * 4);
    unsigned short* o = tl + n * 132 + c4 * 4;
    o[0] = f2bf(v.x); o[1] = f2bf(v.y); o[2] = f2bf(v.z); o[3] = f2bf(v.w);
  }
  __syncthreads();
  int c = t >> 1, half = t & 1;
  unsigned short* orow = vtb + (((size_t)b * 4 + (c >> 5)) * 32 + (c & 31)) * 1024 + n0 + half * 32;
#pragma unroll
  for (int k = 0; k < 4; ++k) {
    short8 pack;
#pragma unroll
    for (int j = 0; j < 8; ++j)
      pack[j] = (short)tl[(half * 32 + k * 8 + j) * 132 + c];
    *(short8*)(orow + k * 8) = pack;
  }
}

// K6 (MFMA): flash attention; swapped QK^T. Epilogue writes bf16 swizzled atth.
__global__ __launch_bounds__(256) void k_attn(const float* __restrict__ qkv,
                                              const unsigned short* __restrict__ qkb,
                                              const unsigned short* __restrict__ vtb,
                                              unsigned short* __restrict__ atth) {
  int qt = blockIdx.x, h = blockIdx.y, b = blockIdx.z;
  __shared__ unsigned short Qs[64 * 40];
  __shared__ unsigned short Ks[64 * 40];
  __shared__ unsigned short Vt[32 * 72];
  __shared__ unsigned short Pw[4 * 16 * 68];
  int t = threadIdx.x;
  int lane = t & 63, w = t >> 6;
  int quad = lane >> 4, l16 = lane & 15;
  const float* qbase = qkv + (size_t)b * 1024 * 384;
  const unsigned short* qrow = qkb + (((size_t)b * 4 + h) * 2 + 0) * 1024 * 32;
  const unsigned short* krow = qkb + (((size_t)b * 4 + h) * 2 + 1) * 1024 * 32;
  const unsigned short* vrow = vtb + ((size_t)b * 4 + h) * 32 * 1024;
  int q0 = qt << 6;
  int hd = h * 32;

  {
    int r = t >> 2, cq = t & 3;
    short8 v = *(const short8*)(qrow + (size_t)(q0 + r) * 32 + cq * 8);
    *(short8*)(Qs + r * 40 + cq * 8) = v;
  }
  __syncthreads();
  short8 aq = *(const short8*)(Qs + (w * 16 + l16) * 40 + quad * 8);

  f32x4 O[2];
  O[0] = (f32x4){0.f, 0.f, 0.f, 0.f};
  O[1] = (f32x4){0.f, 0.f, 0.f, 0.f};
  float mi0 = -1e30f, li0 = 0.f;
  unsigned short* Pme = Pw + w * (16 * 68);
  const float scl = 0.17677669529663688f;

  for (int ci = 0; ci < 16; ++ci) {
    __syncthreads();
    int kn0 = ci << 6;
    {
      int r = t >> 2, cq = t & 3;
      short8 kv = *(const short8*)(krow + (size_t)(kn0 + r) * 32 + cq * 8);
      *(short8*)(Ks + r * 40 + cq * 8) = kv;
      int d = t >> 3, cc = t & 7;
      short8 vv = *(const short8*)(vrow + (size_t)d * 1024 + kn0 + cc * 8);
      *(short8*)(Vt + d * 72 + cc * 8) = vv;
    }
    __syncthreads();

    f32x4 S[4];
#pragma unroll
    for (int nt = 0; nt < 4; ++nt) S[nt] = (f32x4){0.f, 0.f, 0.f, 0.f};
#pragma unroll
    for (int nt = 0; nt < 4; ++nt) {
      short8 bk = *(const short8*)(Ks + (nt * 16 + l16) * 40 + quad * 8);
      S[nt] = __builtin_amdgcn_mfma_f32_16x16x32_bf16(bk, aq, S[nt], 0, 0, 0);
    }

    float sv[16];
#pragma unroll
    for (int nt = 0; nt < 4; ++nt)
#pragma unroll
      for (int r = 0; r < 4; ++r) sv[nt * 4 + r] = S[nt][r] * scl;
    float m0 = fmaxf(fmaxf(sv[0], sv[1]), fmaxf(sv[2], sv[3]));
    float m1 = fmaxf(fmaxf(sv[4], sv[5]), fmaxf(sv[6], sv[7]));
    float m2 = fmaxf(fmaxf(sv[8], sv[9]), fmaxf(sv[10], sv[11]));
    float m3 = fmaxf(fmaxf(sv[12], sv[13]), fmaxf(sv[14], sv[15]));
    float rm = fmaxf(fmaxf(m0, m1), fmaxf(m2, m3));
    rm = fmaxf(rm, __shfl_xor(rm, 16));
    rm = fmaxf(rm, __shfl_xor(rm, 32));
    float nm = fmaxf(mi0, rm);
    float alpha = __expf(mi0 - nm);
    mi0 = nm;

    float psnt[4];
    unsigned short* pwr = Pme + l16 * 68 + quad * 4;
#pragma unroll
    for (int nt = 0; nt < 4; ++nt) {
      float p0 = __expf(sv[nt * 4 + 0] - nm);
      float p1 = __expf(sv[nt * 4 + 1] - nm);
      float p2 = __expf(sv[nt * 4 + 2] - nm);
      float p3 = __expf(sv[nt * 4 + 3] - nm);
      psnt[nt] = (p0 + p1) + (p2 + p3);
      uint2 u;
      u.x = (unsigned int)f2bf(p0) | ((unsigned int)f2bf(p1) << 16);
      u.y = (unsigned int)f2bf(p2) | ((unsigned int)f2bf(p3) << 16);
      *(uint2*)(pwr + nt * 16) = u;
    }
    float ps = (psnt[0] + psnt[1]) + (psnt[2] + psnt[3]);
    ps += __shfl_xor(ps, 16);
    ps += __shfl_xor(ps, 32);
    li0 = li0 * alpha + ps;

    float al0 = __shfl(alpha, quad * 4 + 0);
    float al1 = __shfl(alpha, quad * 4 + 1);
    float al2 = __shfl(alpha, quad * 4 + 2);
    float al3 = __shfl(alpha, quad * 4 + 3);
    O[0][0] *= al0; O[1][0] *= al0;
    O[0][1] *= al1; O[1][1] *= al1;
    O[0][2] *= al2; O[1][2] *= al2;
    O[0][3] *= al3; O[1][3] *= al3;

#pragma unroll
    for (int kc = 0; kc < 2; ++kc) {
      short8 bv0 = *(const short8*)(Vt + l16 * 72 + kc * 32 + quad * 8);
      short8 bv1 = *(const short8*)(Vt + (16 + l16) * 72 + kc * 32 + quad * 8);
      short8 ap = *(const short8*)(Pme + l16 * 68 + kc * 32 + quad * 8);
      O[0] = __builtin_amdgcn_mfma_f32_16x16x32_bf16(ap, bv0, O[0], 0, 0, 0);
      O[1] = __builtin_amdgcn_mfma_f32_16x16x32_bf16(ap, bv1, O[1], 0, 0, 0);
    }
  }

#pragma unroll
  for (int reg = 0; reg < 4; ++reg) {
    float lit = __shfl(li0, quad * 4 + reg);
    int n = q0 + w * 16 + quad * 4 + reg;
    float inv = 1.f / lit;
    size_t mrow = ((size_t)b * 1024 + n) * 128;
    int m7 = n & 7;
#pragma unroll
    for (int nt = 0; nt < 2; ++nt) {
      int dd = hd + nt * 16 + l16;
      float val = O[nt][reg] * inv + qbase[(size_t)n * 384 + 256 + dd];
      int ch = dd >> 3;
      int slot = (ch & 8) | ((ch & 7) ^ m7);
      atth[mrow + slot * 8 + (dd & 7)] = f2bf(val);
    }
  }
}

// K8 (MFMA): conv1d over n as GEMM M=64(oc half) x N=128(n tile) x K=640
// (5 taps x 128 ic), windowed B rows like conv_pe. +f32 residual from xv2.
__global__ __launch_bounds__(256) void k_conv1d_mfma(
    const unsigned short* __restrict__ xph, const unsigned short* __restrict__ wch,
    const float* __restrict__ xv2, float* __restrict__ xv3) {
  extern __shared__ char cs[];
  unsigned short* Wl = (unsigned short*)cs;            // [64][640] = 81920 B
  unsigned short* xl = (unsigned short*)(cs + 81920);  // [132][128] = 33792 B
  int ntile = blockIdx.x, b = blockIdx.y, oh = blockIdx.z;
  int n0 = ntile << 7;                     // 128 n per block
  int t = threadIdx.x, lane = t & 63, w = t >> 6;
  int n16 = lane & 15, q = lane >> 4;

  const unsigned short* wsrc = wch + (size_t)oh * 64 * 640;
  for (int j = 0; j < 20; ++j) {
    int seg = w * 20 + j;                  // 80 segs x 1KiB
    gl_lds16((const char*)wsrc + (seg << 10) + lane * 16, (char*)Wl + (seg << 10));
  }
  const unsigned short* xpb = xph + (size_t)b * 1024 * 128;
  for (int j = 0; j < 8; ++j) {
    int seg = w * 8 + j;                   // 32 segs: xl rows 2..129 <- n0..n0+127
    gl_lds16((const char*)xpb + (size_t)n0 * 256 + (seg << 10) + lane * 16,
             (char*)xl + 512 + (seg << 10));
  }
  {                                        // patch rows 0,1,130,131 (window edges)
    int ri = t >> 6, j2 = t & 63;
    int j = (ri < 2) ? ri : (128 + ri);
    int n = n0 + j - 2;
    unsigned int v = 0;
    if (n >= 0 && n < 1024) v = ((const unsigned int*)xpb)[(size_t)n * 64 + j2];
    ((unsigned int*)xl)[j * 64 + j2] = v;
  }
  __syncthreads();

  f32x4 acc[4][2];
#pragma unroll
  for (int mt = 0; mt < 4; ++mt)
#pragma unroll
    for (int nt = 0; nt < 2; ++nt) acc[mt][nt] = (f32x4){0.f, 0.f, 0.f, 0.f};

  int nb = w * 32;
#pragma unroll
  for (int kk = 0; kk < 5; ++kk) {
    int swb = (n16 + kk + 6) & 7;          // global x-row parity (n0 mult of 128)
#pragma unroll
    for (int kf = 0; kf < 4; ++kf) {
      int ca = kf * 4 + q;
      int LC = kk * 16 + kf * 4 + q;
      int slotA = (LC & 120) | ((LC & 7) ^ (n16 & 7));
      const unsigned short* Ap = Wl + n16 * 640 + slotA * 8;
      short8 a0 = *(const short8*)(Ap);
      short8 a1 = *(const short8*)(Ap + 16 * 640);
      short8 a2 = *(const short8*)(Ap + 32 * 640);
      short8 a3 = *(const short8*)(Ap + 48 * 640);
      int slotB = (ca & 8) | ((ca & 7) ^ swb);
      const unsigned short* Bp = xl + (nb + n16 + kk) * 128 + slotB * 8;
      short8 b0 = *(const short8*)(Bp);
      short8 b1 = *(const short8*)(Bp + 16 * 128);
      acc[0][0] = __builtin_amdgcn_mfma_f32_16x16x32_bf16(a0, b0, acc[0][0], 0, 0, 0);
      acc[0][1] = __builtin_amdgcn_mfma_f32_16x16x32_bf16(a0, b1, acc[0][1], 0, 0, 0);
      acc[1][0] = __builtin_amdgcn_mfma_f32_16x16x32_bf16(a1, b0, acc[1][0], 0, 0, 0);
      acc[1][1] = __builtin_amdgcn_mfma_f32_16x16x32_bf16(a1, b1, acc[1][1], 0, 0, 0);
      acc[2][0] = __builtin_amdgcn_mfma_f32_16x16x32_bf16(a2, b0, acc[2][0], 0, 0, 0);
      acc[2][1] = __builtin_amdgcn_mfma_f32_16x16x32_bf16(a2, b1, acc[2][1], 0, 0, 0);
      acc[3][0] = __builtin_amdgcn_mfma_f32_16x16x32_bf16(a3, b0, acc[3][0], 0, 0, 0);
      acc[3][1] = __builtin_amdgcn_mfma_f32_16x16x32_bf16(a3, b1, acc[3][1], 0, 0, 0);
    }
  }

#pragma unroll
  for (int mt = 0; mt < 4; ++mt) {
#pragma unroll
    for (int i = 0; i < 4; ++i) {
      int oc = oh * 64 + mt * 16 + q * 4 + i;
      const float* res = xv2 + ((size_t)b * 128 + oc) * 1024;
      float* outp = xv3 + ((size_t)b * 128 + oc) * 1024;
#pragma unroll
      for (int nt = 0; nt < 2; ++nt) {
        int n = n0 + nb + nt * 16 + n16;
        outp[n] = acc[mt][nt][i] + res[n];
      }
    }
  }
}

// K9: bilinear 32->96 align_corners=True, f32 out
__global__ __launch_bounds__(256) void k_bilinear(const float* __restrict__ xv3,
                                                  float* __restrict__ out) {
  int idx = blockIdx.x * 256 + threadIdx.x;
  int X = idx % 96;
  int t2 = idx / 96;
  int Y = t2 % 96;
  int bc = t2 / 96;
  const float* src = xv3 + (size_t)bc * 1024;
  const float r = 31.f / 95.f;
  float py = Y * r, px = X * r;
  int y0 = (int)py, x0 = (int)px;
  float wy = py - y0, wx = px - x0;
  int y1 = y0 < 31 ? y0 + 1 : 31, x1 = x0 < 31 ? x0 + 1 : 31;
  float a = src[y0 * 32 + x0], b_ = src[y0 * 32 + x1];
  float c_ = src[y1 * 32 + x0], d_ = src[y1 * 32 + x1];
  float t0 = a * (1.f - wy) + c_ * wy;
  float t1 = b_ * (1.f - wy) + d_ * wy;
  out[idx] = t0 * (1.f - wx) + t1 * wx;
}

extern "C" void kernel_launch(void* const* d_in, const int* in_sizes, int n_in,
                              void* d_out, int out_size, void* d_ws, size_t ws_size,
                              hipStream_t stream) {
  (void)in_sizes; (void)n_in; (void)out_size; (void)ws_size;
  const float* s1    = (const float*)d_in[0];
  const float* o     = (const float*)d_in[1];
  const int*   indx  = (const int*)d_in[2];
  const float* pe_w  = (const float*)d_in[3];
  const float* bn_g  = (const float*)d_in[4];
  const float* bn_b  = (const float*)d_in[5];
  const float* bn_m  = (const float*)d_in[6];
  const float* bn_v  = (const float*)d_in[7];
  const float* lnx_g = (const float*)d_in[8];
  const float* lnx_b = (const float*)d_in[9];
  const float* lny_g = (const float*)d_in[10];
  const float* lny_b = (const float*)d_in[11];
  const float* qkv_w = (const float*)d_in[12];
  const float* qkv_b = (const float*)d_in[13];
  const float* yv_w  = (const float*)d_in[14];
  const float* yv_b  = (const float*)d_in[15];
  const float* proj_w = (const float*)d_in[16];
  const float* proj_b = (const float*)d_in[17];
  const float* c1d_w  = (const float*)d_in[18];

  char* ws = (char*)d_ws;
  unsigned short* xTh = (unsigned short*)ws;
  unsigned short* ymh = (unsigned short*)(ws + 37748736);
  // d_out scratch: wpk +0 (41KB); wch +64KB (160KB); wqkh +448KB (98KB);
  // wyvh +560KB (32KB); wprh +608KB (32KB).
  unsigned short* wpk = (unsigned short*)d_out;
  unsigned short* wch = (unsigned short*)((char*)d_out + 65536);
  unsigned short* wqkh = (unsigned short*)((char*)d_out + 458752);
  unsigned short* wyvh = (unsigned short*)((char*)d_out + 573440);
  unsigned short* wprh = (unsigned short*)((char*)d_out + 622592);
  // Phase 2 (xTh dead after k_conv_pe): region A = [ws+0, 37.7MB)
  float* ori  = (float*)ws;                 // [0, 8.4MB)
  unsigned short* snh  = (unsigned short*)(ws + 8388608);   // 4.2MB bf16
  unsigned short* oflh = (unsigned short*)(ws + 16777216);  // 4.2MB bf16
  unsigned short* atth = (unsigned short*)(ws + 25165824);  // 4.2MB bf16
  // Phase 3 (ymh dead after k_pool9ln): region B = [ws+37.7MB, 75.5MB)
  float* qkvb  = (float*)(ws + 37748736);   // 25.2MB
  float* yvbuf = (float*)(ws + 62914560);   // 8.4MB, dead after k_cvt
  unsigned short* qkb = (unsigned short*)(ws + 16777216);  // alias oflh (dead), 8.4MB
  unsigned short* vtb = (unsigned short*)(ws + 71303168);  // tail, 4.2MB
  float* xv2   = (float*)(ws + 37748736);   // alias qkvb (dead after k_attn)
  float* xv3   = (float*)(ws + 46137344);
  unsigned short* xph = (unsigned short*)(ws + 62914560);  // alias yvbuf (dead), 4.2MB

  hipLaunchKernelGGL(k_prep, dim3(8), dim3(256), 0, stream, pe_w, wpk);
  hipLaunchKernelGGL(k_prepcw, dim3(320), dim3(256), 0, stream, c1d_w, wch);
  hipLaunchKernelGGL(k_prepw, dim3(24), dim3(256), 0, stream, qkv_w, wqkh, 384);
  hipLaunchKernelGGL(k_prepw, dim3(8), dim3(256), 0, stream, yv_w, wyvh, 128);
  hipLaunchKernelGGL(k_prepw, dim3(8), dim3(256), 0, stream, proj_w, wprh, 128);
  hipLaunchKernelGGL(k_transpose, dim3(128, 16), dim3(256), 0, stream, s1, xTh);
  hipLaunchKernelGGL(k_conv_pe, dim3(36, 16), dim3(256), 75008, stream,
                     xTh, wpk, bn_g, bn_b, bn_m, bn_v, indx, ymh);
  hipLaunchKernelGGL(k_pool9ln, dim3(64, 16), dim3(256), 0, stream, ymh, lny_g, lny_b, ori, snh);
  hipLaunchKernelGGL(k_poolo_ln, dim3(32, 16), dim3(256), 0, stream, o, lnx_g, lnx_b, oflh);
  hipLaunchKernelGGL(k_gemm_mfma, dim3(128, 6), dim3(256), 0, stream, oflh, wqkh, qkv_b, qkvb, 384);
  hipLaunchKernelGGL(k_gemm_mfma, dim3(128, 2), dim3(256), 0, stream, snh, wyvh, yv_b, yvbuf, 128);
  hipLaunchKernelGGL(k_cvt, dim3(16, 16), dim3(256), 0, stream, qkvb, yvbuf, qkb, vtb);
  hipLaunchKernelGGL(k_attn, dim3(16, 4, 16), dim3(256), 0, stream, qkvb, qkb, vtb, atth);
  hipLaunchKernelGGL(k_proj_mfma, dim3(128, 2), dim3(256), 0, stream, atth, wprh, proj_b, ori, xv2, xph);
  hipLaunchKernelGGL(k_conv1d_mfma, dim3(8, 16, 2), dim3(256), 115712, stream, xph, wch, xv2, xv3);
  hipLaunchKernelGGL(k_bilinear, dim3(73728), dim3(256), 0, stream, xv3, (float*)d_out);
}

// Round 16
// 345.591 us; speedup vs baseline: 1.7182x; 1.0285x over previous
//
#include <hip/hip_runtime.h>

#define FEAT 18432

typedef __attribute__((ext_vector_type(8))) short short8;
typedef __attribute__((ext_vector_type(4))) float f32x4;

__device__ __forceinline__ float b2f(unsigned short s) {
  union { unsigned int u; float f; } v; v.u = ((unsigned int)s) << 16; return v.f;
}
__device__ __forceinline__ unsigned short f2bf(float x) {
  union { float f; unsigned int u; } v; v.f = x;
  unsigned int u = v.u;
  unsigned int r = (u + 0x7FFFu + ((u >> 16) & 1u)) >> 16;
  return (unsigned short)r;
}

// async global->LDS, 16B per lane; LDS dest = base + lane*16 (wave-uniform base)
__device__ __forceinline__ void gl_lds16(const void* g, void* l) {
  __builtin_amdgcn_global_load_lds(
      (const __attribute__((address_space(1))) unsigned int*)g,
      (__attribute__((address_space(3))) unsigned int*)l, 16, 0, 0);
}

// K0: s1[b][c][96][96] (f32) -> xTn[b][f][ic] bf16, swizzled 16B chunks.
__global__ __launch_bounds__(256) void k_transpose(const float* __restrict__ s1,
                                                   unsigned short* __restrict__ xT) {
  int c = blockIdx.x, b = blockIdx.y;
  __shared__ float lds[96 * 99];            // plane [h][w], pad 99
  int t = threadIdx.x;
  const float* src = s1 + ((size_t)b * 128 + c) * 9216;
  for (int idx = t; idx < 2304; idx += 256) {
    float4 v = ((const float4*)src)[idx];
    int h = idx / 24, w0 = (idx - h * 24) * 4;
    float* p = lds + h * 99 + w0;
    p[0] = v.x; p[1] = v.y; p[2] = v.z; p[3] = v.w;
  }
  __syncthreads();
  unsigned short* dstb = xT + (size_t)b * FEAT * 64;
  int sw = c & 7;
  for (int idx = t; idx < 1152; idx += 256) {
    int p1p2 = idx >> 3, gh = idx & 7;
    int p1 = p1p2 / 12, p2 = p1p2 - p1 * 12;
    const float* row = lds + (gh * 12 + p1) * 99 + p2;
    uint4 u;
    u.x = f2bf(row[0])  | ((unsigned int)f2bf(row[12]) << 16);
    u.y = f2bf(row[24]) | ((unsigned int)f2bf(row[36]) << 16);
    u.z = f2bf(row[48]) | ((unsigned int)f2bf(row[60]) << 16);
    u.w = f2bf(row[72]) | ((unsigned int)f2bf(row[84]) << 16);
    int f = p1p2 * 128 + c;
    int pos = gh ^ sw;
    *(uint4*)(dstb + (size_t)f * 64 + pos * 8) = u;
  }
}

// K_prep: pack pe_w -> wpk[oc][320] bf16 with chunk swizzle
__global__ __launch_bounds__(256) void k_prep(const float* __restrict__ pe_w,
                                              unsigned short* __restrict__ wpk) {
  int oc0 = blockIdx.x * 8;
  for (int e = threadIdx.x; e < 2560; e += 256) {
    int oc = oc0 + e / 320;
    int kL = e - (e / 320) * 320;
    int ic = kL & 63, kk = kL >> 6;
    float v = pe_w[(oc * 64 + ic) * 5 + kk];
    int LC = kL >> 3;
    int pos = (LC & 56) | ((LC & 7) ^ (oc & 7));
    wpk[oc * 320 + (pos << 3) + (kL & 7)] = f2bf(v);
  }
}

// K_prepcw: pack c1d_w[oc][ic][5] f32 -> wch[ochalf][64][640] bf16, k=kk*128+ic,
// 16B-chunk swizzle: pos = (LC&120) | ((LC&7)^(oc&7)).
__global__ __launch_bounds__(256) void k_prepcw(const float* __restrict__ cw,
                                                unsigned short* __restrict__ wch) {
  int e = blockIdx.x * 256 + threadIdx.x;    // 320 blocks x 256 = 81920
  int oc = e / 640, kl = e - (e / 640) * 640;
  int kk = kl >> 7, ic = kl & 127;
  float v = cw[(size_t)oc * 640 + ic * 5 + kk];
  int LC = kl >> 3;
  int pos = (LC & 120) | ((LC & 7) ^ (oc & 7));
  wch[(size_t)oc * 640 + pos * 8 + (kl & 7)] = f2bf(v);
}

// K_prepw: pack GEMM weights W[ncols][128] f32 -> bf16 swizzled rows.
__global__ __launch_bounds__(256) void k_prepw(const float* __restrict__ W,
                                               unsigned short* __restrict__ dst,
                                               int ncols) {
  int idx = blockIdx.x * 256 + threadIdx.x;
  if (idx >= ncols * 16) return;
  int n = idx >> 4, c = idx & 15;
  int slot = (c & 8) | ((c & 7) ^ (n & 7));
  const float* s = W + (size_t)n * 128 + c * 8;
  uint4 u;
  u.x = (unsigned int)f2bf(s[0]) | ((unsigned int)f2bf(s[1]) << 16);
  u.y = (unsigned int)f2bf(s[2]) | ((unsigned int)f2bf(s[3]) << 16);
  u.z = (unsigned int)f2bf(s[4]) | ((unsigned int)f2bf(s[5]) << 16);
  u.w = (unsigned int)f2bf(s[6]) | ((unsigned int)f2bf(s[7]) << 16);
  *(uint4*)(dst + (size_t)n * 128 + slot * 8) = u;
}

// K1 (MFMA): conv1d over f as GEMM + BN(eval) + ReLU + selective square.
__global__ __launch_bounds__(256) void k_conv_pe(
    const unsigned short* __restrict__ xT, const unsigned short* __restrict__ wpk,
    const float* __restrict__ bn_g, const float* __restrict__ bn_b,
    const float* __restrict__ bn_m, const float* __restrict__ bn_v,
    const int* __restrict__ indexp, unsigned short* __restrict__ ym) {
  extern __shared__ char smem[];
  unsigned short* Wl = (unsigned short*)smem;
  unsigned short* xl = (unsigned short*)(smem + 40960);
  float* scf = (float*)(smem + 74240);
  float* shf = (float*)(smem + 74496);
  int*   sli = (int*)(smem + 74752);
  int t = threadIdx.x;
  int b = blockIdx.y;
  int blk_f0 = blockIdx.x << 9;
  int lane = t & 63, w = t >> 6;
  int n16 = lane & 15, q = lane >> 4;

  for (int j = 0; j < 10; ++j) {
    int seg = w * 10 + j;
    gl_lds16((const char*)wpk + (seg << 10) + lane * 16, (char*)Wl + (seg << 10));
  }
  if (t < 64) {
    float sc = bn_g[t] * rsqrtf(bn_v[t] + 1e-5f);
    scf[t] = sc;
    shf[t] = bn_b[t] - bn_m[t] * sc;
    int i0 = indexp[0] / 12 * 8 + indexp[1] / 12;
    int i1 = indexp[2] / 12 * 8 + indexp[3] / 12;
    int i2 = indexp[4] / 12 * 8 + indexp[5] / 12;
    int i3 = indexp[6] / 12 * 8 + indexp[7] / 12;
    sli[t] = (t == i0 || t == i1 || t == i2 || t == i3) ? 1 : 0;
  }

  const unsigned short* xb = xT + (size_t)b * FEAT * 64;
  const unsigned int* xbu = (const unsigned int*)xb;

  for (int wnd = 0; wnd < 2; ++wnd) {
    int F0 = blk_f0 + (wnd << 8);
    __syncthreads();
    int flA = (F0 == 0) ? 2 : 0;
    for (int j = 0; j < 8; ++j) {
      int seg = (w << 3) + j;
      int gRow = F0 - 2 + flA + (seg << 3);
      gl_lds16((const char*)xb + (size_t)gRow * 128 + lane * 16,
               (char*)xl + flA * 128 + (seg << 10));
    }
    if (t < 128) {
      int r0 = (flA == 2) ? 0 : 256;
      int fl = (t < 64) ? (r0 + (t >> 5)) : (258 + ((t >> 5) & 1));
      int j = t & 31;
      int f = F0 - 2 + fl;
      unsigned int v = 0;
      if (f >= 0 && f < FEAT) v = xbu[(size_t)f * 32 + j];
      ((unsigned int*)xl)[fl * 32 + j] = v;
    }
    __syncthreads();

    f32x4 acc[4][4];
#pragma unroll
    for (int mt = 0; mt < 4; ++mt)
#pragma unroll
      for (int nt = 0; nt < 4; ++nt) acc[mt][nt] = (f32x4){0.f, 0.f, 0.f, 0.f};

    int rowB = w * 64 + n16;
#pragma unroll
    for (int kk = 0; kk < 5; ++kk) {
      int swb = (n16 + kk + 6) & 7;
#pragma unroll
      for (int ih = 0; ih < 2; ++ih) {
        int ca = (ih << 2) | q;
        const unsigned short* Ap = Wl + kk * 64 + ((ca ^ (n16 & 7)) << 3) + n16 * 320;
        short8 a0 = *(const short8*)(Ap);
        short8 a1 = *(const short8*)(Ap + 16 * 320);
        short8 a2 = *(const short8*)(Ap + 32 * 320);
        short8 a3 = *(const short8*)(Ap + 48 * 320);
        const unsigned short* Bp = xl + ((ca ^ swb) << 3) + (rowB + kk) * 64;
        short8 b0 = *(const short8*)(Bp);
        short8 b1 = *(const short8*)(Bp + 16 * 64);
        short8 b2 = *(const short8*)(Bp + 32 * 64);
        short8 b3 = *(const short8*)(Bp + 48 * 64);
        acc[0][0] = __builtin_amdgcn_mfma_f32_16x16x32_bf16(a0, b0, acc[0][0], 0, 0, 0);
        acc[0][1] = __builtin_amdgcn_mfma_f32_16x16x32_bf16(a0, b1, acc[0][1], 0, 0, 0);
        acc[0][2] = __builtin_amdgcn_mfma_f32_16x16x32_bf16(a0, b2, acc[0][2], 0, 0, 0);
        acc[0][3] = __builtin_amdgcn_mfma_f32_16x16x32_bf16(a0, b3, acc[0][3], 0, 0, 0);
        acc[1][0] = __builtin_amdgcn_mfma_f32_16x16x32_bf16(a1, b0, acc[1][0], 0, 0, 0);
        acc[1][1] = __builtin_amdgcn_mfma_f32_16x16x32_bf16(a1, b1, acc[1][1], 0, 0, 0);
        acc[1][2] = __builtin_amdgcn_mfma_f32_16x16x32_bf16(a1, b2, acc[1][2], 0, 0, 0);
        acc[1][3] = __builtin_amdgcn_mfma_f32_16x16x32_bf16(a1, b3, acc[1][3], 0, 0, 0);
        acc[2][0] = __builtin_amdgcn_mfma_f32_16x16x32_bf16(a2, b0, acc[2][0], 0, 0, 0);
        acc[2][1] = __builtin_amdgcn_mfma_f32_16x16x32_bf16(a2, b1, acc[2][1], 0, 0, 0);
        acc[2][2] = __builtin_amdgcn_mfma_f32_16x16x32_bf16(a2, b2, acc[2][2], 0, 0, 0);
        acc[2][3] = __builtin_amdgcn_mfma_f32_16x16x32_bf16(a2, b3, acc[2][3], 0, 0, 0);
        acc[3][0] = __builtin_amdgcn_mfma_f32_16x16x32_bf16(a3, b0, acc[3][0], 0, 0, 0);
        acc[3][1] = __builtin_amdgcn_mfma_f32_16x16x32_bf16(a3, b1, acc[3][1], 0, 0, 0);
        acc[3][2] = __builtin_amdgcn_mfma_f32_16x16x32_bf16(a3, b2, acc[3][2], 0, 0, 0);
        acc[3][3] = __builtin_amdgcn_mfma_f32_16x16x32_bf16(a3, b3, acc[3][3], 0, 0, 0);
      }
    }

#pragma unroll
    for (int mt = 0; mt < 4; ++mt) {
#pragma unroll
      for (int i = 0; i < 4; ++i) {
        int oc = mt * 16 + q * 4 + i;
        float sc = scf[oc], sh = shf[oc];
        bool sel = sli[oc] != 0;
        unsigned short* yo = ym + ((size_t)b * 64 + oc) * FEAT + F0 + w * 64 + n16;
#pragma unroll
        for (int nt = 0; nt < 4; ++nt) {
          float y = fmaf(acc[mt][nt][i], sc, sh);
          y = fmaxf(y, 0.f);
          if (!sel) y *= y;
          yo[nt * 16] = f2bf(y);
        }
      }
    }
  }
}

// K2: 3x3 avg pool 96->32 + fused LayerNorm. Writes ori (f32) + snh (bf16 swz).
__global__ __launch_bounds__(256) void k_pool9ln(
    const unsigned short* __restrict__ ym, const float* __restrict__ lng,
    const float* __restrict__ lnb, float* __restrict__ ori,
    unsigned short* __restrict__ snh) {
  int oc = blockIdx.x, b = blockIdx.y;
  const unsigned short* src = ym + ((size_t)b * 64 + oc) * FEAT;
  int oh0 = (oc >> 3) << 2, ow0 = (oc & 7) << 2;
  __shared__ float red[8];
  int t = threadIdx.x;
  int c = t & 127, hr = t >> 7, wv = t >> 6, l64 = t & 63;
  float g = lng[c], bb = lnb[c];
  for (int p = 0; p < 8; ++p) {
    int nl = p * 2 + hr;
    int pg1 = nl >> 2, pg2 = nl & 3;
    int pbase = (pg1 * 36 + pg2 * 3) * 128 + c;
    float s = 0.f;
#pragma unroll
    for (int dy = 0; dy < 3; ++dy)
#pragma unroll
      for (int dx = 0; dx < 3; ++dx)
        s += b2f(src[pbase + (dy * 12 + dx) * 128]);
    float val = s * (1.f / 9.f);
    float su = val, q = val * val;
#pragma unroll
    for (int off = 32; off > 0; off >>= 1) {
      su += __shfl_xor(su, off, 64);
      q += __shfl_xor(q, off, 64);
    }
    if (l64 == 0) { red[wv * 2] = su; red[wv * 2 + 1] = q; }
    __syncthreads();
    float S = red[hr * 4 + 0] + red[hr * 4 + 2];
    float Q = red[hr * 4 + 1] + red[hr * 4 + 3];
    float mean = S * (1.f / 128.f);
    float var = Q * (1.f / 128.f) - mean * mean;
    float inv = rsqrtf(var + 1e-5f);
    int n = (oh0 + pg1) * 32 + ow0 + pg2;
    size_t base = ((size_t)b * 1024 + n) * 128;
    ori[base + c] = val;
    float lnv = (val - mean) * inv * g + bb;
    int ch = c >> 3;
    int slot = (ch & 8) | ((ch & 7) ^ (n & 7));
    snh[base + slot * 8 + (c & 7)] = f2bf(lnv);
    __syncthreads();
  }
}

// K3: 2x2 avg pool of o + LayerNorm -> oflh bf16 swizzled
__global__ __launch_bounds__(256) void k_poolo_ln(
    const float* __restrict__ o, const float* __restrict__ lng,
    const float* __restrict__ lnb, unsigned short* __restrict__ oflh) {
  int y = blockIdx.x, b = blockIdx.y;
  __shared__ float pl[128 * 33];
  int t = threadIdx.x;
  for (int idx = t; idx < 4096; idx += 256) {
    int xo = idx & 31, c = idx >> 5;
    const float* p = o + (((size_t)b * 128 + c) * 64 + 2 * y) * 64 + 2 * xo;
    float2 a = *(const float2*)p;
    float2 d = *(const float2*)(p + 64);
    pl[c * 33 + xo] = 0.25f * (a.x + a.y + d.x + d.y);
  }
  __syncthreads();
  int xo = t >> 3, l8 = t & 7;
  float v[16]; float s = 0.f, q = 0.f;
#pragma unroll
  for (int i = 0; i < 16; ++i) {
    float x = pl[(l8 * 16 + i) * 33 + xo];
    v[i] = x; s += x; q += x * x;
  }
#pragma unroll
  for (int off = 1; off < 8; off <<= 1) {
    s += __shfl_xor(s, off, 8);
    q += __shfl_xor(q, off, 8);
  }
  float mean = s * (1.f / 128.f);
  float var = q * (1.f / 128.f) - mean * mean;
  float inv = rsqrtf(var + 1e-5f);
  int n = y * 32 + xo;
  unsigned short* dst = oflh + ((size_t)b * 1024 + n) * 128;
  int m7 = n & 7;
#pragma unroll
  for (int h = 0; h < 2; ++h) {
    int c = l8 * 2 + h;
    int slot = (c & 8) | ((c & 7) ^ m7);
    uint4 u;
    float w0 = (v[h * 8 + 0] - mean) * inv * lng[c * 8 + 0] + lnb[c * 8 + 0];
    float w1 = (v[h * 8 + 1] - mean) * inv * lng[c * 8 + 1] + lnb[c * 8 + 1];
    float w2 = (v[h * 8 + 2] - mean) * inv * lng[c * 8 + 2] + lnb[c * 8 + 2];
    float w3 = (v[h * 8 + 3] - mean) * inv * lng[c * 8 + 3] + lnb[c * 8 + 3];
    float w4 = (v[h * 8 + 4] - mean) * inv * lng[c * 8 + 4] + lnb[c * 8 + 4];
    float w5 = (v[h * 8 + 5] - mean) * inv * lng[c * 8 + 5] + lnb[c * 8 + 5];
    float w6 = (v[h * 8 + 6] - mean) * inv * lng[c * 8 + 6] + lnb[c * 8 + 6];
    float w7 = (v[h * 8 + 7] - mean) * inv * lng[c * 8 + 7] + lnb[c * 8 + 7];
    u.x = (unsigned int)f2bf(w0) | ((unsigned int)f2bf(w1) << 16);
    u.y = (unsigned int)f2bf(w2) | ((unsigned int)f2bf(w3) << 16);
    u.z = (unsigned int)f2bf(w4) | ((unsigned int)f2bf(w5) << 16);
    u.w = (unsigned int)f2bf(w6) | ((unsigned int)f2bf(w7) << 16);
    *(uint4*)(dst + slot * 8) = u;
  }
}

// K5 (MFMA): out[M][Ncols] = A @ W^T + bias, f32 out. A,W bf16 swizzled.
__global__ __launch_bounds__(256) void k_gemm_mfma(
    const unsigned short* __restrict__ A, const unsigned short* __restrict__ W,
    const float* __restrict__ bias, float* __restrict__ out, int Ncols) {
  __shared__ unsigned short Al[128 * 128];
  __shared__ unsigned short Bl[64 * 128];
  int m0 = blockIdx.x << 7, n0 = blockIdx.y << 6;
  int t = threadIdx.x;
  int lane = t & 63, w = t >> 6;
  int n16 = lane & 15, q = lane >> 4;

  for (int j = 0; j < 8; ++j) {
    int seg = w * 8 + j;
    gl_lds16((const char*)A + (size_t)m0 * 256 + (seg << 10) + lane * 16,
             (char*)Al + (seg << 10));
  }
  for (int j = 0; j < 4; ++j) {
    int seg = w * 4 + j;
    gl_lds16((const char*)W + (size_t)n0 * 256 + (seg << 10) + lane * 16,
             (char*)Bl + (seg << 10));
  }
  __syncthreads();

  int wm = w >> 1, wn = w & 1;
  f32x4 acc[4][2];
#pragma unroll
  for (int mt = 0; mt < 4; ++mt)
#pragma unroll
    for (int nt = 0; nt < 2; ++nt) acc[mt][nt] = (f32x4){0.f, 0.f, 0.f, 0.f};

#pragma unroll
  for (int kf = 0; kf < 4; ++kf) {
    int ca = kf * 4 + q;
    int rA0 = wm * 64 + n16;
    const unsigned short* Ap0 = Al + (size_t)rA0 * 128;
    int slotA = (ca & 8) | ((ca & 7) ^ (rA0 & 7));
    short8 a0 = *(const short8*)(Ap0 + slotA * 8);
    short8 a1 = *(const short8*)(Ap0 + 16 * 128 + slotA * 8);
    short8 a2 = *(const short8*)(Ap0 + 32 * 128 + slotA * 8);
    short8 a3 = *(const short8*)(Ap0 + 48 * 128 + slotA * 8);
    int rB0 = wn * 32 + n16;
    const unsigned short* Bp0 = Bl + (size_t)rB0 * 128;
    int slotB = (ca & 8) | ((ca & 7) ^ (rB0 & 7));
    short8 b0 = *(const short8*)(Bp0 + slotB * 8);
    short8 b1 = *(const short8*)(Bp0 + 16 * 128 + slotB * 8);
    acc[0][0] = __builtin_amdgcn_mfma_f32_16x16x32_bf16(a0, b0, acc[0][0], 0, 0, 0);
    acc[0][1] = __builtin_amdgcn_mfma_f32_16x16x32_bf16(a0, b1, acc[0][1], 0, 0, 0);
    acc[1][0] = __builtin_amdgcn_mfma_f32_16x16x32_bf16(a1, b0, acc[1][0], 0, 0, 0);
    acc[1][1] = __builtin_amdgcn_mfma_f32_16x16x32_bf16(a1, b1, acc[1][1], 0, 0, 0);
    acc[2][0] = __builtin_amdgcn_mfma_f32_16x16x32_bf16(a2, b0, acc[2][0], 0, 0, 0);
    acc[2][1] = __builtin_amdgcn_mfma_f32_16x16x32_bf16(a2, b1, acc[2][1], 0, 0, 0);
    acc[3][0] = __builtin_amdgcn_mfma_f32_16x16x32_bf16(a3, b0, acc[3][0], 0, 0, 0);
    acc[3][1] = __builtin_amdgcn_mfma_f32_16x16x32_bf16(a3, b1, acc[3][1], 0, 0, 0);
  }

#pragma unroll
  for (int mt = 0; mt < 4; ++mt) {
#pragma unroll
    for (int i = 0; i < 4; ++i) {
      int m = m0 + wm * 64 + mt * 16 + q * 4 + i;
#pragma unroll
      for (int nt = 0; nt < 2; ++nt) {
        int n = n0 + wn * 32 + nt * 16 + n16;
        out[(size_t)m * Ncols + n] = acc[mt][nt][i] + bias[n];
      }
    }
  }
}

// K_projm (MFMA): xv2[b][c][n] f32 + xph[b][n][c] bf16 (swizzled rows) =
// (atth @ proj_w^T) + proj_b + ori.
__global__ __launch_bounds__(256) void k_proj_mfma(
    const unsigned short* __restrict__ A, const unsigned short* __restrict__ W,
    const float* __restrict__ bias, const float* __restrict__ ori,
    float* __restrict__ xv2, unsigned short* __restrict__ xph) {
  __shared__ unsigned short Al[128 * 128];
  __shared__ unsigned short Bl[64 * 128];
  int m0 = blockIdx.x << 7, n0 = blockIdx.y << 6;
  int t = threadIdx.x;
  int lane = t & 63, w = t >> 6;
  int n16 = lane & 15, q = lane >> 4;

  for (int j = 0; j < 8; ++j) {
    int seg = w * 8 + j;
    gl_lds16((const char*)A + (size_t)m0 * 256 + (seg << 10) + lane * 16,
             (char*)Al + (seg << 10));
  }
  for (int j = 0; j < 4; ++j) {
    int seg = w * 4 + j;
    gl_lds16((const char*)W + (size_t)n0 * 256 + (seg << 10) + lane * 16,
             (char*)Bl + (seg << 10));
  }
  __syncthreads();

  int wm = w >> 1, wn = w & 1;
  f32x4 acc[4][2];
#pragma unroll
  for (int mt = 0; mt < 4; ++mt)
#pragma unroll
    for (int nt = 0; nt < 2; ++nt) acc[mt][nt] = (f32x4){0.f, 0.f, 0.f, 0.f};

#pragma unroll
  for (int kf = 0; kf < 4; ++kf) {
    int ca = kf * 4 + q;
    int rA0 = wm * 64 + n16;
    const unsigned short* Ap0 = Al + (size_t)rA0 * 128;
    int slotA = (ca & 8) | ((ca & 7) ^ (rA0 & 7));
    short8 a0 = *(const short8*)(Ap0 + slotA * 8);
    short8 a1 = *(const short8*)(Ap0 + 16 * 128 + slotA * 8);
    short8 a2 = *(const short8*)(Ap0 + 32 * 128 + slotA * 8);
    short8 a3 = *(const short8*)(Ap0 + 48 * 128 + slotA * 8);
    int rB0 = wn * 32 + n16;
    const unsigned short* Bp0 = Bl + (size_t)rB0 * 128;
    int slotB = (ca & 8) | ((ca & 7) ^ (rB0 & 7));
    short8 b0 = *(const short8*)(Bp0 + slotB * 8);
    short8 b1 = *(const short8*)(Bp0 + 16 * 128 + slotB * 8);
    acc[0][0] = __builtin_amdgcn_mfma_f32_16x16x32_bf16(a0, b0, acc[0][0], 0, 0, 0);
    acc[0][1] = __builtin_amdgcn_mfma_f32_16x16x32_bf16(a0, b1, acc[0][1], 0, 0, 0);
    acc[1][0] = __builtin_amdgcn_mfma_f32_16x16x32_bf16(a1, b0, acc[1][0], 0, 0, 0);
    acc[1][1] = __builtin_amdgcn_mfma_f32_16x16x32_bf16(a1, b1, acc[1][1], 0, 0, 0);
    acc[2][0] = __builtin_amdgcn_mfma_f32_16x16x32_bf16(a2, b0, acc[2][0], 0, 0, 0);
    acc[2][1] = __builtin_amdgcn_mfma_f32_16x16x32_bf16(a2, b1, acc[2][1], 0, 0, 0);
    acc[3][0] = __builtin_amdgcn_mfma_f32_16x16x32_bf16(a3, b0, acc[3][0], 0, 0, 0);
    acc[3][1] = __builtin_amdgcn_mfma_f32_16x16x32_bf16(a3, b1, acc[3][1], 0, 0, 0);
  }

  int bb = m0 >> 10;                       // 1024 % 128 == 0: b fixed per tile
  int nbase = (m0 & 1023) + wm * 64;
#pragma unroll
  for (int mt = 0; mt < 4; ++mt) {
    int nloc = nbase + mt * 16 + q * 4;
    const float* orow = ori + ((size_t)bb * 1024 + nloc) * 128;
#pragma unroll
    for (int nt = 0; nt < 2; ++nt) {
      int c = n0 + wn * 32 + nt * 16 + n16;
      float pb = bias[c];
      float4 vv;
      vv.x = acc[mt][nt][0] + pb + orow[c];
      vv.y = acc[mt][nt][1] + pb + orow[128 + c];
      vv.z = acc[mt][nt][2] + pb + orow[256 + c];
      vv.w = acc[mt][nt][3] + pb + orow[384 + c];
      *(float4*)(xv2 + ((size_t)bb * 128 + c) * 1024 + nloc) = vv;
      // bf16 swizzled-row copy for conv1d's MFMA B-operand
      int ch = c >> 3, ce = c & 7;
#pragma unroll
      for (int i = 0; i < 4; ++i) {
        int nrow = nloc + i;
        int slot = (ch & 8) | ((ch & 7) ^ (nrow & 7));
        float val = (i == 0) ? vv.x : (i == 1) ? vv.y : (i == 2) ? vv.z : vv.w;
        xph[((size_t)bb * 1024 + nrow) * 128 + slot * 8 + ce] = f2bf(val);
      }
    }
  }
}

// K_cvt: qkvb f32 -> qkb bf16 [b][h][{q,k}][1024][32]; yvbuf -> vtb bf16 transposed.
__global__ __launch_bounds__(256) void k_cvt(const float* __restrict__ qkv,
                                             const float* __restrict__ yv,
                                             unsigned short* __restrict__ qkb,
                                             unsigned short* __restrict__ vtb) {
  int nt = blockIdx.x, b = blockIdx.y;
  int n0 = nt << 6;
  int t = threadIdx.x;
  __shared__ unsigned short tl[64 * 132];
  const float* qb = qkv + ((size_t)b * 1024 + n0) * 384;
  for (int it = 0; it < 16; ++it) {
    int idx = it * 256 + t;
    int n = idx >> 6, c4 = idx & 63;
    float4 v = *(const float4*)(qb + (size_t)n * 384 + c4 * 4);
    int c = c4 << 2;
    int kind = c >> 7, h = (c >> 5) & 3, d = c & 31;
    uint2 u;
    u.x = (unsigned int)f2bf(v.x) | ((unsigned int)f2bf(v.y) << 16);
    u.y = (unsigned int)f2bf(v.z) | ((unsigned int)f2bf(v.w) << 16);
    *(uint2*)(qkb + ((((size_t)b * 4 + h) * 2 + kind) * 1024 + n0 + n) * 32 + d) = u;
  }
  const float* vb = yv + ((size_t)b * 1024 + n0) * 128;
  for (int it = 0; it < 8; ++it) {
    int idx = it * 256 + t;
    int n = idx >> 5, c4 = idx & 31;
    float4 v = *(const float4*)(vb + (size_t)n * 128 + c4 * 4);
    unsigned short* o = tl + n * 132 + c4 * 4;
    o[0] = f2bf(v.x); o[1] = f2bf(v.y); o[2] = f2bf(v.z); o[3] = f2bf(v.w);
  }
  __syncthreads();
  int c = t >> 1, half = t & 1;
  unsigned short* orow = vtb + (((size_t)b * 4 + (c >> 5)) * 32 + (c & 31)) * 1024 + n0 + half * 32;
#pragma unroll
  for (int k = 0; k < 4; ++k) {
    short8 pack;
#pragma unroll
    for (int j = 0; j < 8; ++j)
      pack[j] = (short)tl[(half * 32 + k * 8 + j) * 132 + c];
    *(short8*)(orow + k * 8) = pack;
  }
}

// K6 (MFMA): flash attention; swapped QK^T. v5: KVBLK=128 (8 iters; fixed
// per-iter costs halve), s_setprio around MFMA clusters (T5).
__global__ __launch_bounds__(256) void k_attn(const float* __restrict__ qkv,
                                              const unsigned short* __restrict__ qkb,
                                              const unsigned short* __restrict__ vtb,
                                              unsigned short* __restrict__ atth) {
  int qt = blockIdx.x, h = blockIdx.y, b = blockIdx.z;
  __shared__ unsigned short Qs[64 * 40];     // 5120 B
  __shared__ unsigned short Ks[128 * 40];    // 10240 B
  __shared__ unsigned short Vt[32 * 136];    // 8704 B
  __shared__ unsigned short Pw[4 * 16 * 136];// 17408 B  (per-wave [q16][key128])
  int t = threadIdx.x;
  int lane = t & 63, w = t >> 6;
  int quad = lane >> 4, l16 = lane & 15;
  const float* qbase = qkv + (size_t)b * 1024 * 384;
  const unsigned short* qrow = qkb + (((size_t)b * 4 + h) * 2 + 0) * 1024 * 32;
  const unsigned short* krow = qkb + (((size_t)b * 4 + h) * 2 + 1) * 1024 * 32;
  const unsigned short* vrow = vtb + ((size_t)b * 4 + h) * 32 * 1024;
  int q0 = qt << 6;
  int hd = h * 32;

  {
    int r = t >> 2, cq = t & 3;
    short8 v = *(const short8*)(qrow + (size_t)(q0 + r) * 32 + cq * 8);
    *(short8*)(Qs + r * 40 + cq * 8) = v;
  }
  __syncthreads();
  short8 aq = *(const short8*)(Qs + (w * 16 + l16) * 40 + quad * 8);

  f32x4 O[2];
  O[0] = (f32x4){0.f, 0.f, 0.f, 0.f};
  O[1] = (f32x4){0.f, 0.f, 0.f, 0.f};
  float mi0 = -1e30f, li0 = 0.f;
  unsigned short* Pme = Pw + w * (16 * 136);
  const float scl = 0.17677669529663688f;

  for (int ci = 0; ci < 8; ++ci) {
    __syncthreads();
    int kn0 = ci << 7;
#pragma unroll
    for (int it = 0; it < 2; ++it) {
      int idx = it * 256 + t;
      int r = idx >> 2, cq = idx & 3;
      short8 kv = *(const short8*)(krow + (size_t)(kn0 + r) * 32 + cq * 8);
      *(short8*)(Ks + r * 40 + cq * 8) = kv;
      int d = idx >> 4, cc = idx & 15;
      short8 vv = *(const short8*)(vrow + (size_t)d * 1024 + kn0 + cc * 8);
      *(short8*)(Vt + d * 136 + cc * 8) = vv;
    }
    __syncthreads();

    // swapped: S[nt] row = key(nt*16 + quad*4+reg), col = q(l16)
    f32x4 S[8];
#pragma unroll
    for (int nt = 0; nt < 8; ++nt) S[nt] = (f32x4){0.f, 0.f, 0.f, 0.f};
    __builtin_amdgcn_s_setprio(1);
#pragma unroll
    for (int nt = 0; nt < 8; ++nt) {
      short8 bk = *(const short8*)(Ks + (nt * 16 + l16) * 40 + quad * 8);
      S[nt] = __builtin_amdgcn_mfma_f32_16x16x32_bf16(bk, aq, S[nt], 0, 0, 0);
    }
    __builtin_amdgcn_s_setprio(0);

    // lane-local 32 scores of q-row l16
    float mg[8];
#pragma unroll
    for (int nt = 0; nt < 8; ++nt)
      mg[nt] = fmaxf(fmaxf(S[nt][0], S[nt][1]), fmaxf(S[nt][2], S[nt][3]));
    float rmr = fmaxf(fmaxf(fmaxf(mg[0], mg[1]), fmaxf(mg[2], mg[3])),
                      fmaxf(fmaxf(mg[4], mg[5]), fmaxf(mg[6], mg[7])));
    float rm = rmr * scl;
    rm = fmaxf(rm, __shfl_xor(rm, 16));
    rm = fmaxf(rm, __shfl_xor(rm, 32));
    float nm = fmaxf(mi0, rm);
    float alpha = __expf(mi0 - nm);
    mi0 = nm;

    float pstot = 0.f;
    unsigned short* pwr = Pme + l16 * 136 + quad * 4;
#pragma unroll
    for (int nt = 0; nt < 8; ++nt) {
      float p0 = __expf(S[nt][0] * scl - nm);
      float p1 = __expf(S[nt][1] * scl - nm);
      float p2 = __expf(S[nt][2] * scl - nm);
      float p3 = __expf(S[nt][3] * scl - nm);
      pstot += (p0 + p1) + (p2 + p3);
      uint2 u;
      u.x = (unsigned int)f2bf(p0) | ((unsigned int)f2bf(p1) << 16);
      u.y = (unsigned int)f2bf(p2) | ((unsigned int)f2bf(p3) << 16);
      *(uint2*)(pwr + nt * 16) = u;
    }
    float ps = pstot;
    ps += __shfl_xor(ps, 16);
    ps += __shfl_xor(ps, 32);
    li0 = li0 * alpha + ps;

    // transpose alpha from q=l16 domain to q=quad*4+reg (O row domain)
    float al0 = __shfl(alpha, quad * 4 + 0);
    float al1 = __shfl(alpha, quad * 4 + 1);
    float al2 = __shfl(alpha, quad * 4 + 2);
    float al3 = __shfl(alpha, quad * 4 + 3);
    O[0][0] *= al0; O[1][0] *= al0;
    O[0][1] *= al1; O[1][1] *= al1;
    O[0][2] *= al2; O[1][2] *= al2;
    O[0][3] *= al3; O[1][3] *= al3;

    __builtin_amdgcn_s_setprio(1);
#pragma unroll
    for (int kc = 0; kc < 4; ++kc) {
      short8 bv0 = *(const short8*)(Vt + l16 * 136 + kc * 32 + quad * 8);
      short8 bv1 = *(const short8*)(Vt + (16 + l16) * 136 + kc * 32 + quad * 8);
      short8 ap = *(const short8*)(Pme + l16 * 136 + kc * 32 + quad * 8);
      O[0] = __builtin_amdgcn_mfma_f32_16x16x32_bf16(ap, bv0, O[0], 0, 0, 0);
      O[1] = __builtin_amdgcn_mfma_f32_16x16x32_bf16(ap, bv1, O[1], 0, 0, 0);
    }
    __builtin_amdgcn_s_setprio(0);
  }

#pragma unroll
  for (int reg = 0; reg < 4; ++reg) {
    float lit = __shfl(li0, quad * 4 + reg);
    int n = q0 + w * 16 + quad * 4 + reg;
    float inv = 1.f / lit;
    size_t mrow = ((size_t)b * 1024 + n) * 128;
    int m7 = n & 7;
#pragma unroll
    for (int nt = 0; nt < 2; ++nt) {
      int dd = hd + nt * 16 + l16;
      float val = O[nt][reg] * inv + qbase[(size_t)n * 384 + 256 + dd];
      int ch = dd >> 3;
      int slot = (ch & 8) | ((ch & 7) ^ m7);
      atth[mrow + slot * 8 + (dd & 7)] = f2bf(val);
    }
  }
}

// K8 (MFMA): conv1d over n as GEMM M=64(oc half) x N=128(n tile) x K=640
// (5 taps x 128 ic), windowed B rows like conv_pe. +f32 residual from xv2.
__global__ __launch_bounds__(256) void k_conv1d_mfma(
    const unsigned short* __restrict__ xph, const unsigned short* __restrict__ wch,
    const float* __restrict__ xv2, float* __restrict__ xv3) {
  extern __shared__ char cs[];
  unsigned short* Wl = (unsigned short*)cs;            // [64][640] = 81920 B
  unsigned short* xl = (unsigned short*)(cs + 81920);  // [132][128] = 33792 B
  int ntile = blockIdx.x, b = blockIdx.y, oh = blockIdx.z;
  int n0 = ntile << 7;                     // 128 n per block
  int t = threadIdx.x, lane = t & 63, w = t >> 6;
  int n16 = lane & 15, q = lane >> 4;

  const unsigned short* wsrc = wch + (size_t)oh * 64 * 640;
  for (int j = 0; j < 20; ++j) {
    int seg = w * 20 + j;                  // 80 segs x 1KiB
    gl_lds16((const char*)wsrc + (seg << 10) + lane * 16, (char*)Wl + (seg << 10));
  }
  const unsigned short* xpb = xph + (size_t)b * 1024 * 128;
  for (int j = 0; j < 8; ++j) {
    int seg = w * 8 + j;                   // 32 segs: xl rows 2..129 <- n0..n0+127
    gl_lds16((const char*)xpb + (size_t)n0 * 256 + (seg << 10) + lane * 16,
             (char*)xl + 512 + (seg << 10));
  }
  {                                        // patch rows 0,1,130,131 (window edges)
    int ri = t >> 6, j2 = t & 63;
    int j = (ri < 2) ? ri : (128 + ri);
    int n = n0 + j - 2;
    unsigned int v = 0;
    if (n >= 0 && n < 1024) v = ((const unsigned int*)xpb)[(size_t)n * 64 + j2];
    ((unsigned int*)xl)[j * 64 + j2] = v;
  }
  __syncthreads();

  f32x4 acc[4][2];
#pragma unroll
  for (int mt = 0; mt < 4; ++mt)
#pragma unroll
    for (int nt = 0; nt < 2; ++nt) acc[mt][nt] = (f32x4){0.f, 0.f, 0.f, 0.f};

  int nb = w * 32;
#pragma unroll
  for (int kk = 0; kk < 5; ++kk) {
    int swb = (n16 + kk + 6) & 7;          // global x-row parity (n0 mult of 128)
#pragma unroll
    for (int kf = 0; kf < 4; ++kf) {
      int ca = kf * 4 + q;
      int LC = kk * 16 + kf * 4 + q;
      int slotA = (LC & 120) | ((LC & 7) ^ (n16 & 7));
      const unsigned short* Ap = Wl + n16 * 640 + slotA * 8;
      short8 a0 = *(const short8*)(Ap);
      short8 a1 = *(const short8*)(Ap + 16 * 640);
      short8 a2 = *(const short8*)(Ap + 32 * 640);
      short8 a3 = *(const short8*)(Ap + 48 * 640);
      int slotB = (ca & 8) | ((ca & 7) ^ swb);
      const unsigned short* Bp = xl + (nb + n16 + kk) * 128 + slotB * 8;
      short8 b0 = *(const short8*)(Bp);
      short8 b1 = *(const short8*)(Bp + 16 * 128);
      acc[0][0] = __builtin_amdgcn_mfma_f32_16x16x32_bf16(a0, b0, acc[0][0], 0, 0, 0);
      acc[0][1] = __builtin_amdgcn_mfma_f32_16x16x32_bf16(a0, b1, acc[0][1], 0, 0, 0);
      acc[1][0] = __builtin_amdgcn_mfma_f32_16x16x32_bf16(a1, b0, acc[1][0], 0, 0, 0);
      acc[1][1] = __builtin_amdgcn_mfma_f32_16x16x32_bf16(a1, b1, acc[1][1], 0, 0, 0);
      acc[2][0] = __builtin_amdgcn_mfma_f32_16x16x32_bf16(a2, b0, acc[2][0], 0, 0, 0);
      acc[2][1] = __builtin_amdgcn_mfma_f32_16x16x32_bf16(a2, b1, acc[2][1], 0, 0, 0);
      acc[3][0] = __builtin_amdgcn_mfma_f32_16x16x32_bf16(a3, b0, acc[3][0], 0, 0, 0);
      acc[3][1] = __builtin_amdgcn_mfma_f32_16x16x32_bf16(a3, b1, acc[3][1], 0, 0, 0);
    }
  }

#pragma unroll
  for (int mt = 0; mt < 4; ++mt) {
#pragma unroll
    for (int i = 0; i < 4; ++i) {
      int oc = oh * 64 + mt * 16 + q * 4 + i;
      const float* res = xv2 + ((size_t)b * 128 + oc) * 1024;
      float* outp = xv3 + ((size_t)b * 128 + oc) * 1024;
#pragma unroll
      for (int nt = 0; nt < 2; ++nt) {
        int n = n0 + nb + nt * 16 + n16;
        outp[n] = acc[mt][nt][i] + res[n];
      }
    }
  }
}

// K9: bilinear 32->96 align_corners=True, f32 out
__global__ __launch_bounds__(256) void k_bilinear(const float* __restrict__ xv3,
                                                  float* __restrict__ out) {
  int idx = blockIdx.x * 256 + threadIdx.x;
  int X = idx % 96;
  int t2 = idx / 96;
  int Y = t2 % 96;
  int bc = t2 / 96;
  const float* src = xv3 + (size_t)bc * 1024;
  const float r = 31.f / 95.f;
  float py = Y * r, px = X * r;
  int y0 = (int)py, x0 = (int)px;
  float wy = py - y0, wx = px - x0;
  int y1 = y0 < 31 ? y0 + 1 : 31, x1 = x0 < 31 ? x0 + 1 : 31;
  float a = src[y0 * 32 + x0], b_ = src[y0 * 32 + x1];
  float c_ = src[y1 * 32 + x0], d_ = src[y1 * 32 + x1];
  float t0 = a * (1.f - wy) + c_ * wy;
  float t1 = b_ * (1.f - wy) + d_ * wy;
  out[idx] = t0 * (1.f - wx) + t1 * wx;
}

extern "C" void kernel_launch(void* const* d_in, const int* in_sizes, int n_in,
                              void* d_out, int out_size, void* d_ws, size_t ws_size,
                              hipStream_t stream) {
  (void)in_sizes; (void)n_in; (void)out_size; (void)ws_size;
  const float* s1    = (const float*)d_in[0];
  const float* o     = (const float*)d_in[1];
  const int*   indx  = (const int*)d_in[2];
  const float* pe_w  = (const float*)d_in[3];
  const float* bn_g  = (const float*)d_in[4];
  const float* bn_b  = (const float*)d_in[5];
  const float* bn_m  = (const float*)d_in[6];
  const float* bn_v  = (const float*)d_in[7];
  const float* lnx_g = (const float*)d_in[8];
  const float* lnx_b = (const float*)d_in[9];
  const float* lny_g = (const float*)d_in[10];
  const float* lny_b = (const float*)d_in[11];
  const float* qkv_w = (const float*)d_in[12];
  const float* qkv_b = (const float*)d_in[13];
  const float* yv_w  = (const float*)d_in[14];
  const float* yv_b  = (const float*)d_in[15];
  const float* proj_w = (const float*)d_in[16];
  const float* proj_b = (const float*)d_in[17];
  const float* c1d_w  = (const float*)d_in[18];

  char* ws = (char*)d_ws;
  unsigned short* xTh = (unsigned short*)ws;
  unsigned short* ymh = (unsigned short*)(ws + 37748736);
  // d_out scratch: wpk +0 (41KB); wch +64KB (160KB); wqkh +448KB (98KB);
  // wyvh +560KB (32KB); wprh +608KB (32KB).
  unsigned short* wpk = (unsigned short*)d_out;
  unsigned short* wch = (unsigned short*)((char*)d_out + 65536);
  unsigned short* wqkh = (unsigned short*)((char*)d_out + 458752);
  unsigned short* wyvh = (unsigned short*)((char*)d_out + 573440);
  unsigned short* wprh = (unsigned short*)((char*)d_out + 622592);
  // Phase 2 (xTh dead after k_conv_pe): region A = [ws+0, 37.7MB)
  float* ori  = (float*)ws;                 // [0, 8.4MB)
  unsigned short* snh  = (unsigned short*)(ws + 8388608);   // 4.2MB bf16
  unsigned short* oflh = (unsigned short*)(ws + 16777216);  // 4.2MB bf16
  unsigned short* atth = (unsigned short*)(ws + 25165824);  // 4.2MB bf16
  // Phase 3 (ymh dead after k_pool9ln): region B = [ws+37.7MB, 75.5MB)
  float* qkvb  = (float*)(ws + 37748736);   // 25.2MB
  float* yvbuf = (float*)(ws + 62914560);   // 8.4MB, dead after k_cvt
  unsigned short* qkb = (unsigned short*)(ws + 16777216);  // alias oflh (dead), 8.4MB
  unsigned short* vtb = (unsigned short*)(ws + 71303168);  // tail, 4.2MB
  float* xv2   = (float*)(ws + 37748736);   // alias qkvb (dead after k_attn)
  float* xv3   = (float*)(ws + 46137344);
  unsigned short* xph = (unsigned short*)(ws + 62914560);  // alias yvbuf (dead), 4.2MB

  hipLaunchKernelGGL(k_prep, dim3(8), dim3(256), 0, stream, pe_w, wpk);
  hipLaunchKernelGGL(k_prepcw, dim3(320), dim3(256), 0, stream, c1d_w, wch);
  hipLaunchKernelGGL(k_prepw, dim3(24), dim3(256), 0, stream, qkv_w, wqkh, 384);
  hipLaunchKernelGGL(k_prepw, dim3(8), dim3(256), 0, stream, yv_w, wyvh, 128);
  hipLaunchKernelGGL(k_prepw, dim3(8), dim3(256), 0, stream, proj_w, wprh, 128);
  hipLaunchKernelGGL(k_transpose, dim3(128, 16), dim3(256), 0, stream, s1, xTh);
  hipLaunchKernelGGL(k_conv_pe, dim3(36, 16), dim3(256), 75008, stream,
                     xTh, wpk, bn_g, bn_b, bn_m, bn_v, indx, ymh);
  hipLaunchKernelGGL(k_pool9ln, dim3(64, 16), dim3(256), 0, stream, ymh, lny_g, lny_b, ori, snh);
  hipLaunchKernelGGL(k_poolo_ln, dim3(32, 16), dim3(256), 0, stream, o, lnx_g, lnx_b, oflh);
  hipLaunchKernelGGL(k_gemm_mfma, dim3(128, 6), dim3(256), 0, stream, oflh, wqkh, qkv_b, qkvb, 384);
  hipLaunchKernelGGL(k_gemm_mfma, dim3(128, 2), dim3(256), 0, stream, snh, wyvh, yv_b, yvbuf, 128);
  hipLaunchKernelGGL(k_cvt, dim3(16, 16), dim3(256), 0, stream, qkvb, yvbuf, qkb, vtb);
  hipLaunchKernelGGL(k_attn, dim3(16, 4, 16), dim3(256), 0, stream, qkvb, qkb, vtb, atth);
  hipLaunchKernelGGL(k_proj_mfma, dim3(128, 2), dim3(256), 0, stream, atth, wprh, proj_b, ori, xv2, xph);
  hipLaunchKernelGGL(k_conv1d_mfma, dim3(8, 16, 2), dim3(256), 115712, stream, xph, wch, xv2, xv3);
  hipLaunchKernelGGL(k_bilinear, dim3(73728), dim3(256), 0, stream, xv3, (float*)d_out);
}

// Round 17
// 330.890 us; speedup vs baseline: 1.7945x; 1.0444x over previous
//
#include <hip/hip_runtime.h>

#define FEAT 18432

typedef __attribute__((ext_vector_type(8))) short short8;
typedef __attribute__((ext_vector_type(4))) short short4t;
typedef __attribute__((ext_vector_type(4))) float f32x4;

__device__ __forceinline__ float b2f(unsigned short s) {
  union { unsigned int u; float f; } v; v.u = ((unsigned int)s) << 16; return v.f;
}
__device__ __forceinline__ unsigned short f2bf(float x) {
  union { float f; unsigned int u; } v; v.f = x;
  unsigned int u = v.u;
  unsigned int r = (u + 0x7FFFu + ((u >> 16) & 1u)) >> 16;
  return (unsigned short)r;
}

// async global->LDS, 16B per lane; LDS dest = base + lane*16 (wave-uniform base)
__device__ __forceinline__ void gl_lds16(const void* g, void* l) {
  __builtin_amdgcn_global_load_lds(
      (const __attribute__((address_space(1))) unsigned int*)g,
      (__attribute__((address_space(3))) unsigned int*)l, 16, 0, 0);
}

// K0: s1[b][c][96][96] (f32) -> xTn[b][f][ic] bf16, swizzled 16B chunks.
__global__ __launch_bounds__(256) void k_transpose(const float* __restrict__ s1,
                                                   unsigned short* __restrict__ xT) {
  int c = blockIdx.x, b = blockIdx.y;
  __shared__ float lds[96 * 99];            // plane [h][w], pad 99
  int t = threadIdx.x;
  const float* src = s1 + ((size_t)b * 128 + c) * 9216;
  for (int idx = t; idx < 2304; idx += 256) {
    float4 v = ((const float4*)src)[idx];
    int h = idx / 24, w0 = (idx - h * 24) * 4;
    float* p = lds + h * 99 + w0;
    p[0] = v.x; p[1] = v.y; p[2] = v.z; p[3] = v.w;
  }
  __syncthreads();
  unsigned short* dstb = xT + (size_t)b * FEAT * 64;
  int sw = c & 7;
  for (int idx = t; idx < 1152; idx += 256) {
    int p1p2 = idx >> 3, gh = idx & 7;
    int p1 = p1p2 / 12, p2 = p1p2 - p1 * 12;
    const float* row = lds + (gh * 12 + p1) * 99 + p2;
    uint4 u;
    u.x = f2bf(row[0])  | ((unsigned int)f2bf(row[12]) << 16);
    u.y = f2bf(row[24]) | ((unsigned int)f2bf(row[36]) << 16);
    u.z = f2bf(row[48]) | ((unsigned int)f2bf(row[60]) << 16);
    u.w = f2bf(row[72]) | ((unsigned int)f2bf(row[84]) << 16);
    int f = p1p2 * 128 + c;
    int pos = gh ^ sw;
    *(uint4*)(dstb + (size_t)f * 64 + pos * 8) = u;
  }
}

// K_prepall: all weight packing in one launch (368 blocks).
// [0,8): pe_w->wpk; [8,328): c1d_w->wch; [328,352): qkv_w->wqkh;
// [352,360): yv_w->wyvh; [360,368): proj_w->wprh.
__device__ __forceinline__ void prepw_body(const float* __restrict__ W,
                                           unsigned short* __restrict__ dst,
                                           int ncols, int bx, int t) {
  int idx = bx * 256 + t;
  if (idx >= ncols * 16) return;
  int n = idx >> 4, c = idx & 15;
  int slot = (c & 8) | ((c & 7) ^ (n & 7));
  const float* s = W + (size_t)n * 128 + c * 8;
  uint4 u;
  u.x = (unsigned int)f2bf(s[0]) | ((unsigned int)f2bf(s[1]) << 16);
  u.y = (unsigned int)f2bf(s[2]) | ((unsigned int)f2bf(s[3]) << 16);
  u.z = (unsigned int)f2bf(s[4]) | ((unsigned int)f2bf(s[5]) << 16);
  u.w = (unsigned int)f2bf(s[6]) | ((unsigned int)f2bf(s[7]) << 16);
  *(uint4*)(dst + (size_t)n * 128 + slot * 8) = u;
}

__global__ __launch_bounds__(256) void k_prepall(
    const float* __restrict__ pe_w, unsigned short* __restrict__ wpk,
    const float* __restrict__ cw, unsigned short* __restrict__ wch,
    const float* __restrict__ qkv_w, unsigned short* __restrict__ wqkh,
    const float* __restrict__ yv_w, unsigned short* __restrict__ wyvh,
    const float* __restrict__ proj_w, unsigned short* __restrict__ wprh) {
  int bx = blockIdx.x, t = threadIdx.x;
  if (bx < 8) {
    int oc0 = bx * 8;
    for (int e = t; e < 2560; e += 256) {
      int oc = oc0 + e / 320;
      int kL = e - (e / 320) * 320;
      int ic = kL & 63, kk = kL >> 6;
      float v = pe_w[(oc * 64 + ic) * 5 + kk];
      int LC = kL >> 3;
      int pos = (LC & 56) | ((LC & 7) ^ (oc & 7));
      wpk[oc * 320 + (pos << 3) + (kL & 7)] = f2bf(v);
    }
  } else if (bx < 328) {
    int e = (bx - 8) * 256 + t;
    int oc = e / 640, kl = e - (e / 640) * 640;
    int kk = kl >> 7, ic = kl & 127;
    float v = cw[(size_t)oc * 640 + ic * 5 + kk];
    int LC = kl >> 3;
    int pos = (LC & 120) | ((LC & 7) ^ (oc & 7));
    wch[(size_t)oc * 640 + pos * 8 + (kl & 7)] = f2bf(v);
  } else if (bx < 352) {
    prepw_body(qkv_w, wqkh, 384, bx - 328, t);
  } else if (bx < 360) {
    prepw_body(yv_w, wyvh, 128, bx - 352, t);
  } else {
    prepw_body(proj_w, wprh, 128, bx - 360, t);
  }
}

// K1 (MFMA): conv1d over f as GEMM + BN(eval) + ReLU + selective square.
__global__ __launch_bounds__(256) void k_conv_pe(
    const unsigned short* __restrict__ xT, const unsigned short* __restrict__ wpk,
    const float* __restrict__ bn_g, const float* __restrict__ bn_b,
    const float* __restrict__ bn_m, const float* __restrict__ bn_v,
    const int* __restrict__ indexp, unsigned short* __restrict__ ym) {
  extern __shared__ char smem[];
  unsigned short* Wl = (unsigned short*)smem;
  unsigned short* xl = (unsigned short*)(smem + 40960);
  float* scf = (float*)(smem + 74240);
  float* shf = (float*)(smem + 74496);
  int*   sli = (int*)(smem + 74752);
  int t = threadIdx.x;
  int b = blockIdx.y;
  int blk_f0 = blockIdx.x << 9;
  int lane = t & 63, w = t >> 6;
  int n16 = lane & 15, q = lane >> 4;

  for (int j = 0; j < 10; ++j) {
    int seg = w * 10 + j;
    gl_lds16((const char*)wpk + (seg << 10) + lane * 16, (char*)Wl + (seg << 10));
  }
  if (t < 64) {
    float sc = bn_g[t] * rsqrtf(bn_v[t] + 1e-5f);
    scf[t] = sc;
    shf[t] = bn_b[t] - bn_m[t] * sc;
    int i0 = indexp[0] / 12 * 8 + indexp[1] / 12;
    int i1 = indexp[2] / 12 * 8 + indexp[3] / 12;
    int i2 = indexp[4] / 12 * 8 + indexp[5] / 12;
    int i3 = indexp[6] / 12 * 8 + indexp[7] / 12;
    sli[t] = (t == i0 || t == i1 || t == i2 || t == i3) ? 1 : 0;
  }

  const unsigned short* xb = xT + (size_t)b * FEAT * 64;
  const unsigned int* xbu = (const unsigned int*)xb;

  for (int wnd = 0; wnd < 2; ++wnd) {
    int F0 = blk_f0 + (wnd << 8);
    __syncthreads();
    int flA = (F0 == 0) ? 2 : 0;
    for (int j = 0; j < 8; ++j) {
      int seg = (w << 3) + j;
      int gRow = F0 - 2 + flA + (seg << 3);
      gl_lds16((const char*)xb + (size_t)gRow * 128 + lane * 16,
               (char*)xl + flA * 128 + (seg << 10));
    }
    if (t < 128) {
      int r0 = (flA == 2) ? 0 : 256;
      int fl = (t < 64) ? (r0 + (t >> 5)) : (258 + ((t >> 5) & 1));
      int j = t & 31;
      int f = F0 - 2 + fl;
      unsigned int v = 0;
      if (f >= 0 && f < FEAT) v = xbu[(size_t)f * 32 + j];
      ((unsigned int*)xl)[fl * 32 + j] = v;
    }
    __syncthreads();

    f32x4 acc[4][4];
#pragma unroll
    for (int mt = 0; mt < 4; ++mt)
#pragma unroll
      for (int nt = 0; nt < 4; ++nt) acc[mt][nt] = (f32x4){0.f, 0.f, 0.f, 0.f};

    int rowB = w * 64 + n16;
#pragma unroll
    for (int kk = 0; kk < 5; ++kk) {
      int swb = (n16 + kk + 6) & 7;
#pragma unroll
      for (int ih = 0; ih < 2; ++ih) {
        int ca = (ih << 2) | q;
        const unsigned short* Ap = Wl + kk * 64 + ((ca ^ (n16 & 7)) << 3) + n16 * 320;
        short8 a0 = *(const short8*)(Ap);
        short8 a1 = *(const short8*)(Ap + 16 * 320);
        short8 a2 = *(const short8*)(Ap + 32 * 320);
        short8 a3 = *(const short8*)(Ap + 48 * 320);
        const unsigned short* Bp = xl + ((ca ^ swb) << 3) + (rowB + kk) * 64;
        short8 b0 = *(const short8*)(Bp);
        short8 b1 = *(const short8*)(Bp + 16 * 64);
        short8 b2 = *(const short8*)(Bp + 32 * 64);
        short8 b3 = *(const short8*)(Bp + 48 * 64);
        acc[0][0] = __builtin_amdgcn_mfma_f32_16x16x32_bf16(a0, b0, acc[0][0], 0, 0, 0);
        acc[0][1] = __builtin_amdgcn_mfma_f32_16x16x32_bf16(a0, b1, acc[0][1], 0, 0, 0);
        acc[0][2] = __builtin_amdgcn_mfma_f32_16x16x32_bf16(a0, b2, acc[0][2], 0, 0, 0);
        acc[0][3] = __builtin_amdgcn_mfma_f32_16x16x32_bf16(a0, b3, acc[0][3], 0, 0, 0);
        acc[1][0] = __builtin_amdgcn_mfma_f32_16x16x32_bf16(a1, b0, acc[1][0], 0, 0, 0);
        acc[1][1] = __builtin_amdgcn_mfma_f32_16x16x32_bf16(a1, b1, acc[1][1], 0, 0, 0);
        acc[1][2] = __builtin_amdgcn_mfma_f32_16x16x32_bf16(a1, b2, acc[1][2], 0, 0, 0);
        acc[1][3] = __builtin_amdgcn_mfma_f32_16x16x32_bf16(a1, b3, acc[1][3], 0, 0, 0);
        acc[2][0] = __builtin_amdgcn_mfma_f32_16x16x32_bf16(a2, b0, acc[2][0], 0, 0, 0);
        acc[2][1] = __builtin_amdgcn_mfma_f32_16x16x32_bf16(a2, b1, acc[2][1], 0, 0, 0);
        acc[2][2] = __builtin_amdgcn_mfma_f32_16x16x32_bf16(a2, b2, acc[2][2], 0, 0, 0);
        acc[2][3] = __builtin_amdgcn_mfma_f32_16x16x32_bf16(a2, b3, acc[2][3], 0, 0, 0);
        acc[3][0] = __builtin_amdgcn_mfma_f32_16x16x32_bf16(a3, b0, acc[3][0], 0, 0, 0);
        acc[3][1] = __builtin_amdgcn_mfma_f32_16x16x32_bf16(a3, b1, acc[3][1], 0, 0, 0);
        acc[3][2] = __builtin_amdgcn_mfma_f32_16x16x32_bf16(a3, b2, acc[3][2], 0, 0, 0);
        acc[3][3] = __builtin_amdgcn_mfma_f32_16x16x32_bf16(a3, b3, acc[3][3], 0, 0, 0);
      }
    }

#pragma unroll
    for (int mt = 0; mt < 4; ++mt) {
#pragma unroll
      for (int i = 0; i < 4; ++i) {
        int oc = mt * 16 + q * 4 + i;
        float sc = scf[oc], sh = shf[oc];
        bool sel = sli[oc] != 0;
        unsigned short* yo = ym + ((size_t)b * 64 + oc) * FEAT + F0 + w * 64 + n16;
#pragma unroll
        for (int nt = 0; nt < 4; ++nt) {
          float y = fmaf(acc[mt][nt][i], sc, sh);
          y = fmaxf(y, 0.f);
          if (!sel) y *= y;
          yo[nt * 16] = f2bf(y);
        }
      }
    }
  }
}

// K2: 3x3 avg pool 96->32 + fused LayerNorm. Writes ori (f32) + snh (bf16 swz).
__global__ __launch_bounds__(256) void k_pool9ln(
    const unsigned short* __restrict__ ym, const float* __restrict__ lng,
    const float* __restrict__ lnb, float* __restrict__ ori,
    unsigned short* __restrict__ snh) {
  int oc = blockIdx.x, b = blockIdx.y;
  const unsigned short* src = ym + ((size_t)b * 64 + oc) * FEAT;
  int oh0 = (oc >> 3) << 2, ow0 = (oc & 7) << 2;
  __shared__ float red[8];
  int t = threadIdx.x;
  int c = t & 127, hr = t >> 7, wv = t >> 6, l64 = t & 63;
  float g = lng[c], bb = lnb[c];
  for (int p = 0; p < 8; ++p) {
    int nl = p * 2 + hr;
    int pg1 = nl >> 2, pg2 = nl & 3;
    int pbase = (pg1 * 36 + pg2 * 3) * 128 + c;
    float s = 0.f;
#pragma unroll
    for (int dy = 0; dy < 3; ++dy)
#pragma unroll
      for (int dx = 0; dx < 3; ++dx)
        s += b2f(src[pbase + (dy * 12 + dx) * 128]);
    float val = s * (1.f / 9.f);
    float su = val, q = val * val;
#pragma unroll
    for (int off = 32; off > 0; off >>= 1) {
      su += __shfl_xor(su, off, 64);
      q += __shfl_xor(q, off, 64);
    }
    if (l64 == 0) { red[wv * 2] = su; red[wv * 2 + 1] = q; }
    __syncthreads();
    float S = red[hr * 4 + 0] + red[hr * 4 + 2];
    float Q = red[hr * 4 + 1] + red[hr * 4 + 3];
    float mean = S * (1.f / 128.f);
    float var = Q * (1.f / 128.f) - mean * mean;
    float inv = rsqrtf(var + 1e-5f);
    int n = (oh0 + pg1) * 32 + ow0 + pg2;
    size_t base = ((size_t)b * 1024 + n) * 128;
    ori[base + c] = val;
    float lnv = (val - mean) * inv * g + bb;
    int ch = c >> 3;
    int slot = (ch & 8) | ((ch & 7) ^ (n & 7));
    snh[base + slot * 8 + (c & 7)] = f2bf(lnv);
    __syncthreads();
  }
}

// K3: 2x2 avg pool of o + LayerNorm -> oflh bf16 swizzled
__global__ __launch_bounds__(256) void k_poolo_ln(
    const float* __restrict__ o, const float* __restrict__ lng,
    const float* __restrict__ lnb, unsigned short* __restrict__ oflh) {
  int y = blockIdx.x, b = blockIdx.y;
  __shared__ float pl[128 * 33];
  int t = threadIdx.x;
  for (int idx = t; idx < 4096; idx += 256) {
    int xo = idx & 31, c = idx >> 5;
    const float* p = o + (((size_t)b * 128 + c) * 64 + 2 * y) * 64 + 2 * xo;
    float2 a = *(const float2*)p;
    float2 d = *(const float2*)(p + 64);
    pl[c * 33 + xo] = 0.25f * (a.x + a.y + d.x + d.y);
  }
  __syncthreads();
  int xo = t >> 3, l8 = t & 7;
  float v[16]; float s = 0.f, q = 0.f;
#pragma unroll
  for (int i = 0; i < 16; ++i) {
    float x = pl[(l8 * 16 + i) * 33 + xo];
    v[i] = x; s += x; q += x * x;
  }
#pragma unroll
  for (int off = 1; off < 8; off <<= 1) {
    s += __shfl_xor(s, off, 8);
    q += __shfl_xor(q, off, 8);
  }
  float mean = s * (1.f / 128.f);
  float var = q * (1.f / 128.f) - mean * mean;
  float inv = rsqrtf(var + 1e-5f);
  int n = y * 32 + xo;
  unsigned short* dst = oflh + ((size_t)b * 1024 + n) * 128;
  int m7 = n & 7;
#pragma unroll
  for (int h = 0; h < 2; ++h) {
    int c = l8 * 2 + h;
    int slot = (c & 8) | ((c & 7) ^ m7);
    uint4 u;
    float w0 = (v[h * 8 + 0] - mean) * inv * lng[c * 8 + 0] + lnb[c * 8 + 0];
    float w1 = (v[h * 8 + 1] - mean) * inv * lng[c * 8 + 1] + lnb[c * 8 + 1];
    float w2 = (v[h * 8 + 2] - mean) * inv * lng[c * 8 + 2] + lnb[c * 8 + 2];
    float w3 = (v[h * 8 + 3] - mean) * inv * lng[c * 8 + 3] + lnb[c * 8 + 3];
    float w4 = (v[h * 8 + 4] - mean) * inv * lng[c * 8 + 4] + lnb[c * 8 + 4];
    float w5 = (v[h * 8 + 5] - mean) * inv * lng[c * 8 + 5] + lnb[c * 8 + 5];
    float w6 = (v[h * 8 + 6] - mean) * inv * lng[c * 8 + 6] + lnb[c * 8 + 6];
    float w7 = (v[h * 8 + 7] - mean) * inv * lng[c * 8 + 7] + lnb[c * 8 + 7];
    u.x = (unsigned int)f2bf(w0) | ((unsigned int)f2bf(w1) << 16);
    u.y = (unsigned int)f2bf(w2) | ((unsigned int)f2bf(w3) << 16);
    u.z = (unsigned int)f2bf(w4) | ((unsigned int)f2bf(w5) << 16);
    u.w = (unsigned int)f2bf(w6) | ((unsigned int)f2bf(w7) << 16);
    *(uint4*)(dst + slot * 8) = u;
  }
}

// Shared MFMA GEMM core: A[128 rows] x W[64 cols], K=128, bf16 swizzled inputs.
#define GEMM_CORE()                                                              \
  for (int j = 0; j < 8; ++j) {                                                  \
    int seg = w * 8 + j;                                                         \
    gl_lds16((const char*)A + (size_t)m0 * 256 + (seg << 10) + lane * 16,        \
             (char*)Al + (seg << 10));                                           \
  }                                                                              \
  for (int j = 0; j < 4; ++j) {                                                  \
    int seg = w * 4 + j;                                                         \
    gl_lds16((const char*)W + (size_t)n0 * 256 + (seg << 10) + lane * 16,        \
             (char*)Bl + (seg << 10));                                           \
  }                                                                              \
  __syncthreads();                                                               \
  int wm = w >> 1, wn = w & 1;                                                   \
  f32x4 acc[4][2];                                                               \
  _Pragma("unroll")                                                              \
  for (int mt = 0; mt < 4; ++mt)                                                 \
    _Pragma("unroll")                                                            \
    for (int nt = 0; nt < 2; ++nt) acc[mt][nt] = (f32x4){0.f, 0.f, 0.f, 0.f};    \
  _Pragma("unroll")                                                              \
  for (int kf = 0; kf < 4; ++kf) {                                               \
    int ca = kf * 4 + q;                                                         \
    int rA0 = wm * 64 + n16;                                                     \
    const unsigned short* Ap0 = Al + (size_t)rA0 * 128;                          \
    int slotA = (ca & 8) | ((ca & 7) ^ (rA0 & 7));                               \
    short8 a0 = *(const short8*)(Ap0 + slotA * 8);                               \
    short8 a1 = *(const short8*)(Ap0 + 16 * 128 + slotA * 8);                    \
    short8 a2 = *(const short8*)(Ap0 + 32 * 128 + slotA * 8);                    \
    short8 a3 = *(const short8*)(Ap0 + 48 * 128 + slotA * 8);                    \
    int rB0 = wn * 32 + n16;                                                     \
    const unsigned short* Bp0 = Bl + (size_t)rB0 * 128;                          \
    int slotB = (ca & 8) | ((ca & 7) ^ (rB0 & 7));                               \
    short8 b0 = *(const short8*)(Bp0 + slotB * 8);                               \
    short8 b1 = *(const short8*)(Bp0 + 16 * 128 + slotB * 8);                    \
    acc[0][0] = __builtin_amdgcn_mfma_f32_16x16x32_bf16(a0, b0, acc[0][0], 0, 0, 0); \
    acc[0][1] = __builtin_amdgcn_mfma_f32_16x16x32_bf16(a0, b1, acc[0][1], 0, 0, 0); \
    acc[1][0] = __builtin_amdgcn_mfma_f32_16x16x32_bf16(a1, b0, acc[1][0], 0, 0, 0); \
    acc[1][1] = __builtin_amdgcn_mfma_f32_16x16x32_bf16(a1, b1, acc[1][1], 0, 0, 0); \
    acc[2][0] = __builtin_amdgcn_mfma_f32_16x16x32_bf16(a2, b0, acc[2][0], 0, 0, 0); \
    acc[2][1] = __builtin_amdgcn_mfma_f32_16x16x32_bf16(a2, b1, acc[2][1], 0, 0, 0); \
    acc[3][0] = __builtin_amdgcn_mfma_f32_16x16x32_bf16(a3, b0, acc[3][0], 0, 0, 0); \
    acc[3][1] = __builtin_amdgcn_mfma_f32_16x16x32_bf16(a3, b1, acc[3][1], 0, 0, 0); \
  }

// K5a (MFMA): qkv GEMM + fused cvt. n<256 -> qkb bf16 [b][h][kind][1024][32];
// n>=256 -> vres f32 [b][1024][128].
__global__ __launch_bounds__(256) void k_gemm_qkv(
    const unsigned short* __restrict__ A, const unsigned short* __restrict__ W,
    const float* __restrict__ bias, unsigned short* __restrict__ qkb,
    float* __restrict__ vres) {
  __shared__ unsigned short Al[128 * 128];
  __shared__ unsigned short Bl[64 * 128];
  int m0 = blockIdx.x << 7, n0 = blockIdx.y << 6;
  int t = threadIdx.x;
  int lane = t & 63, w = t >> 6;
  int n16 = lane & 15, q = lane >> 4;
  GEMM_CORE()

  int bb = m0 >> 10;
  int nbase = (m0 & 1023) + wm * 64;
#pragma unroll
  for (int mt = 0; mt < 4; ++mt) {
#pragma unroll
    for (int i = 0; i < 4; ++i) {
      int nloc = nbase + mt * 16 + q * 4 + i;
#pragma unroll
      for (int nt = 0; nt < 2; ++nt) {
        int n = n0 + wn * 32 + nt * 16 + n16;
        float val = acc[mt][nt][i] + bias[n];
        if (n < 256) {
          int kind = n >> 7, h = (n >> 5) & 3, d = n & 31;
          qkb[((((size_t)bb * 4 + h) * 2 + kind) * 1024 + nloc) * 32 + d] = f2bf(val);
        } else {
          vres[((size_t)bb * 1024 + nloc) * 128 + (n - 256)] = val;
        }
      }
    }
  }
}

// K5b (MFMA): yv GEMM + fused transpose-cvt -> vtb bf16 [b][h][32][1024].
__global__ __launch_bounds__(256) void k_gemm_yv(
    const unsigned short* __restrict__ A, const unsigned short* __restrict__ W,
    const float* __restrict__ bias, unsigned short* __restrict__ vtb) {
  __shared__ unsigned short Al[128 * 128];
  __shared__ unsigned short Bl[64 * 128];
  int m0 = blockIdx.x << 7, n0 = blockIdx.y << 6;
  int t = threadIdx.x;
  int lane = t & 63, w = t >> 6;
  int n16 = lane & 15, q = lane >> 4;
  GEMM_CORE()

  int bb = m0 >> 10;
  int nbase = (m0 & 1023) + wm * 64;
#pragma unroll
  for (int mt = 0; mt < 4; ++mt) {
    int nloc = nbase + mt * 16 + q * 4;      // 4 consecutive n, 8B-aligned
#pragma unroll
    for (int nt = 0; nt < 2; ++nt) {
      int c = n0 + wn * 32 + nt * 16 + n16;  // 0..127
      float pb = bias[c];
      int h = c >> 5, d = c & 31;
      short4t pk;
      pk[0] = (short)f2bf(acc[mt][nt][0] + pb);
      pk[1] = (short)f2bf(acc[mt][nt][1] + pb);
      pk[2] = (short)f2bf(acc[mt][nt][2] + pb);
      pk[3] = (short)f2bf(acc[mt][nt][3] + pb);
      *(short4t*)(vtb + (((size_t)bb * 4 + h) * 32 + d) * 1024 + nloc) = pk;
    }
  }
}

// K_projm (MFMA): xv2[b][c][n] f32 + xph[b][n][c] bf16 (swizzled rows) =
// (atth @ proj_w^T) + proj_b + ori.
__global__ __launch_bounds__(256) void k_proj_mfma(
    const unsigned short* __restrict__ A, const unsigned short* __restrict__ W,
    const float* __restrict__ bias, const float* __restrict__ ori,
    float* __restrict__ xv2, unsigned short* __restrict__ xph) {
  __shared__ unsigned short Al[128 * 128];
  __shared__ unsigned short Bl[64 * 128];
  int m0 = blockIdx.x << 7, n0 = blockIdx.y << 6;
  int t = threadIdx.x;
  int lane = t & 63, w = t >> 6;
  int n16 = lane & 15, q = lane >> 4;
  GEMM_CORE()

  int bb = m0 >> 10;
  int nbase = (m0 & 1023) + wm * 64;
#pragma unroll
  for (int mt = 0; mt < 4; ++mt) {
    int nloc = nbase + mt * 16 + q * 4;
    const float* orow = ori + ((size_t)bb * 1024 + nloc) * 128;
#pragma unroll
    for (int nt = 0; nt < 2; ++nt) {
      int c = n0 + wn * 32 + nt * 16 + n16;
      float pb = bias[c];
      float4 vv;
      vv.x = acc[mt][nt][0] + pb + orow[c];
      vv.y = acc[mt][nt][1] + pb + orow[128 + c];
      vv.z = acc[mt][nt][2] + pb + orow[256 + c];
      vv.w = acc[mt][nt][3] + pb + orow[384 + c];
      *(float4*)(xv2 + ((size_t)bb * 128 + c) * 1024 + nloc) = vv;
      int ch = c >> 3, ce = c & 7;
#pragma unroll
      for (int i = 0; i < 4; ++i) {
        int nrow = nloc + i;
        int slot = (ch & 8) | ((ch & 7) ^ (nrow & 7));
        float val = (i == 0) ? vv.x : (i == 1) ? vv.y : (i == 2) ? vv.z : vv.w;
        xph[((size_t)bb * 1024 + nrow) * 128 + slot * 8 + ce] = f2bf(val);
      }
    }
  }
}

// K6 (MFMA): flash attention; swapped QK^T; KVBLK=128; setprio around MFMA.
// v residual from compact vres f32.
__global__ __launch_bounds__(256) void k_attn(const float* __restrict__ vres,
                                              const unsigned short* __restrict__ qkb,
                                              const unsigned short* __restrict__ vtb,
                                              unsigned short* __restrict__ atth) {
  int qt = blockIdx.x, h = blockIdx.y, b = blockIdx.z;
  __shared__ unsigned short Qs[64 * 40];     // 5120 B
  __shared__ unsigned short Ks[128 * 40];    // 10240 B
  __shared__ unsigned short Vt[32 * 136];    // 8704 B
  __shared__ unsigned short Pw[4 * 16 * 136];// 17408 B
  int t = threadIdx.x;
  int lane = t & 63, w = t >> 6;
  int quad = lane >> 4, l16 = lane & 15;
  const unsigned short* qrow = qkb + (((size_t)b * 4 + h) * 2 + 0) * 1024 * 32;
  const unsigned short* krow = qkb + (((size_t)b * 4 + h) * 2 + 1) * 1024 * 32;
  const unsigned short* vrow = vtb + ((size_t)b * 4 + h) * 32 * 1024;
  int q0 = qt << 6;
  int hd = h * 32;

  {
    int r = t >> 2, cq = t & 3;
    short8 v = *(const short8*)(qrow + (size_t)(q0 + r) * 32 + cq * 8);
    *(short8*)(Qs + r * 40 + cq * 8) = v;
  }
  __syncthreads();
  short8 aq = *(const short8*)(Qs + (w * 16 + l16) * 40 + quad * 8);

  f32x4 O[2];
  O[0] = (f32x4){0.f, 0.f, 0.f, 0.f};
  O[1] = (f32x4){0.f, 0.f, 0.f, 0.f};
  float mi0 = -1e30f, li0 = 0.f;
  unsigned short* Pme = Pw + w * (16 * 136);
  const float scl = 0.17677669529663688f;

  for (int ci = 0; ci < 8; ++ci) {
    __syncthreads();
    int kn0 = ci << 7;
#pragma unroll
    for (int it = 0; it < 2; ++it) {
      int idx = it * 256 + t;
      int r = idx >> 2, cq = idx & 3;
      short8 kv = *(const short8*)(krow + (size_t)(kn0 + r) * 32 + cq * 8);
      *(short8*)(Ks + r * 40 + cq * 8) = kv;
      int d = idx >> 4, cc = idx & 15;
      short8 vv = *(const short8*)(vrow + (size_t)d * 1024 + kn0 + cc * 8);
      *(short8*)(Vt + d * 136 + cc * 8) = vv;
    }
    __syncthreads();

    f32x4 S[8];
#pragma unroll
    for (int nt = 0; nt < 8; ++nt) S[nt] = (f32x4){0.f, 0.f, 0.f, 0.f};
    __builtin_amdgcn_s_setprio(1);
#pragma unroll
    for (int nt = 0; nt < 8; ++nt) {
      short8 bk = *(const short8*)(Ks + (nt * 16 + l16) * 40 + quad * 8);
      S[nt] = __builtin_amdgcn_mfma_f32_16x16x32_bf16(bk, aq, S[nt], 0, 0, 0);
    }
    __builtin_amdgcn_s_setprio(0);

    float mg[8];
#pragma unroll
    for (int nt = 0; nt < 8; ++nt)
      mg[nt] = fmaxf(fmaxf(S[nt][0], S[nt][1]), fmaxf(S[nt][2], S[nt][3]));
    float rmr = fmaxf(fmaxf(fmaxf(mg[0], mg[1]), fmaxf(mg[2], mg[3])),
                      fmaxf(fmaxf(mg[4], mg[5]), fmaxf(mg[6], mg[7])));
    float rm = rmr * scl;
    rm = fmaxf(rm, __shfl_xor(rm, 16));
    rm = fmaxf(rm, __shfl_xor(rm, 32));
    float nm = fmaxf(mi0, rm);
    float alpha = __expf(mi0 - nm);
    mi0 = nm;

    float pstot = 0.f;
    unsigned short* pwr = Pme + l16 * 136 + quad * 4;
#pragma unroll
    for (int nt = 0; nt < 8; ++nt) {
      float p0 = __expf(S[nt][0] * scl - nm);
      float p1 = __expf(S[nt][1] * scl - nm);
      float p2 = __expf(S[nt][2] * scl - nm);
      float p3 = __expf(S[nt][3] * scl - nm);
      pstot += (p0 + p1) + (p2 + p3);
      uint2 u;
      u.x = (unsigned int)f2bf(p0) | ((unsigned int)f2bf(p1) << 16);
      u.y = (unsigned int)f2bf(p2) | ((unsigned int)f2bf(p3) << 16);
      *(uint2*)(pwr + nt * 16) = u;
    }
    float ps = pstot;
    ps += __shfl_xor(ps, 16);
    ps += __shfl_xor(ps, 32);
    li0 = li0 * alpha + ps;

    float al0 = __shfl(alpha, quad * 4 + 0);
    float al1 = __shfl(alpha, quad * 4 + 1);
    float al2 = __shfl(alpha, quad * 4 + 2);
    float al3 = __shfl(alpha, quad * 4 + 3);
    O[0][0] *= al0; O[1][0] *= al0;
    O[0][1] *= al1; O[1][1] *= al1;
    O[0][2] *= al2; O[1][2] *= al2;
    O[0][3] *= al3; O[1][3] *= al3;

    __builtin_amdgcn_s_setprio(1);
#pragma unroll
    for (int kc = 0; kc < 4; ++kc) {
      short8 bv0 = *(const short8*)(Vt + l16 * 136 + kc * 32 + quad * 8);
      short8 bv1 = *(const short8*)(Vt + (16 + l16) * 136 + kc * 32 + quad * 8);
      short8 ap = *(const short8*)(Pme + l16 * 136 + kc * 32 + quad * 8);
      O[0] = __builtin_amdgcn_mfma_f32_16x16x32_bf16(ap, bv0, O[0], 0, 0, 0);
      O[1] = __builtin_amdgcn_mfma_f32_16x16x32_bf16(ap, bv1, O[1], 0, 0, 0);
    }
    __builtin_amdgcn_s_setprio(0);
  }

#pragma unroll
  for (int reg = 0; reg < 4; ++reg) {
    float lit = __shfl(li0, quad * 4 + reg);
    int n = q0 + w * 16 + quad * 4 + reg;
    float inv = 1.f / lit;
    size_t mrow = ((size_t)b * 1024 + n) * 128;
    int m7 = n & 7;
#pragma unroll
    for (int nt = 0; nt < 2; ++nt) {
      int dd = hd + nt * 16 + l16;
      float val = O[nt][reg] * inv + vres[mrow + dd];
      int ch = dd >> 3;
      int slot = (ch & 8) | ((ch & 7) ^ m7);
      atth[mrow + slot * 8 + (dd & 7)] = f2bf(val);
    }
  }
}

// K8 (MFMA): conv1d over n as GEMM M=64 x N=128 x K=640, windowed B rows.
__global__ __launch_bounds__(256) void k_conv1d_mfma(
    const unsigned short* __restrict__ xph, const unsigned short* __restrict__ wch,
    const float* __restrict__ xv2, float* __restrict__ xv3) {
  extern __shared__ char cs[];
  unsigned short* Wl = (unsigned short*)cs;            // [64][640] = 81920 B
  unsigned short* xl = (unsigned short*)(cs + 81920);  // [132][128] = 33792 B
  int ntile = blockIdx.x, b = blockIdx.y, oh = blockIdx.z;
  int n0 = ntile << 7;
  int t = threadIdx.x, lane = t & 63, w = t >> 6;
  int n16 = lane & 15, q = lane >> 4;

  const unsigned short* wsrc = wch + (size_t)oh * 64 * 640;
  for (int j = 0; j < 20; ++j) {
    int seg = w * 20 + j;
    gl_lds16((const char*)wsrc + (seg << 10) + lane * 16, (char*)Wl + (seg << 10));
  }
  const unsigned short* xpb = xph + (size_t)b * 1024 * 128;
  for (int j = 0; j < 8; ++j) {
    int seg = w * 8 + j;
    gl_lds16((const char*)xpb + (size_t)n0 * 256 + (seg << 10) + lane * 16,
             (char*)xl + 512 + (seg << 10));
  }
  {
    int ri = t >> 6, j2 = t & 63;
    int j = (ri < 2) ? ri : (128 + ri);
    int n = n0 + j - 2;
    unsigned int v = 0;
    if (n >= 0 && n < 1024) v = ((const unsigned int*)xpb)[(size_t)n * 64 + j2];
    ((unsigned int*)xl)[j * 64 + j2] = v;
  }
  __syncthreads();

  f32x4 acc[4][2];
#pragma unroll
  for (int mt = 0; mt < 4; ++mt)
#pragma unroll
    for (int nt = 0; nt < 2; ++nt) acc[mt][nt] = (f32x4){0.f, 0.f, 0.f, 0.f};

  int nb = w * 32;
#pragma unroll
  for (int kk = 0; kk < 5; ++kk) {
    int swb = (n16 + kk + 6) & 7;
#pragma unroll
    for (int kf = 0; kf < 4; ++kf) {
      int ca = kf * 4 + q;
      int LC = kk * 16 + kf * 4 + q;
      int slotA = (LC & 120) | ((LC & 7) ^ (n16 & 7));
      const unsigned short* Ap = Wl + n16 * 640 + slotA * 8;
      short8 a0 = *(const short8*)(Ap);
      short8 a1 = *(const short8*)(Ap + 16 * 640);
      short8 a2 = *(const short8*)(Ap + 32 * 640);
      short8 a3 = *(const short8*)(Ap + 48 * 640);
      int slotB = (ca & 8) | ((ca & 7) ^ swb);
      const unsigned short* Bp = xl + (nb + n16 + kk) * 128 + slotB * 8;
      short8 b0 = *(const short8*)(Bp);
      short8 b1 = *(const short8*)(Bp + 16 * 128);
      acc[0][0] = __builtin_amdgcn_mfma_f32_16x16x32_bf16(a0, b0, acc[0][0], 0, 0, 0);
      acc[0][1] = __builtin_amdgcn_mfma_f32_16x16x32_bf16(a0, b1, acc[0][1], 0, 0, 0);
      acc[1][0] = __builtin_amdgcn_mfma_f32_16x16x32_bf16(a1, b0, acc[1][0], 0, 0, 0);
      acc[1][1] = __builtin_amdgcn_mfma_f32_16x16x32_bf16(a1, b1, acc[1][1], 0, 0, 0);
      acc[2][0] = __builtin_amdgcn_mfma_f32_16x16x32_bf16(a2, b0, acc[2][0], 0, 0, 0);
      acc[2][1] = __builtin_amdgcn_mfma_f32_16x16x32_bf16(a2, b1, acc[2][1], 0, 0, 0);
      acc[3][0] = __builtin_amdgcn_mfma_f32_16x16x32_bf16(a3, b0, acc[3][0], 0, 0, 0);
      acc[3][1] = __builtin_amdgcn_mfma_f32_16x16x32_bf16(a3, b1, acc[3][1], 0, 0, 0);
    }
  }

#pragma unroll
  for (int mt = 0; mt < 4; ++mt) {
#pragma unroll
    for (int i = 0; i < 4; ++i) {
      int oc = oh * 64 + mt * 16 + q * 4 + i;
      const float* res = xv2 + ((size_t)b * 128 + oc) * 1024;
      float* outp = xv3 + ((size_t)b * 128 + oc) * 1024;
#pragma unroll
      for (int nt = 0; nt < 2; ++nt) {
        int n = n0 + nb + nt * 16 + n16;
        outp[n] = acc[mt][nt][i] + res[n];
      }
    }
  }
}

// K9: bilinear 32->96 align_corners=True, f32 out
__global__ __launch_bounds__(256) void k_bilinear(const float* __restrict__ xv3,
                                                  float* __restrict__ out) {
  int idx = blockIdx.x * 256 + threadIdx.x;
  int X = idx % 96;
  int t2 = idx / 96;
  int Y = t2 % 96;
  int bc = t2 / 96;
  const float* src = xv3 + (size_t)bc * 1024;
  const float r = 31.f / 95.f;
  float py = Y * r, px = X * r;
  int y0 = (int)py, x0 = (int)px;
  float wy = py - y0, wx = px - x0;
  int y1 = y0 < 31 ? y0 + 1 : 31, x1 = x0 < 31 ? x0 + 1 : 31;
  float a = src[y0 * 32 + x0], b_ = src[y0 * 32 + x1];
  float c_ = src[y1 * 32 + x0], d_ = src[y1 * 32 + x1];
  float t0 = a * (1.f - wy) + c_ * wy;
  float t1 = b_ * (1.f - wy) + d_ * wy;
  out[idx] = t0 * (1.f - wx) + t1 * wx;
}

extern "C" void kernel_launch(void* const* d_in, const int* in_sizes, int n_in,
                              void* d_out, int out_size, void* d_ws, size_t ws_size,
                              hipStream_t stream) {
  (void)in_sizes; (void)n_in; (void)out_size; (void)ws_size;
  const float* s1    = (const float*)d_in[0];
  const float* o     = (const float*)d_in[1];
  const int*   indx  = (const int*)d_in[2];
  const float* pe_w  = (const float*)d_in[3];
  const float* bn_g  = (const float*)d_in[4];
  const float* bn_b  = (const float*)d_in[5];
  const float* bn_m  = (const float*)d_in[6];
  const float* bn_v  = (const float*)d_in[7];
  const float* lnx_g = (const float*)d_in[8];
  const float* lnx_b = (const float*)d_in[9];
  const float* lny_g = (const float*)d_in[10];
  const float* lny_b = (const float*)d_in[11];
  const float* qkv_w = (const float*)d_in[12];
  const float* qkv_b = (const float*)d_in[13];
  const float* yv_w  = (const float*)d_in[14];
  const float* yv_b  = (const float*)d_in[15];
  const float* proj_w = (const float*)d_in[16];
  const float* proj_b = (const float*)d_in[17];
  const float* c1d_w  = (const float*)d_in[18];

  char* ws = (char*)d_ws;
  unsigned short* xTh = (unsigned short*)ws;
  unsigned short* ymh = (unsigned short*)(ws + 37748736);
  // d_out scratch: wpk +0 (41KB); wch +64KB (160KB); wqkh +448KB (98KB);
  // wyvh +560KB (32KB); wprh +608KB (32KB).
  unsigned short* wpk = (unsigned short*)d_out;
  unsigned short* wch = (unsigned short*)((char*)d_out + 65536);
  unsigned short* wqkh = (unsigned short*)((char*)d_out + 458752);
  unsigned short* wyvh = (unsigned short*)((char*)d_out + 573440);
  unsigned short* wprh = (unsigned short*)((char*)d_out + 622592);
  // Region A = [ws+0, 37.7MB) (xTh dead after k_conv_pe)
  float* ori  = (float*)ws;                 // [0, 8.4MB)
  unsigned short* snh  = (unsigned short*)(ws + 8388608);   // 4.2MB bf16
  unsigned short* oflh = (unsigned short*)(ws + 16777216);  // 4.2MB bf16
  unsigned short* atth = (unsigned short*)(ws + 25165824);  // 4.2MB bf16
  // Region B = [ws+37.7MB, 75.5MB) (ymh dead after k_pool9ln)
  float* vres = (float*)(ws + 37748736);                    // 8.4MB f32, dead after attn
  unsigned short* qkb = (unsigned short*)(ws + 46137344);   // 8.4MB bf16, dead after attn
  unsigned short* vtb = (unsigned short*)(ws + 54525952);   // 4.2MB bf16, dead after attn
  float* xv2 = (float*)(ws + 37748736);                     // alias vres (after attn)
  unsigned short* xph = (unsigned short*)(ws + 46137344);   // alias qkb (after attn)
  float* xv3 = (float*)(ws + 54525952);                     // alias vtb (after attn)

  hipLaunchKernelGGL(k_prepall, dim3(368), dim3(256), 0, stream,
                     pe_w, wpk, c1d_w, wch, qkv_w, wqkh, yv_w, wyvh, proj_w, wprh);
  hipLaunchKernelGGL(k_transpose, dim3(128, 16), dim3(256), 0, stream, s1, xTh);
  hipLaunchKernelGGL(k_conv_pe, dim3(36, 16), dim3(256), 75008, stream,
                     xTh, wpk, bn_g, bn_b, bn_m, bn_v, indx, ymh);
  hipLaunchKernelGGL(k_pool9ln, dim3(64, 16), dim3(256), 0, stream, ymh, lny_g, lny_b, ori, snh);
  hipLaunchKernelGGL(k_poolo_ln, dim3(32, 16), dim3(256), 0, stream, o, lnx_g, lnx_b, oflh);
  hipLaunchKernelGGL(k_gemm_qkv, dim3(128, 6), dim3(256), 0, stream, oflh, wqkh, qkv_b, qkb, vres);
  hipLaunchKernelGGL(k_gemm_yv, dim3(128, 2), dim3(256), 0, stream, snh, wyvh, yv_b, vtb);
  hipLaunchKernelGGL(k_attn, dim3(16, 4, 16), dim3(256), 0, stream, vres, qkb, vtb, atth);
  hipLaunchKernelGGL(k_proj_mfma, dim3(128, 2), dim3(256), 0, stream, atth, wprh, proj_b, ori, xv2, xph);
  hipLaunchKernelGGL(k_conv1d_mfma, dim3(8, 16, 2), dim3(256), 115712, stream, xph, wch, xv2, xv3);
  hipLaunchKernelGGL(k_bilinear, dim3(73728), dim3(256), 0, stream, xv3, (float*)d_out);
}